// Round 3
// baseline (1229.363 us; speedup 1.0000x reference)
//
#include <hip/hip_runtime.h>

// BasisAttention: B=16,S=2048,D=1024,N=4096,K_TOP=64. fp32 in/out.
// Strategy: fp32-accurate GEMMs via 3-product bf16 split (hi/lo) MFMA.
// R2: XOR chunk-swizzle on bf16 LDS tiles (conflicts 1.7e7 -> 0).
// R3: T3 minimum-2-phase LDS double-buffer: stage(t+1) issued before
//     compute(t), ONE __syncthreads per K-step after MFMA -> HBM/L2
//     latency hides under compute instead of serializing.

namespace {

constexpr int D_DIM = 1024;
constexpr int NE    = 4096;
constexpr int BATCH = 16;
constexpr int SEQ   = 2048;
constexpr int MX    = BATCH * SEQ;   // 32768
constexpr int MCH   = 8192;          // m-chunk (4 chunks)
constexpr int KTOP  = 64;
constexpr int BK    = 32;
constexpr int NT    = D_DIM / BK;    // 32 K-steps

using f32x4  = __attribute__((ext_vector_type(4))) float;
using bf16x8 = __attribute__((ext_vector_type(8))) short;

__device__ inline unsigned encf(float f) {
  unsigned u = __float_as_uint(f);
  return (u & 0x80000000u) ? ~u : (u | 0x80000000u);
}
__device__ inline float decf(unsigned e) {
  unsigned u = (e & 0x80000000u) ? (e ^ 0x80000000u) : ~e;
  return __uint_as_float(u);
}

__device__ inline unsigned short f2bf(float f) {  // RNE float->bf16 bits
  unsigned u = __float_as_uint(f);
  unsigned lsb = (u >> 16) & 1u;
  u += 0x7fffu + lsb;
  return (unsigned short)(u >> 16);
}
__device__ inline float bf2f(unsigned short h) {
  return __uint_as_float(((unsigned)h) << 16);
}

__device__ inline void gload16(const void* gsrc, void* ldst) {
  __builtin_amdgcn_global_load_lds(
      (const __attribute__((address_space(1))) unsigned int*)gsrc,
      (__attribute__((address_space(3))) unsigned int*)ldst, 16, 0, 0);
}

// ---------------- K1: per-row rsqrt(mean(x^2)+eps) ----------------
__global__ void row_rinv_k(const float* __restrict__ X, float* __restrict__ rinv) {
  __shared__ float l4[4];
  int row = blockIdx.x;
  float4 v = ((const float4*)(X + (size_t)row * D_DIM))[threadIdx.x];
  float ss = v.x * v.x + v.y * v.y + v.z * v.z + v.w * v.w;
  for (int o = 32; o > 0; o >>= 1) ss += __shfl_xor(ss, o);
  int lane = threadIdx.x & 63, w = threadIdx.x >> 6;
  if (lane == 0) l4[w] = ss;
  __syncthreads();
  if (threadIdx.x == 0) {
    float t = l4[0] + l4[1] + l4[2] + l4[3];
    rinv[row] = rsqrtf(t * (1.0f / D_DIM) + 1e-6f);
  }
}

// ---------------- K1b: split W[n,k]*cw[k] into bf16 hi/lo ----------------
__global__ void split_w_k(const float* __restrict__ W, const float* __restrict__ cw,
                          unsigned short* __restrict__ H, unsigned short* __restrict__ L) {
  int row = blockIdx.x;
  int c0 = threadIdx.x * 4;
  float4 wv = *(const float4*)(W + (size_t)row * D_DIM + c0);
  float4 cv = *(const float4*)(cw + c0);
  float y[4] = {wv.x * cv.x, wv.y * cv.y, wv.z * cv.z, wv.w * cv.w};
  unsigned short h[4], l[4];
#pragma unroll
  for (int i = 0; i < 4; ++i) {
    h[i] = f2bf(y[i]);
    l[i] = f2bf(y[i] - bf2f(h[i]));
  }
  *(ushort4*)(H + (size_t)row * D_DIM + c0) = make_ushort4(h[0], h[1], h[2], h[3]);
  *(ushort4*)(L + (size_t)row * D_DIM + c0) = make_ushort4(l[0], l[1], l[2], l[3]);
}

// ---------------- K2: O(hi,lo) = rowscale(A_f32) @ B(hi,lo)^T ----------------
// 128x128 tile, BK=32, 4 waves (2x2), 16x16x32 MFMA, 3-product split.
// Double-buffered LDS, one barrier per K-step.
__global__ __launch_bounds__(256, 2) void gemm_a32_k(
    const float* __restrict__ A, const float* __restrict__ rinv,
    const unsigned short* __restrict__ BH, const unsigned short* __restrict__ BL,
    unsigned short* __restrict__ OH, unsigned short* __restrict__ OL) {
  __shared__ __align__(16) float lA[2][128 * 32];        // XOR-swizzled (16B chunks)
  __shared__ __align__(16) unsigned short lBH[2][128 * 32];
  __shared__ __align__(16) unsigned short lBL[2][128 * 32];
  __shared__ float ldsR[128];

  int tid = threadIdx.x;
  int lane = tid & 63, wid = tid >> 6;
  int wr = wid >> 1, wc = wid & 1;
  int fr = lane & 15, fg = lane >> 4;
  long m0 = (long)blockIdx.x * 128;
  long n0 = (long)blockIdx.y * 128;

  if (tid < 128) ldsR[tid] = rinv[m0 + tid];

  f32x4 acc[4][4] = {};

  auto stage = [&](int buf, int kk) {
    // A f32 tile [128][32]: 1024 x 16B chunks; source swizzled c^(r&7)
#pragma unroll
    for (int i = 0; i < 4; ++i) {
      int chunk = i * 256 + tid;
      int r = chunk >> 3, c = chunk & 7;
      int cs = c ^ (r & 7);
      const float* src = A + (m0 + r) * (long)D_DIM + kk + cs * 4;
      gload16(src, (void*)(&lA[buf][0] + ((i * 256 + (tid & ~63)) << 2)));
    }
    // B bf16 tiles [128][32]: 4 chunks/row, source swizzled c^((r>>1)&3)
#pragma unroll
    for (int i = 0; i < 2; ++i) {
      int chunk = i * 256 + tid;
      int r = chunk >> 2, c = chunk & 3;
      int cs = c ^ ((r >> 1) & 3);
      long boff = (n0 + r) * (long)D_DIM + kk + cs * 8;
      int lo = (i * 256 + (tid & ~63)) << 3;
      gload16(BH + boff, (void*)(&lBH[buf][0] + lo));
      gload16(BL + boff, (void*)(&lBL[buf][0] + lo));
    }
  };

  stage(0, 0);
  __syncthreads();
  int cur = 0;

  for (int t = 0; t < NT; ++t) {
    if (t + 1 < NT) stage(cur ^ 1, (t + 1) * BK);

    bf16x8 aH[4], aL[4], bH[4], bL[4];
#pragma unroll
    for (int m = 0; m < 4; ++m) {
      int row = wr * 64 + m * 16 + fr;
      int rm = row & 7;
      f32x4 p0 = *(const f32x4*)(&lA[cur][0] + row * 32 + (((fg * 2 + 0) ^ rm) * 4));
      f32x4 p1 = *(const f32x4*)(&lA[cur][0] + row * 32 + (((fg * 2 + 1) ^ rm) * 4));
#pragma unroll
      for (int e = 0; e < 8; ++e) {
        float f = (e < 4) ? p0[e] : p1[e - 4];
        unsigned short h = f2bf(f);
        aH[m][e] = (short)h;
        aL[m][e] = (short)f2bf(f - bf2f(h));
      }
    }
#pragma unroll
    for (int n = 0; n < 4; ++n) {
      int row = wc * 64 + n * 16 + fr;
      int sc = fg ^ ((row >> 1) & 3);
      bH[n] = *(const bf16x8*)(&lBH[cur][0] + row * 32 + sc * 8);
      bL[n] = *(const bf16x8*)(&lBL[cur][0] + row * 32 + sc * 8);
    }
#pragma unroll
    for (int m = 0; m < 4; ++m)
#pragma unroll
      for (int n = 0; n < 4; ++n) {
        acc[m][n] = __builtin_amdgcn_mfma_f32_16x16x32_bf16(aH[m], bH[n], acc[m][n], 0, 0, 0);
        acc[m][n] = __builtin_amdgcn_mfma_f32_16x16x32_bf16(aH[m], bL[n], acc[m][n], 0, 0, 0);
        acc[m][n] = __builtin_amdgcn_mfma_f32_16x16x32_bf16(aL[m], bH[n], acc[m][n], 0, 0, 0);
      }
    __syncthreads();   // drains vmcnt(0): next tile staged; frees cur for overwrite
    cur ^= 1;
  }

  // epilogue: scale by rinv[row], split to bf16 hi/lo, store.
  // C/D layout (m89-verified): col = lane&15, row = (lane>>4)*4 + j
#pragma unroll
  for (int m = 0; m < 4; ++m) {
#pragma unroll
    for (int j = 0; j < 4; ++j) {
      int rloc = wr * 64 + m * 16 + fg * 4 + j;
      float rv = ldsR[rloc];
      long grow = m0 + rloc;
#pragma unroll
      for (int n = 0; n < 4; ++n) {
        long gcol = n0 + wc * 64 + n * 16 + fr;
        float v = acc[m][n][j] * rv;
        unsigned short h = f2bf(v);
        OH[grow * D_DIM + gcol] = h;
        OL[grow * D_DIM + gcol] = f2bf(v - bf2f(h));
      }
    }
  }
}

// ---------------- K3: scores tile + column-max reduce -> atomicMax ----------------
__global__ __launch_bounds__(256, 2) void gemm_scores_k(
    const unsigned short* __restrict__ QH, const unsigned short* __restrict__ QL,
    const unsigned short* __restrict__ KH, const unsigned short* __restrict__ KL,
    unsigned* __restrict__ gmax, int b_base) {
  __shared__ __align__(16) unsigned short lAH[2][128 * 32], lAL[2][128 * 32];
  __shared__ __align__(16) unsigned short lBH[2][128 * 32], lBL[2][128 * 32];

  int tid = threadIdx.x;
  int lane = tid & 63, wid = tid >> 6;
  int wr = wid >> 1, wc = wid & 1;
  int fr = lane & 15, fg = lane >> 4;
  long m0 = (long)blockIdx.x * 128;
  long n0 = (long)blockIdx.y * 128;

  f32x4 acc[4][4] = {};

  auto stage = [&](int buf, int kk) {
#pragma unroll
    for (int i = 0; i < 2; ++i) {
      int chunk = i * 256 + tid;
      int r = chunk >> 2, c = chunk & 3;
      int cs = c ^ ((r >> 1) & 3);
      long aoff = (m0 + r) * (long)D_DIM + kk + cs * 8;
      long boff = (n0 + r) * (long)D_DIM + kk + cs * 8;
      int lo = (i * 256 + (tid & ~63)) << 3;
      gload16(QH + aoff, (void*)(&lAH[buf][0] + lo));
      gload16(QL + aoff, (void*)(&lAL[buf][0] + lo));
      gload16(KH + boff, (void*)(&lBH[buf][0] + lo));
      gload16(KL + boff, (void*)(&lBL[buf][0] + lo));
    }
  };

  stage(0, 0);
  __syncthreads();
  int cur = 0;

  for (int t = 0; t < NT; ++t) {
    if (t + 1 < NT) stage(cur ^ 1, (t + 1) * BK);

    bf16x8 aH[4], aL[4], bH[4], bL[4];
#pragma unroll
    for (int m = 0; m < 4; ++m) {
      int row = wr * 64 + m * 16 + fr;
      int sc = fg ^ ((row >> 1) & 3);
      aH[m] = *(const bf16x8*)(&lAH[cur][0] + row * 32 + sc * 8);
      aL[m] = *(const bf16x8*)(&lAL[cur][0] + row * 32 + sc * 8);
    }
#pragma unroll
    for (int n = 0; n < 4; ++n) {
      int row = wc * 64 + n * 16 + fr;
      int sc = fg ^ ((row >> 1) & 3);
      bH[n] = *(const bf16x8*)(&lBH[cur][0] + row * 32 + sc * 8);
      bL[n] = *(const bf16x8*)(&lBL[cur][0] + row * 32 + sc * 8);
    }
#pragma unroll
    for (int m = 0; m < 4; ++m)
#pragma unroll
      for (int n = 0; n < 4; ++n) {
        acc[m][n] = __builtin_amdgcn_mfma_f32_16x16x32_bf16(aH[m], bH[n], acc[m][n], 0, 0, 0);
        acc[m][n] = __builtin_amdgcn_mfma_f32_16x16x32_bf16(aH[m], bL[n], acc[m][n], 0, 0, 0);
        acc[m][n] = __builtin_amdgcn_mfma_f32_16x16x32_bf16(aL[m], bH[n], acc[m][n], 0, 0, 0);
      }
    __syncthreads();
    cur ^= 1;
  }

  // per-column max over this tile's 128 rows; scale by 2^-5 (exact), encode, atomic.
  int b = b_base + (int)(m0 >> 11);
#pragma unroll
  for (int n = 0; n < 4; ++n) {
    float v = -3.0e38f;
#pragma unroll
    for (int m = 0; m < 4; ++m)
#pragma unroll
      for (int j = 0; j < 4; ++j) v = fmaxf(v, acc[m][n][j]);
    v = fmaxf(v, __shfl_xor(v, 16));
    v = fmaxf(v, __shfl_xor(v, 32));
    if (fg == 0) {
      long col = n0 + wc * 64 + n * 16 + fr;
      atomicMax(&gmax[(long)b * NE + col], encf(v * 0.03125f));
    }
  }
}

// ---------------- K4: per-batch exact top-64 cutoff + softmax weights ----------------
__global__ void topk_weights_k(const unsigned* __restrict__ gmax,
                               const float* __restrict__ alpha_p,
                               float* __restrict__ wout, int* __restrict__ idx,
                               int* __restrict__ cnt) {
  __shared__ unsigned enc[NE];
  __shared__ unsigned ubc[4];
  __shared__ float l4[4];
  __shared__ int ic[257];
  int tid = threadIdx.x;
  int lane = tid & 63, w = tid >> 6;
  const unsigned* g = gmax + (size_t)blockIdx.x * NE;
  for (int i = tid; i < NE; i += 256) enc[i] = g[i];
  __syncthreads();

  // block max (encoded domain, monotonic)
  unsigned mx = 0;
  for (int i = tid; i < NE; i += 256) mx = enc[i] > mx ? enc[i] : mx;
  for (int o = 32; o > 0; o >>= 1) {
    unsigned other = (unsigned)__shfl_xor((int)mx, o);
    if (other > mx) mx = other;
  }
  if (lane == 0) ubc[w] = mx;
  __syncthreads();
  unsigned m1e = ubc[0];
  for (int t = 1; t < 4; ++t) m1e = ubc[t] > m1e ? ubc[t] : m1e;
  float m1 = decf(m1e);

  // binary search: largest u with count(enc >= u) >= KTOP  -> u = enc(64th largest)
  unsigned cur = 0;
  for (int bit = 31; bit >= 0; --bit) {
    unsigned cand = cur | (1u << bit);
    int c = 0;
    for (int i = tid; i < NE; i += 256) c += (enc[i] >= cand) ? 1 : 0;
    for (int o = 32; o > 0; o >>= 1) c += __shfl_xor(c, o);
    __syncthreads();
    if (lane == 0) ic[w] = c;
    __syncthreads();
    int tot = ic[0] + ic[1] + ic[2] + ic[3];
    if (tot >= KTOP) cur = cand;
  }

  // softmax sums
  float sd = 0.f, ssum = 0.f;
  for (int i = tid; i < NE; i += 256) {
    float e = expf(decf(enc[i]) - m1);
    sd += e;
    if (enc[i] >= cur) ssum += e;
  }
  for (int o = 32; o > 0; o >>= 1) { sd += __shfl_xor(sd, o); ssum += __shfl_xor(ssum, o); }
  __syncthreads();
  if (lane == 0) { l4[w] = sd; }
  __syncthreads();
  float SD = l4[0] + l4[1] + l4[2] + l4[3];
  __syncthreads();
  if (lane == 0) { l4[w] = ssum; }
  __syncthreads();
  float SS = l4[0] + l4[1] + l4[2] + l4[3];

  float alpha = alpha_p[0];
  float wd = alpha / SD;
  float ws_ = (1.0f - alpha) / SS;
  for (int i = tid; i < NE; i += 256) {
    float e = expf(decf(enc[i]) - m1);
    float wv = wd * e + ((enc[i] >= cur) ? ws_ * e : 0.0f);
    wout[(size_t)blockIdx.x * NE + i] = wv;
  }

  // deterministic compaction of selected indices (for K5 sparse path)
  int myc = 0;
  for (int i = tid; i < NE; i += 256) myc += (enc[i] >= cur) ? 1 : 0;
  __syncthreads();
  ic[tid] = myc;
  __syncthreads();
  if (tid == 0) {
    int s = 0;
    for (int t = 0; t < 256; ++t) { int v = ic[t]; ic[t] = s; s += v; }
    ic[256] = s;
    cnt[blockIdx.x] = s;
  }
  __syncthreads();
  int off = ic[tid];
  for (int i = tid; i < NE; i += 256)
    if (enc[i] >= cur) idx[(size_t)blockIdx.x * NE + (off++)] = i;
}

// ---------------- K5: O = rmsnorm(weights @ En, on_w) ----------------
__global__ void out_o_k(const float* __restrict__ wts, const float* __restrict__ E,
                        const float* __restrict__ rinvE, const float* __restrict__ sn_w,
                        const float* __restrict__ on_w, const float* __restrict__ alpha_p,
                        const int* __restrict__ idx, const int* __restrict__ cnt,
                        float* __restrict__ O) {
  __shared__ float l4[4];
  int b = blockIdx.x, tid = threadIdx.x;
  float acc[4] = {0.f, 0.f, 0.f, 0.f};
  float alpha = alpha_p[0];
  if (alpha == 0.0f) {
    int nsel = cnt[b];
    for (int j = 0; j < nsel; ++j) {
      int n = idx[(size_t)b * NE + j];
      float wv = wts[(size_t)b * NE + n] * rinvE[n];
      const float* er = E + (size_t)n * D_DIM;
#pragma unroll
      for (int i = 0; i < 4; ++i) acc[i] += wv * er[tid + 256 * i];
    }
  } else {
    for (int n = 0; n < NE; ++n) {
      float wv = wts[(size_t)b * NE + n] * rinvE[n];
      const float* er = E + (size_t)n * D_DIM;
#pragma unroll
      for (int i = 0; i < 4; ++i) acc[i] += wv * er[tid + 256 * i];
    }
  }
  float ssq = 0.f;
#pragma unroll
  for (int i = 0; i < 4; ++i) {
    acc[i] *= sn_w[tid + 256 * i];
    ssq += acc[i] * acc[i];
  }
  for (int o = 32; o > 0; o >>= 1) ssq += __shfl_xor(ssq, o);
  int lane = tid & 63, w = tid >> 6;
  if (lane == 0) l4[w] = ssq;
  __syncthreads();
  float tot = l4[0] + l4[1] + l4[2] + l4[3];
  float r = rsqrtf(tot * (1.0f / D_DIM) + 1e-6f);
#pragma unroll
  for (int i = 0; i < 4; ++i)
    O[(size_t)b * D_DIM + tid + 256 * i] = acc[i] * r * on_w[tid + 256 * i];
}

}  // namespace

extern "C" void kernel_launch(void* const* d_in, const int* in_sizes, int n_in,
                              void* d_out, int out_size, void* d_ws, size_t ws_size,
                              hipStream_t stream) {
  const float* X     = (const float*)d_in[0];
  const float* alpha = (const float*)d_in[1];
  const float* E     = (const float*)d_in[2];
  const float* Wq    = (const float*)d_in[3];
  const float* Wk    = (const float*)d_in[4];
  const float* xn_w  = (const float*)d_in[5];
  const float* sn_w  = (const float*)d_in[6];
  const float* on_w  = (const float*)d_in[7];
  float* O    = (float*)d_out;                       // [16][1024]
  float* Wout = (float*)d_out + (size_t)BATCH * D_DIM;  // [16][4096]

  char* ws = (char*)d_ws;
  size_t off = 0;
  auto alloc = [&](size_t bytes) {
    char* p = ws + off;
    off += (bytes + 255) & ~(size_t)255;
    return p;
  };
  unsigned short* QH  = (unsigned short*)alloc((size_t)MCH * D_DIM * 2);
  unsigned short* QL  = (unsigned short*)alloc((size_t)MCH * D_DIM * 2);
  unsigned short* KmH = (unsigned short*)alloc((size_t)NE * D_DIM * 2);
  unsigned short* KmL = (unsigned short*)alloc((size_t)NE * D_DIM * 2);
  unsigned short* WqH = (unsigned short*)alloc((size_t)D_DIM * D_DIM * 2);
  unsigned short* WqL = (unsigned short*)alloc((size_t)D_DIM * D_DIM * 2);
  unsigned short* WkH = (unsigned short*)alloc((size_t)D_DIM * D_DIM * 2);
  unsigned short* WkL = (unsigned short*)alloc((size_t)D_DIM * D_DIM * 2);
  float* rinvX = (float*)alloc((size_t)MX * 4);
  float* rinvE = (float*)alloc((size_t)NE * 4);
  unsigned* gmax = (unsigned*)alloc((size_t)BATCH * NE * 4);
  int* idx = (int*)alloc((size_t)BATCH * NE * 4);
  int* cnt = (int*)alloc((size_t)BATCH * 4);
  if (off > ws_size) return;  // needs ~60 MB scratch

  row_rinv_k<<<MX, 256, 0, stream>>>(X, rinvX);
  row_rinv_k<<<NE, 256, 0, stream>>>(E, rinvE);
  split_w_k<<<D_DIM, 256, 0, stream>>>(Wq, xn_w, WqH, WqL);
  split_w_k<<<D_DIM, 256, 0, stream>>>(Wk, sn_w, WkH, WkL);

  // Km = (E * rinvE) @ (Wk*sn_w)^T, split output
  gemm_a32_k<<<dim3(NE / 128, D_DIM / 128), 256, 0, stream>>>(E, rinvE, WkH, WkL, KmH, KmL);

  hipMemsetAsync(gmax, 0, (size_t)BATCH * NE * 4, stream);

  for (int ch = 0; ch < MX / MCH; ++ch) {
    long m0 = (long)ch * MCH;
    gemm_a32_k<<<dim3(MCH / 128, D_DIM / 128), 256, 0, stream>>>(
        X + m0 * D_DIM, rinvX + m0, WqH, WqL, QH, QL);
    gemm_scores_k<<<dim3(MCH / 128, NE / 128), 256, 0, stream>>>(
        QH, QL, KmH, KmL, gmax, (int)(m0 >> 11));
  }

  topk_weights_k<<<BATCH, 256, 0, stream>>>(gmax, alpha, Wout, idx, cnt);
  out_o_k<<<BATCH, 256, 0, stream>>>(Wout, E, rinvE, sn_w, on_w, alpha, idx, cnt, O);
}

// Round 4
// 955.186 us; speedup vs baseline: 1.2870x; 1.2870x over previous
//
#include <hip/hip_runtime.h>

// BasisAttention: B=16,S=2048,D=1024,N=4096,K_TOP=64. fp32 in/out.
// R2: XOR chunk-swizzle (conflicts 1.7e7 -> 0). R3 dbuf REVERTED (regressed:
//     __syncthreads drains vmcnt(0) anyway + occupancy loss).
// R4: approx-then-rescore. Scores pass is 1-product bf16 (QH*KH) for
//     candidate max only; per-batch top-128 candidates re-scored with the
//     exact 3-product split; exact values scattered over approx gmax.
//     Batches are chunk-local (2048 | 8192) so this runs per chunk.

namespace {

constexpr int D_DIM = 1024;
constexpr int NE    = 4096;
constexpr int BATCH = 16;
constexpr int SEQ   = 2048;
constexpr int MX    = BATCH * SEQ;   // 32768
constexpr int MCH   = 8192;          // m-chunk (4 chunks, 4 batches each)
constexpr int KTOP  = 64;
constexpr int CAND  = 128;           // candidates per batch (>= KTOP, margin ~20x)
constexpr int BK    = 32;

using f32x4  = __attribute__((ext_vector_type(4))) float;
using bf16x8 = __attribute__((ext_vector_type(8))) short;

__device__ inline unsigned encf(float f) {
  unsigned u = __float_as_uint(f);
  return (u & 0x80000000u) ? ~u : (u | 0x80000000u);
}
__device__ inline float decf(unsigned e) {
  unsigned u = (e & 0x80000000u) ? (e ^ 0x80000000u) : ~e;
  return __uint_as_float(u);
}

__device__ inline unsigned short f2bf(float f) {  // RNE float->bf16 bits
  unsigned u = __float_as_uint(f);
  unsigned lsb = (u >> 16) & 1u;
  u += 0x7fffu + lsb;
  return (unsigned short)(u >> 16);
}
__device__ inline float bf2f(unsigned short h) {
  return __uint_as_float(((unsigned)h) << 16);
}

__device__ inline void gload16(const void* gsrc, void* ldst) {
  __builtin_amdgcn_global_load_lds(
      (const __attribute__((address_space(1))) unsigned int*)gsrc,
      (__attribute__((address_space(3))) unsigned int*)ldst, 16, 0, 0);
}

// ---------------- K1: per-row rsqrt(mean(x^2)+eps) ----------------
__global__ void row_rinv_k(const float* __restrict__ X, float* __restrict__ rinv) {
  __shared__ float l4[4];
  int row = blockIdx.x;
  float4 v = ((const float4*)(X + (size_t)row * D_DIM))[threadIdx.x];
  float ss = v.x * v.x + v.y * v.y + v.z * v.z + v.w * v.w;
  for (int o = 32; o > 0; o >>= 1) ss += __shfl_xor(ss, o);
  int lane = threadIdx.x & 63, w = threadIdx.x >> 6;
  if (lane == 0) l4[w] = ss;
  __syncthreads();
  if (threadIdx.x == 0) {
    float t = l4[0] + l4[1] + l4[2] + l4[3];
    rinv[row] = rsqrtf(t * (1.0f / D_DIM) + 1e-6f);
  }
}

// ---------------- K1b: split W[n,k]*cw[k] into bf16 hi/lo ----------------
__global__ void split_w_k(const float* __restrict__ W, const float* __restrict__ cw,
                          unsigned short* __restrict__ H, unsigned short* __restrict__ L) {
  int row = blockIdx.x;
  int c0 = threadIdx.x * 4;
  float4 wv = *(const float4*)(W + (size_t)row * D_DIM + c0);
  float4 cv = *(const float4*)(cw + c0);
  float y[4] = {wv.x * cv.x, wv.y * cv.y, wv.z * cv.z, wv.w * cv.w};
  unsigned short h[4], l[4];
#pragma unroll
  for (int i = 0; i < 4; ++i) {
    h[i] = f2bf(y[i]);
    l[i] = f2bf(y[i] - bf2f(h[i]));
  }
  *(ushort4*)(H + (size_t)row * D_DIM + c0) = make_ushort4(h[0], h[1], h[2], h[3]);
  *(ushort4*)(L + (size_t)row * D_DIM + c0) = make_ushort4(l[0], l[1], l[2], l[3]);
}

// ---------------- K2: O(hi,lo) = rowscale(A_f32) @ B(hi,lo)^T ----------------
// 128x128 tile, BK=32, 4 waves (2x2), 16x16x32 MFMA, 3-product split.
// Single-buffer (R2 form).
__global__ __launch_bounds__(256, 2) void gemm_a32_k(
    const float* __restrict__ A, const float* __restrict__ rinv,
    const unsigned short* __restrict__ BH, const unsigned short* __restrict__ BL,
    unsigned short* __restrict__ OH, unsigned short* __restrict__ OL) {
  __shared__ __align__(16) float lA[128 * 32];        // XOR-swizzled (16B chunks)
  __shared__ __align__(16) unsigned short lBH[128 * 32];
  __shared__ __align__(16) unsigned short lBL[128 * 32];
  __shared__ float ldsR[128];

  int tid = threadIdx.x;
  int lane = tid & 63, wid = tid >> 6;
  int wr = wid >> 1, wc = wid & 1;
  int fr = lane & 15, fg = lane >> 4;
  long m0 = (long)blockIdx.x * 128;
  long n0 = (long)blockIdx.y * 128;

  if (tid < 128) ldsR[tid] = rinv[m0 + tid];

  f32x4 acc[4][4] = {};

  for (int kk = 0; kk < D_DIM; kk += BK) {
#pragma unroll
    for (int i = 0; i < 4; ++i) {
      int chunk = i * 256 + tid;
      int r = chunk >> 3, c = chunk & 7;
      int cs = c ^ (r & 7);
      const float* src = A + (m0 + r) * (long)D_DIM + kk + cs * 4;
      gload16(src, (void*)(lA + ((i * 256 + (tid & ~63)) << 2)));
    }
#pragma unroll
    for (int i = 0; i < 2; ++i) {
      int chunk = i * 256 + tid;
      int r = chunk >> 2, c = chunk & 3;
      int cs = c ^ ((r >> 1) & 3);
      long boff = (n0 + r) * (long)D_DIM + kk + cs * 8;
      int lo = (i * 256 + (tid & ~63)) << 3;
      gload16(BH + boff, (void*)(lBH + lo));
      gload16(BL + boff, (void*)(lBL + lo));
    }
    __syncthreads();

    bf16x8 aH[4], aL[4], bH[4], bL[4];
#pragma unroll
    for (int m = 0; m < 4; ++m) {
      int row = wr * 64 + m * 16 + fr;
      int rm = row & 7;
      f32x4 p0 = *(const f32x4*)(lA + row * 32 + (((fg * 2 + 0) ^ rm) * 4));
      f32x4 p1 = *(const f32x4*)(lA + row * 32 + (((fg * 2 + 1) ^ rm) * 4));
#pragma unroll
      for (int e = 0; e < 8; ++e) {
        float f = (e < 4) ? p0[e] : p1[e - 4];
        unsigned short h = f2bf(f);
        aH[m][e] = (short)h;
        aL[m][e] = (short)f2bf(f - bf2f(h));
      }
    }
#pragma unroll
    for (int n = 0; n < 4; ++n) {
      int row = wc * 64 + n * 16 + fr;
      int sc = fg ^ ((row >> 1) & 3);
      bH[n] = *(const bf16x8*)(lBH + row * 32 + sc * 8);
      bL[n] = *(const bf16x8*)(lBL + row * 32 + sc * 8);
    }
#pragma unroll
    for (int m = 0; m < 4; ++m)
#pragma unroll
      for (int n = 0; n < 4; ++n) {
        acc[m][n] = __builtin_amdgcn_mfma_f32_16x16x32_bf16(aH[m], bH[n], acc[m][n], 0, 0, 0);
        acc[m][n] = __builtin_amdgcn_mfma_f32_16x16x32_bf16(aH[m], bL[n], acc[m][n], 0, 0, 0);
        acc[m][n] = __builtin_amdgcn_mfma_f32_16x16x32_bf16(aL[m], bH[n], acc[m][n], 0, 0, 0);
      }
    __syncthreads();
  }

  // epilogue: scale by rinv[row], split to bf16 hi/lo, store.
#pragma unroll
  for (int m = 0; m < 4; ++m) {
#pragma unroll
    for (int j = 0; j < 4; ++j) {
      int rloc = wr * 64 + m * 16 + fg * 4 + j;
      float rv = ldsR[rloc];
      long grow = m0 + rloc;
#pragma unroll
      for (int n = 0; n < 4; ++n) {
        long gcol = n0 + wc * 64 + n * 16 + fr;
        float v = acc[m][n][j] * rv;
        unsigned short h = f2bf(v);
        OH[grow * D_DIM + gcol] = h;
        OL[grow * D_DIM + gcol] = f2bf(v - bf2f(h));
      }
    }
  }
}

// ---------------- K3a: APPROX scores (1-product) + column-max -> atomicMax ----------------
__global__ __launch_bounds__(256, 2) void gemm_scores1_k(
    const unsigned short* __restrict__ QH, const unsigned short* __restrict__ KH,
    unsigned* __restrict__ gmax, int b_base) {
  __shared__ __align__(16) unsigned short lAH[128 * 32];
  __shared__ __align__(16) unsigned short lBH[128 * 32];

  int tid = threadIdx.x;
  int lane = tid & 63, wid = tid >> 6;
  int wr = wid >> 1, wc = wid & 1;
  int fr = lane & 15, fg = lane >> 4;
  long m0 = (long)blockIdx.x * 128;
  long n0 = (long)blockIdx.y * 128;

  f32x4 acc[4][4] = {};

  for (int kk = 0; kk < D_DIM; kk += BK) {
#pragma unroll
    for (int i = 0; i < 2; ++i) {
      int chunk = i * 256 + tid;
      int r = chunk >> 2, c = chunk & 3;
      int cs = c ^ ((r >> 1) & 3);
      long aoff = (m0 + r) * (long)D_DIM + kk + cs * 8;
      long boff = (n0 + r) * (long)D_DIM + kk + cs * 8;
      int lo = (i * 256 + (tid & ~63)) << 3;
      gload16(QH + aoff, (void*)(lAH + lo));
      gload16(KH + boff, (void*)(lBH + lo));
    }
    __syncthreads();

    bf16x8 aH[4], bH[4];
#pragma unroll
    for (int m = 0; m < 4; ++m) {
      int row = wr * 64 + m * 16 + fr;
      int sc = fg ^ ((row >> 1) & 3);
      aH[m] = *(const bf16x8*)(lAH + row * 32 + sc * 8);
    }
#pragma unroll
    for (int n = 0; n < 4; ++n) {
      int row = wc * 64 + n * 16 + fr;
      int sc = fg ^ ((row >> 1) & 3);
      bH[n] = *(const bf16x8*)(lBH + row * 32 + sc * 8);
    }
#pragma unroll
    for (int m = 0; m < 4; ++m)
#pragma unroll
      for (int n = 0; n < 4; ++n)
        acc[m][n] = __builtin_amdgcn_mfma_f32_16x16x32_bf16(aH[m], bH[n], acc[m][n], 0, 0, 0);
    __syncthreads();
  }

  int b = b_base + (int)(m0 >> 11);
#pragma unroll
  for (int n = 0; n < 4; ++n) {
    float v = -3.0e38f;
#pragma unroll
    for (int m = 0; m < 4; ++m)
#pragma unroll
      for (int j = 0; j < 4; ++j) v = fmaxf(v, acc[m][n][j]);
    v = fmaxf(v, __shfl_xor(v, 16));
    v = fmaxf(v, __shfl_xor(v, 32));
    if (fg == 0) {
      long col = n0 + wc * 64 + n * 16 + fr;
      atomicMax(&gmax[(long)b * NE + col], encf(v * 0.03125f));
    }
  }
}

// ---------------- K3b: per-batch top-CAND candidate selection ----------------
__global__ void cand_select_k(const unsigned* __restrict__ gmax, int b_base,
                              int* __restrict__ candIdx) {
  __shared__ unsigned enc[NE];
  __shared__ int ic[257];
  int tid = threadIdx.x;
  int lane = tid & 63, w = tid >> 6;
  int z = blockIdx.x;
  const unsigned* g = gmax + (size_t)(b_base + z) * NE;
  for (int i = tid; i < NE; i += 256) enc[i] = g[i];
  __syncthreads();

  // binary search: largest u with count(enc >= u) >= CAND
  unsigned cur = 0;
  for (int bit = 31; bit >= 0; --bit) {
    unsigned cand = cur | (1u << bit);
    int c = 0;
    for (int i = tid; i < NE; i += 256) c += (enc[i] >= cand) ? 1 : 0;
    for (int o = 32; o > 0; o >>= 1) c += __shfl_xor(c, o);
    __syncthreads();
    if (lane == 0) ic[w] = c;
    __syncthreads();
    int tot = ic[0] + ic[1] + ic[2] + ic[3];
    if (tot >= CAND) cur = cand;
  }

  // deterministic compaction, capped at CAND
  int myc = 0;
  for (int i = tid; i < NE; i += 256) myc += (enc[i] >= cur) ? 1 : 0;
  __syncthreads();
  ic[tid] = myc;
  __syncthreads();
  if (tid == 0) {
    int s = 0;
    for (int t = 0; t < 256; ++t) { int v = ic[t]; ic[t] = s; s += v; }
  }
  __syncthreads();
  int off = ic[tid];
  for (int i = tid; i < NE; i += 256)
    if (enc[i] >= cur) {
      if (off < CAND) candIdx[z * CAND + off] = i;
      ++off;
    }
}

// ---------------- K3c: gather candidate Km rows ----------------
__global__ void gather_k(const unsigned short* __restrict__ KmH,
                         const unsigned short* __restrict__ KmL,
                         const int* __restrict__ candIdx,
                         unsigned short* __restrict__ cKH,
                         unsigned short* __restrict__ cKL) {
  int j = blockIdx.x, z = blockIdx.y;
  int n = candIdx[z * CAND + j];
  int t4 = threadIdx.x * 4;
  size_t dst = ((size_t)(z * CAND + j)) * D_DIM + t4;
  size_t src = (size_t)n * D_DIM + t4;
  *(ushort4*)(cKH + dst) = *(const ushort4*)(KmH + src);
  *(ushort4*)(cKL + dst) = *(const ushort4*)(KmL + src);
}

// ---------------- K3d: EXACT rescore of candidates (3-product) ----------------
// grid (2048/128, 1, 4): per batch z of chunk, A rows = z*2048+m0.., B = cK[z].
__global__ __launch_bounds__(256, 2) void gemm_rescore_k(
    const unsigned short* __restrict__ QH, const unsigned short* __restrict__ QL,
    const unsigned short* __restrict__ cKH, const unsigned short* __restrict__ cKL,
    unsigned* __restrict__ gmax2) {
  __shared__ __align__(16) unsigned short lAH[128 * 32], lAL[128 * 32];
  __shared__ __align__(16) unsigned short lBH[128 * 32], lBL[128 * 32];

  int tid = threadIdx.x;
  int lane = tid & 63, wid = tid >> 6;
  int wr = wid >> 1, wc = wid & 1;
  int fr = lane & 15, fg = lane >> 4;
  int z = blockIdx.z;
  long m0 = (long)blockIdx.x * 128;
  long arow0 = (long)z * SEQ + m0;
  long brow0 = (long)z * CAND;

  f32x4 acc[4][4] = {};

  for (int kk = 0; kk < D_DIM; kk += BK) {
#pragma unroll
    for (int i = 0; i < 2; ++i) {
      int chunk = i * 256 + tid;
      int r = chunk >> 2, c = chunk & 3;
      int cs = c ^ ((r >> 1) & 3);
      long aoff = (arow0 + r) * (long)D_DIM + kk + cs * 8;
      long boff = (brow0 + r) * (long)D_DIM + kk + cs * 8;
      int lo = (i * 256 + (tid & ~63)) << 3;
      gload16(QH + aoff, (void*)(lAH + lo));
      gload16(QL + aoff, (void*)(lAL + lo));
      gload16(cKH + boff, (void*)(lBH + lo));
      gload16(cKL + boff, (void*)(lBL + lo));
    }
    __syncthreads();

    bf16x8 aH[4], aL[4], bH[4], bL[4];
#pragma unroll
    for (int m = 0; m < 4; ++m) {
      int row = wr * 64 + m * 16 + fr;
      int sc = fg ^ ((row >> 1) & 3);
      aH[m] = *(const bf16x8*)(lAH + row * 32 + sc * 8);
      aL[m] = *(const bf16x8*)(lAL + row * 32 + sc * 8);
    }
#pragma unroll
    for (int n = 0; n < 4; ++n) {
      int row = wc * 64 + n * 16 + fr;
      int sc = fg ^ ((row >> 1) & 3);
      bH[n] = *(const bf16x8*)(lBH + row * 32 + sc * 8);
      bL[n] = *(const bf16x8*)(lBL + row * 32 + sc * 8);
    }
#pragma unroll
    for (int m = 0; m < 4; ++m)
#pragma unroll
      for (int n = 0; n < 4; ++n) {
        acc[m][n] = __builtin_amdgcn_mfma_f32_16x16x32_bf16(aH[m], bH[n], acc[m][n], 0, 0, 0);
        acc[m][n] = __builtin_amdgcn_mfma_f32_16x16x32_bf16(aH[m], bL[n], acc[m][n], 0, 0, 0);
        acc[m][n] = __builtin_amdgcn_mfma_f32_16x16x32_bf16(aL[m], bH[n], acc[m][n], 0, 0, 0);
      }
    __syncthreads();
  }

#pragma unroll
  for (int n = 0; n < 4; ++n) {
    float v = -3.0e38f;
#pragma unroll
    for (int m = 0; m < 4; ++m)
#pragma unroll
      for (int j = 0; j < 4; ++j) v = fmaxf(v, acc[m][n][j]);
    v = fmaxf(v, __shfl_xor(v, 16));
    v = fmaxf(v, __shfl_xor(v, 32));
    if (fg == 0) {
      int col = wc * 64 + n * 16 + fr;   // 0..127
      atomicMax(&gmax2[z * CAND + col], encf(v * 0.03125f));
    }
  }
}

// ---------------- K3e: scatter exact candidate values over approx gmax ----------------
__global__ void scatter_k(const unsigned* __restrict__ gmax2,
                          const int* __restrict__ candIdx,
                          unsigned* __restrict__ gmax, int b_base) {
  int z = blockIdx.x, j = threadIdx.x;
  int n = candIdx[z * CAND + j];
  gmax[(size_t)(b_base + z) * NE + n] = gmax2[z * CAND + j];
}

// ---------------- K4: per-batch exact top-64 cutoff + softmax weights ----------------
__global__ void topk_weights_k(const unsigned* __restrict__ gmax,
                               const float* __restrict__ alpha_p,
                               float* __restrict__ wout, int* __restrict__ idx,
                               int* __restrict__ cnt) {
  __shared__ unsigned enc[NE];
  __shared__ unsigned ubc[4];
  __shared__ float l4[4];
  __shared__ int ic[257];
  int tid = threadIdx.x;
  int lane = tid & 63, w = tid >> 6;
  const unsigned* g = gmax + (size_t)blockIdx.x * NE;
  for (int i = tid; i < NE; i += 256) enc[i] = g[i];
  __syncthreads();

  unsigned mx = 0;
  for (int i = tid; i < NE; i += 256) mx = enc[i] > mx ? enc[i] : mx;
  for (int o = 32; o > 0; o >>= 1) {
    unsigned other = (unsigned)__shfl_xor((int)mx, o);
    if (other > mx) mx = other;
  }
  if (lane == 0) ubc[w] = mx;
  __syncthreads();
  unsigned m1e = ubc[0];
  for (int t = 1; t < 4; ++t) m1e = ubc[t] > m1e ? ubc[t] : m1e;
  float m1 = decf(m1e);

  unsigned cur = 0;
  for (int bit = 31; bit >= 0; --bit) {
    unsigned cand = cur | (1u << bit);
    int c = 0;
    for (int i = tid; i < NE; i += 256) c += (enc[i] >= cand) ? 1 : 0;
    for (int o = 32; o > 0; o >>= 1) c += __shfl_xor(c, o);
    __syncthreads();
    if (lane == 0) ic[w] = c;
    __syncthreads();
    int tot = ic[0] + ic[1] + ic[2] + ic[3];
    if (tot >= KTOP) cur = cand;
  }

  float sd = 0.f, ssum = 0.f;
  for (int i = tid; i < NE; i += 256) {
    float e = expf(decf(enc[i]) - m1);
    sd += e;
    if (enc[i] >= cur) ssum += e;
  }
  for (int o = 32; o > 0; o >>= 1) { sd += __shfl_xor(sd, o); ssum += __shfl_xor(ssum, o); }
  __syncthreads();
  if (lane == 0) { l4[w] = sd; }
  __syncthreads();
  float SD = l4[0] + l4[1] + l4[2] + l4[3];
  __syncthreads();
  if (lane == 0) { l4[w] = ssum; }
  __syncthreads();
  float SS = l4[0] + l4[1] + l4[2] + l4[3];

  float alpha = alpha_p[0];
  float wd = alpha / SD;
  float ws_ = (1.0f - alpha) / SS;
  for (int i = tid; i < NE; i += 256) {
    float e = expf(decf(enc[i]) - m1);
    float wv = wd * e + ((enc[i] >= cur) ? ws_ * e : 0.0f);
    wout[(size_t)blockIdx.x * NE + i] = wv;
  }

  int myc = 0;
  for (int i = tid; i < NE; i += 256) myc += (enc[i] >= cur) ? 1 : 0;
  __syncthreads();
  ic[tid] = myc;
  __syncthreads();
  if (tid == 0) {
    int s = 0;
    for (int t = 0; t < 256; ++t) { int v = ic[t]; ic[t] = s; s += v; }
    ic[256] = s;
    cnt[blockIdx.x] = s;
  }
  __syncthreads();
  int off = ic[tid];
  for (int i = tid; i < NE; i += 256)
    if (enc[i] >= cur) idx[(size_t)blockIdx.x * NE + (off++)] = i;
}

// ---------------- K5: O = rmsnorm(weights @ En, on_w) ----------------
__global__ void out_o_k(const float* __restrict__ wts, const float* __restrict__ E,
                        const float* __restrict__ rinvE, const float* __restrict__ sn_w,
                        const float* __restrict__ on_w, const float* __restrict__ alpha_p,
                        const int* __restrict__ idx, const int* __restrict__ cnt,
                        float* __restrict__ O) {
  __shared__ float l4[4];
  int b = blockIdx.x, tid = threadIdx.x;
  float acc[4] = {0.f, 0.f, 0.f, 0.f};
  float alpha = alpha_p[0];
  if (alpha == 0.0f) {
    int nsel = cnt[b];
    for (int j = 0; j < nsel; ++j) {
      int n = idx[(size_t)b * NE + j];
      float wv = wts[(size_t)b * NE + n] * rinvE[n];
      const float* er = E + (size_t)n * D_DIM;
#pragma unroll
      for (int i = 0; i < 4; ++i) acc[i] += wv * er[tid + 256 * i];
    }
  } else {
    for (int n = 0; n < NE; ++n) {
      float wv = wts[(size_t)b * NE + n] * rinvE[n];
      const float* er = E + (size_t)n * D_DIM;
#pragma unroll
      for (int i = 0; i < 4; ++i) acc[i] += wv * er[tid + 256 * i];
    }
  }
  float ssq = 0.f;
#pragma unroll
  for (int i = 0; i < 4; ++i) {
    acc[i] *= sn_w[tid + 256 * i];
    ssq += acc[i] * acc[i];
  }
  for (int o = 32; o > 0; o >>= 1) ssq += __shfl_xor(ssq, o);
  int lane = tid & 63, w = tid >> 6;
  if (lane == 0) l4[w] = ssq;
  __syncthreads();
  float tot = l4[0] + l4[1] + l4[2] + l4[3];
  float r = rsqrtf(tot * (1.0f / D_DIM) + 1e-6f);
#pragma unroll
  for (int i = 0; i < 4; ++i)
    O[(size_t)b * D_DIM + tid + 256 * i] = acc[i] * r * on_w[tid + 256 * i];
}

}  // namespace

extern "C" void kernel_launch(void* const* d_in, const int* in_sizes, int n_in,
                              void* d_out, int out_size, void* d_ws, size_t ws_size,
                              hipStream_t stream) {
  const float* X     = (const float*)d_in[0];
  const float* alpha = (const float*)d_in[1];
  const float* E     = (const float*)d_in[2];
  const float* Wq    = (const float*)d_in[3];
  const float* Wk    = (const float*)d_in[4];
  const float* xn_w  = (const float*)d_in[5];
  const float* sn_w  = (const float*)d_in[6];
  const float* on_w  = (const float*)d_in[7];
  float* O    = (float*)d_out;                          // [16][1024]
  float* Wout = (float*)d_out + (size_t)BATCH * D_DIM;  // [16][4096]

  char* ws = (char*)d_ws;
  size_t off = 0;
  auto alloc = [&](size_t bytes) {
    char* p = ws + off;
    off += (bytes + 255) & ~(size_t)255;
    return p;
  };
  unsigned short* QH  = (unsigned short*)alloc((size_t)MCH * D_DIM * 2);
  unsigned short* QL  = (unsigned short*)alloc((size_t)MCH * D_DIM * 2);
  unsigned short* KmH = (unsigned short*)alloc((size_t)NE * D_DIM * 2);
  unsigned short* KmL = (unsigned short*)alloc((size_t)NE * D_DIM * 2);
  unsigned short* WqH = (unsigned short*)alloc((size_t)D_DIM * D_DIM * 2);
  unsigned short* WqL = (unsigned short*)alloc((size_t)D_DIM * D_DIM * 2);
  unsigned short* WkH = (unsigned short*)alloc((size_t)D_DIM * D_DIM * 2);
  unsigned short* WkL = (unsigned short*)alloc((size_t)D_DIM * D_DIM * 2);
  unsigned short* cKH = (unsigned short*)alloc((size_t)4 * CAND * D_DIM * 2);
  unsigned short* cKL = (unsigned short*)alloc((size_t)4 * CAND * D_DIM * 2);
  float* rinvX = (float*)alloc((size_t)MX * 4);
  float* rinvE = (float*)alloc((size_t)NE * 4);
  unsigned* gmax  = (unsigned*)alloc((size_t)BATCH * NE * 4);
  unsigned* gmax2 = (unsigned*)alloc((size_t)4 * CAND * 4);
  int* candIdx = (int*)alloc((size_t)4 * CAND * 4);
  int* idx = (int*)alloc((size_t)BATCH * NE * 4);
  int* cnt = (int*)alloc((size_t)BATCH * 4);
  if (off > ws_size) return;  // needs ~62 MB scratch

  row_rinv_k<<<MX, 256, 0, stream>>>(X, rinvX);
  row_rinv_k<<<NE, 256, 0, stream>>>(E, rinvE);
  split_w_k<<<D_DIM, 256, 0, stream>>>(Wq, xn_w, WqH, WqL);
  split_w_k<<<D_DIM, 256, 0, stream>>>(Wk, sn_w, WkH, WkL);

  // Km = (E * rinvE) @ (Wk*sn_w)^T, split output
  gemm_a32_k<<<dim3(NE / 128, D_DIM / 128), 256, 0, stream>>>(E, rinvE, WkH, WkL, KmH, KmL);

  hipMemsetAsync(gmax, 0, (size_t)BATCH * NE * 4, stream);

  for (int ch = 0; ch < MX / MCH; ++ch) {
    long m0 = (long)ch * MCH;
    int b4 = ch * 4;  // chunk holds batches b4..b4+3 entirely (2048 | 8192)
    gemm_a32_k<<<dim3(MCH / 128, D_DIM / 128), 256, 0, stream>>>(
        X + m0 * D_DIM, rinvX + m0, WqH, WqL, QH, QL);
    gemm_scores1_k<<<dim3(MCH / 128, NE / 128), 256, 0, stream>>>(QH, KmH, gmax, b4);
    cand_select_k<<<4, 256, 0, stream>>>(gmax, b4, candIdx);
    gather_k<<<dim3(CAND, 4), 256, 0, stream>>>(KmH, KmL, candIdx, cKH, cKL);
    hipMemsetAsync(gmax2, 0, (size_t)4 * CAND * 4, stream);
    gemm_rescore_k<<<dim3(SEQ / 128, 1, 4), 256, 0, stream>>>(QH, QL, cKH, cKL, gmax2);
    scatter_k<<<4, CAND, 0, stream>>>(gmax2, candIdx, gmax, b4);
  }

  topk_weights_k<<<BATCH, 256, 0, stream>>>(gmax, alpha, Wout, idx, cnt);
  out_o_k<<<BATCH, 256, 0, stream>>>(Wout, E, rinvE, sn_w, on_w, alpha, idx, cnt, O);
}

// Round 5
// 836.174 us; speedup vs baseline: 1.4702x; 1.1423x over previous
//
#include <hip/hip_runtime.h>

// BasisAttention: B=16,S=2048,D=1024,N=4096,K_TOP=64. fp32 in/out.
// R2: XOR chunk-swizzle (conflicts 1.7e7 -> 0). R3 dbuf REVERTED.
// R4: approx(1-product bf16)-then-rescore(3-product) for scores/top-k.
// R5: associativity: scores = Xn @ (Km Wq)^T. Q-projection GEMMs eliminated;
//     P = Km@Wq (+xn_w col-fold) precomputed once, split to PH/PL.
//     Approx pass = bf16(X) @ PH^T with rinvX in epilogue; rescore splits
//     fp32 X on the fly. Fused rinv+split-X pass per chunk.

namespace {

constexpr int D_DIM = 1024;
constexpr int NE    = 4096;
constexpr int BATCH = 16;
constexpr int SEQ   = 2048;
constexpr int MX    = BATCH * SEQ;   // 32768
constexpr int MCH   = 8192;          // m-chunk (4 chunks, 4 batches each)
constexpr int KTOP  = 64;
constexpr int CAND  = 128;           // candidates per batch
constexpr int BK    = 32;

using f32x4  = __attribute__((ext_vector_type(4))) float;
using bf16x8 = __attribute__((ext_vector_type(8))) short;

__device__ inline unsigned encf(float f) {
  unsigned u = __float_as_uint(f);
  return (u & 0x80000000u) ? ~u : (u | 0x80000000u);
}
__device__ inline float decf(unsigned e) {
  unsigned u = (e & 0x80000000u) ? (e ^ 0x80000000u) : ~e;
  return __uint_as_float(u);
}

__device__ inline unsigned short f2bf(float f) {  // RNE float->bf16 bits
  unsigned u = __float_as_uint(f);
  unsigned lsb = (u >> 16) & 1u;
  u += 0x7fffu + lsb;
  return (unsigned short)(u >> 16);
}
__device__ inline float bf2f(unsigned short h) {
  return __uint_as_float(((unsigned)h) << 16);
}

__device__ inline void gload16(const void* gsrc, void* ldst) {
  __builtin_amdgcn_global_load_lds(
      (const __attribute__((address_space(1))) unsigned int*)gsrc,
      (__attribute__((address_space(3))) unsigned int*)ldst, 16, 0, 0);
}

// ---------------- K1: per-row rsqrt(mean(x^2)+eps) ----------------
__global__ void row_rinv_k(const float* __restrict__ X, float* __restrict__ rinv) {
  __shared__ float l4[4];
  int row = blockIdx.x;
  float4 v = ((const float4*)(X + (size_t)row * D_DIM))[threadIdx.x];
  float ss = v.x * v.x + v.y * v.y + v.z * v.z + v.w * v.w;
  for (int o = 32; o > 0; o >>= 1) ss += __shfl_xor(ss, o);
  int lane = threadIdx.x & 63, w = threadIdx.x >> 6;
  if (lane == 0) l4[w] = ss;
  __syncthreads();
  if (threadIdx.x == 0) {
    float t = l4[0] + l4[1] + l4[2] + l4[3];
    rinv[row] = rsqrtf(t * (1.0f / D_DIM) + 1e-6f);
  }
}

// ---------------- K1a: fused per-row rinv + bf16 split of X (hi only) ----------------
__global__ void rinv_splitx_k(const float* __restrict__ X, float* __restrict__ rinv,
                              unsigned short* __restrict__ XH) {
  __shared__ float l4[4];
  int row = blockIdx.x;
  float4 v = ((const float4*)(X + (size_t)row * D_DIM))[threadIdx.x];
  float ss = v.x * v.x + v.y * v.y + v.z * v.z + v.w * v.w;
  for (int o = 32; o > 0; o >>= 1) ss += __shfl_xor(ss, o);
  int lane = threadIdx.x & 63, w = threadIdx.x >> 6;
  if (lane == 0) l4[w] = ss;
  __syncthreads();
  if (threadIdx.x == 0) {
    float t = l4[0] + l4[1] + l4[2] + l4[3];
    rinv[row] = rsqrtf(t * (1.0f / D_DIM) + 1e-6f);
  }
  ushort4 h = make_ushort4(f2bf(v.x), f2bf(v.y), f2bf(v.z), f2bf(v.w));
  *(ushort4*)(XH + (size_t)row * D_DIM + threadIdx.x * 4) = h;
}

// ---------------- K1b: split W[n,k]*cw[k] into bf16 hi/lo ----------------
__global__ void split_w_k(const float* __restrict__ W, const float* __restrict__ cw,
                          unsigned short* __restrict__ H, unsigned short* __restrict__ L) {
  int row = blockIdx.x;
  int c0 = threadIdx.x * 4;
  float4 wv = *(const float4*)(W + (size_t)row * D_DIM + c0);
  float4 cv = *(const float4*)(cw + c0);
  float y[4] = {wv.x * cv.x, wv.y * cv.y, wv.z * cv.z, wv.w * cv.w};
  unsigned short h[4], l[4];
#pragma unroll
  for (int i = 0; i < 4; ++i) {
    h[i] = f2bf(y[i]);
    l[i] = f2bf(y[i] - bf2f(h[i]));
  }
  *(ushort4*)(H + (size_t)row * D_DIM + c0) = make_ushort4(h[0], h[1], h[2], h[3]);
  *(ushort4*)(L + (size_t)row * D_DIM + c0) = make_ushort4(l[0], l[1], l[2], l[3]);
}

// ---------------- K1c: transpose-split: out[k][d] = Wq[d][k]*cw[k] ----------------
__global__ void split_wt_k(const float* __restrict__ W, const float* __restrict__ cw,
                           unsigned short* __restrict__ H, unsigned short* __restrict__ L) {
  __shared__ float t[32][33];
  int k0 = blockIdx.x * 32, d0 = blockIdx.y * 32;
  int tx = threadIdx.x & 31, ty4 = (threadIdx.x >> 5) * 4;
#pragma unroll
  for (int i = 0; i < 4; ++i)
    t[ty4 + i][tx] = W[(size_t)(d0 + ty4 + i) * D_DIM + k0 + tx];
  __syncthreads();
#pragma unroll
  for (int i = 0; i < 4; ++i) {
    int a = ty4 + i;                       // local k
    float v = t[tx][a] * cw[k0 + a];       // W[d0+tx][k0+a]*cw
    unsigned short h = f2bf(v);
    H[(size_t)(k0 + a) * D_DIM + d0 + tx] = h;
    L[(size_t)(k0 + a) * D_DIM + d0 + tx] = f2bf(v - bf2f(h));
  }
}

// ---------------- K2: O = rowscale(A_f32) @ B(hi,lo)^T (3-product) ----------------
// FPOUT=0: split bf16 hi/lo output; FPOUT=1: fp32 output.
template <int FPOUT>
__global__ __launch_bounds__(256, 2) void gemm_a32_k(
    const float* __restrict__ A, const float* __restrict__ rinv,
    const unsigned short* __restrict__ BH, const unsigned short* __restrict__ BL,
    unsigned short* __restrict__ OH, unsigned short* __restrict__ OL,
    float* __restrict__ Of) {
  __shared__ __align__(16) float lA[128 * 32];        // XOR-swizzled (16B chunks)
  __shared__ __align__(16) unsigned short lBH[128 * 32];
  __shared__ __align__(16) unsigned short lBL[128 * 32];
  __shared__ float ldsR[128];

  int tid = threadIdx.x;
  int lane = tid & 63, wid = tid >> 6;
  int wr = wid >> 1, wc = wid & 1;
  int fr = lane & 15, fg = lane >> 4;
  long m0 = (long)blockIdx.x * 128;
  long n0 = (long)blockIdx.y * 128;

  if (tid < 128) ldsR[tid] = rinv ? rinv[m0 + tid] : 1.0f;

  f32x4 acc[4][4] = {};

  for (int kk = 0; kk < D_DIM; kk += BK) {
#pragma unroll
    for (int i = 0; i < 4; ++i) {
      int chunk = i * 256 + tid;
      int r = chunk >> 3, c = chunk & 7;
      int cs = c ^ (r & 7);
      const float* src = A + (m0 + r) * (long)D_DIM + kk + cs * 4;
      gload16(src, (void*)(lA + ((i * 256 + (tid & ~63)) << 2)));
    }
#pragma unroll
    for (int i = 0; i < 2; ++i) {
      int chunk = i * 256 + tid;
      int r = chunk >> 2, c = chunk & 3;
      int cs = c ^ ((r >> 1) & 3);
      long boff = (n0 + r) * (long)D_DIM + kk + cs * 8;
      int lo = (i * 256 + (tid & ~63)) << 3;
      gload16(BH + boff, (void*)(lBH + lo));
      gload16(BL + boff, (void*)(lBL + lo));
    }
    __syncthreads();

    bf16x8 aH[4], aL[4], bH[4], bL[4];
#pragma unroll
    for (int m = 0; m < 4; ++m) {
      int row = wr * 64 + m * 16 + fr;
      int rm = row & 7;
      f32x4 p0 = *(const f32x4*)(lA + row * 32 + (((fg * 2 + 0) ^ rm) * 4));
      f32x4 p1 = *(const f32x4*)(lA + row * 32 + (((fg * 2 + 1) ^ rm) * 4));
#pragma unroll
      for (int e = 0; e < 8; ++e) {
        float f = (e < 4) ? p0[e] : p1[e - 4];
        unsigned short h = f2bf(f);
        aH[m][e] = (short)h;
        aL[m][e] = (short)f2bf(f - bf2f(h));
      }
    }
#pragma unroll
    for (int n = 0; n < 4; ++n) {
      int row = wc * 64 + n * 16 + fr;
      int sc = fg ^ ((row >> 1) & 3);
      bH[n] = *(const bf16x8*)(lBH + row * 32 + sc * 8);
      bL[n] = *(const bf16x8*)(lBL + row * 32 + sc * 8);
    }
#pragma unroll
    for (int m = 0; m < 4; ++m)
#pragma unroll
      for (int n = 0; n < 4; ++n) {
        acc[m][n] = __builtin_amdgcn_mfma_f32_16x16x32_bf16(aH[m], bH[n], acc[m][n], 0, 0, 0);
        acc[m][n] = __builtin_amdgcn_mfma_f32_16x16x32_bf16(aH[m], bL[n], acc[m][n], 0, 0, 0);
        acc[m][n] = __builtin_amdgcn_mfma_f32_16x16x32_bf16(aL[m], bH[n], acc[m][n], 0, 0, 0);
      }
    __syncthreads();
  }

  // epilogue: scale by rinv[row]; store split bf16 or fp32.
  // C/D layout (m89-verified): col = lane&15, row = (lane>>4)*4 + j
#pragma unroll
  for (int m = 0; m < 4; ++m) {
#pragma unroll
    for (int j = 0; j < 4; ++j) {
      int rloc = wr * 64 + m * 16 + fg * 4 + j;
      float rv = ldsR[rloc];
      long grow = m0 + rloc;
#pragma unroll
      for (int n = 0; n < 4; ++n) {
        long gcol = n0 + wc * 64 + n * 16 + fr;
        float v = acc[m][n][j] * rv;
        if (FPOUT) {
          Of[grow * D_DIM + gcol] = v;
        } else {
          unsigned short h = f2bf(v);
          OH[grow * D_DIM + gcol] = h;
          OL[grow * D_DIM + gcol] = f2bf(v - bf2f(h));
        }
      }
    }
  }
}

// ---------------- K3a: APPROX scores XH @ PH^T + rowscale + col-max ----------------
__global__ __launch_bounds__(256, 2) void gemm_scores1_k(
    const unsigned short* __restrict__ XH, const unsigned short* __restrict__ PH,
    const float* __restrict__ rinvA, unsigned* __restrict__ gmax, int b_base) {
  __shared__ __align__(16) unsigned short lAH[128 * 32];
  __shared__ __align__(16) unsigned short lBH[128 * 32];
  __shared__ float ldsR[128];

  int tid = threadIdx.x;
  int lane = tid & 63, wid = tid >> 6;
  int wr = wid >> 1, wc = wid & 1;
  int fr = lane & 15, fg = lane >> 4;
  long m0 = (long)blockIdx.x * 128;
  long n0 = (long)blockIdx.y * 128;

  if (tid < 128) ldsR[tid] = rinvA[m0 + tid];

  f32x4 acc[4][4] = {};

  for (int kk = 0; kk < D_DIM; kk += BK) {
#pragma unroll
    for (int i = 0; i < 2; ++i) {
      int chunk = i * 256 + tid;
      int r = chunk >> 2, c = chunk & 3;
      int cs = c ^ ((r >> 1) & 3);
      long aoff = (m0 + r) * (long)D_DIM + kk + cs * 8;
      long boff = (n0 + r) * (long)D_DIM + kk + cs * 8;
      int lo = (i * 256 + (tid & ~63)) << 3;
      gload16(XH + aoff, (void*)(lAH + lo));
      gload16(PH + boff, (void*)(lBH + lo));
    }
    __syncthreads();

    bf16x8 aH[4], bH[4];
#pragma unroll
    for (int m = 0; m < 4; ++m) {
      int row = wr * 64 + m * 16 + fr;
      int sc = fg ^ ((row >> 1) & 3);
      aH[m] = *(const bf16x8*)(lAH + row * 32 + sc * 8);
    }
#pragma unroll
    for (int n = 0; n < 4; ++n) {
      int row = wc * 64 + n * 16 + fr;
      int sc = fg ^ ((row >> 1) & 3);
      bH[n] = *(const bf16x8*)(lBH + row * 32 + sc * 8);
    }
#pragma unroll
    for (int m = 0; m < 4; ++m)
#pragma unroll
      for (int n = 0; n < 4; ++n)
        acc[m][n] = __builtin_amdgcn_mfma_f32_16x16x32_bf16(aH[m], bH[n], acc[m][n], 0, 0, 0);
    __syncthreads();
  }

  int b = b_base + (int)(m0 >> 11);
#pragma unroll
  for (int n = 0; n < 4; ++n) {
    float v = -3.0e38f;
#pragma unroll
    for (int m = 0; m < 4; ++m)
#pragma unroll
      for (int j = 0; j < 4; ++j) {
        float rv = ldsR[wr * 64 + m * 16 + fg * 4 + j];
        v = fmaxf(v, acc[m][n][j] * rv);
      }
    v = fmaxf(v, __shfl_xor(v, 16));
    v = fmaxf(v, __shfl_xor(v, 32));
    if (fg == 0) {
      long col = n0 + wc * 64 + n * 16 + fr;
      atomicMax(&gmax[(long)b * NE + col], encf(v * 0.03125f));
    }
  }
}

// ---------------- K3b: per-batch top-CAND candidate selection (+ zero gmax2) ----------------
__global__ void cand_select_k(const unsigned* __restrict__ gmax, int b_base,
                              int* __restrict__ candIdx, unsigned* __restrict__ gmax2) {
  __shared__ unsigned enc[NE];
  __shared__ int ic[257];
  int tid = threadIdx.x;
  int lane = tid & 63, w = tid >> 6;
  int z = blockIdx.x;
  if (tid < CAND) gmax2[z * CAND + tid] = 0u;
  const unsigned* g = gmax + (size_t)(b_base + z) * NE;
  for (int i = tid; i < NE; i += 256) enc[i] = g[i];
  __syncthreads();

  unsigned cur = 0;
  for (int bit = 31; bit >= 0; --bit) {
    unsigned cand = cur | (1u << bit);
    int c = 0;
    for (int i = tid; i < NE; i += 256) c += (enc[i] >= cand) ? 1 : 0;
    for (int o = 32; o > 0; o >>= 1) c += __shfl_xor(c, o);
    __syncthreads();
    if (lane == 0) ic[w] = c;
    __syncthreads();
    int tot = ic[0] + ic[1] + ic[2] + ic[3];
    if (tot >= CAND) cur = cand;
  }

  int myc = 0;
  for (int i = tid; i < NE; i += 256) myc += (enc[i] >= cur) ? 1 : 0;
  __syncthreads();
  ic[tid] = myc;
  __syncthreads();
  if (tid == 0) {
    int s = 0;
    for (int t = 0; t < 256; ++t) { int v = ic[t]; ic[t] = s; s += v; }
  }
  __syncthreads();
  int off = ic[tid];
  for (int i = tid; i < NE; i += 256)
    if (enc[i] >= cur) {
      if (off < CAND) candIdx[z * CAND + off] = i;
      ++off;
    }
}

// ---------------- K3c: gather candidate P rows ----------------
__global__ void gather_k(const unsigned short* __restrict__ PH,
                         const unsigned short* __restrict__ PL,
                         const int* __restrict__ candIdx,
                         unsigned short* __restrict__ cPH,
                         unsigned short* __restrict__ cPL) {
  int j = blockIdx.x, z = blockIdx.y;
  int n = candIdx[z * CAND + j];
  int t4 = threadIdx.x * 4;
  size_t dst = ((size_t)(z * CAND + j)) * D_DIM + t4;
  size_t src = (size_t)n * D_DIM + t4;
  *(ushort4*)(cPH + dst) = *(const ushort4*)(PH + src);
  *(ushort4*)(cPL + dst) = *(const ushort4*)(PL + src);
}

// ---------------- K3d: EXACT rescore: rowscale(X_f32) @ cP(hi,lo)^T ----------------
// grid (SEQ/128, 1, 4): z = batch within chunk.
__global__ __launch_bounds__(256, 2) void gemm_rescore_k(
    const float* __restrict__ Xc, const float* __restrict__ rinvA,
    const unsigned short* __restrict__ cPH, const unsigned short* __restrict__ cPL,
    unsigned* __restrict__ gmax2) {
  __shared__ __align__(16) float lA[128 * 32];
  __shared__ __align__(16) unsigned short lBH[128 * 32], lBL[128 * 32];
  __shared__ float ldsR[128];

  int tid = threadIdx.x;
  int lane = tid & 63, wid = tid >> 6;
  int wr = wid >> 1, wc = wid & 1;
  int fr = lane & 15, fg = lane >> 4;
  int z = blockIdx.z;
  long m0 = (long)blockIdx.x * 128;
  long arow0 = (long)z * SEQ + m0;
  long brow0 = (long)z * CAND;

  if (tid < 128) ldsR[tid] = rinvA[arow0 + tid];

  f32x4 acc[4][4] = {};

  for (int kk = 0; kk < D_DIM; kk += BK) {
#pragma unroll
    for (int i = 0; i < 4; ++i) {
      int chunk = i * 256 + tid;
      int r = chunk >> 3, c = chunk & 7;
      int cs = c ^ (r & 7);
      const float* src = Xc + (arow0 + r) * (long)D_DIM + kk + cs * 4;
      gload16(src, (void*)(lA + ((i * 256 + (tid & ~63)) << 2)));
    }
#pragma unroll
    for (int i = 0; i < 2; ++i) {
      int chunk = i * 256 + tid;
      int r = chunk >> 2, c = chunk & 3;
      int cs = c ^ ((r >> 1) & 3);
      long boff = (brow0 + r) * (long)D_DIM + kk + cs * 8;
      int lo = (i * 256 + (tid & ~63)) << 3;
      gload16(cPH + boff, (void*)(lBH + lo));
      gload16(cPL + boff, (void*)(lBL + lo));
    }
    __syncthreads();

    bf16x8 aH[4], aL[4], bH[4], bL[4];
#pragma unroll
    for (int m = 0; m < 4; ++m) {
      int row = wr * 64 + m * 16 + fr;
      int rm = row & 7;
      f32x4 p0 = *(const f32x4*)(lA + row * 32 + (((fg * 2 + 0) ^ rm) * 4));
      f32x4 p1 = *(const f32x4*)(lA + row * 32 + (((fg * 2 + 1) ^ rm) * 4));
#pragma unroll
      for (int e = 0; e < 8; ++e) {
        float f = (e < 4) ? p0[e] : p1[e - 4];
        unsigned short h = f2bf(f);
        aH[m][e] = (short)h;
        aL[m][e] = (short)f2bf(f - bf2f(h));
      }
    }
#pragma unroll
    for (int n = 0; n < 4; ++n) {
      int row = wc * 64 + n * 16 + fr;
      int sc = fg ^ ((row >> 1) & 3);
      bH[n] = *(const bf16x8*)(lBH + row * 32 + sc * 8);
      bL[n] = *(const bf16x8*)(lBL + row * 32 + sc * 8);
    }
#pragma unroll
    for (int m = 0; m < 4; ++m)
#pragma unroll
      for (int n = 0; n < 4; ++n) {
        acc[m][n] = __builtin_amdgcn_mfma_f32_16x16x32_bf16(aH[m], bH[n], acc[m][n], 0, 0, 0);
        acc[m][n] = __builtin_amdgcn_mfma_f32_16x16x32_bf16(aH[m], bL[n], acc[m][n], 0, 0, 0);
        acc[m][n] = __builtin_amdgcn_mfma_f32_16x16x32_bf16(aL[m], bH[n], acc[m][n], 0, 0, 0);
      }
    __syncthreads();
  }

#pragma unroll
  for (int n = 0; n < 4; ++n) {
    float v = -3.0e38f;
#pragma unroll
    for (int m = 0; m < 4; ++m)
#pragma unroll
      for (int j = 0; j < 4; ++j) {
        float rv = ldsR[wr * 64 + m * 16 + fg * 4 + j];
        v = fmaxf(v, acc[m][n][j] * rv);
      }
    v = fmaxf(v, __shfl_xor(v, 16));
    v = fmaxf(v, __shfl_xor(v, 32));
    if (fg == 0) {
      int col = wc * 64 + n * 16 + fr;   // 0..127
      atomicMax(&gmax2[z * CAND + col], encf(v * 0.03125f));
    }
  }
}

// ---------------- K3e: scatter exact candidate values over approx gmax ----------------
__global__ void scatter_k(const unsigned* __restrict__ gmax2,
                          const int* __restrict__ candIdx,
                          unsigned* __restrict__ gmax, int b_base) {
  int z = blockIdx.x, j = threadIdx.x;
  int n = candIdx[z * CAND + j];
  gmax[(size_t)(b_base + z) * NE + n] = gmax2[z * CAND + j];
}

// ---------------- K4: per-batch exact top-64 cutoff + softmax weights ----------------
__global__ void topk_weights_k(const unsigned* __restrict__ gmax,
                               const float* __restrict__ alpha_p,
                               float* __restrict__ wout, int* __restrict__ idx,
                               int* __restrict__ cnt) {
  __shared__ unsigned enc[NE];
  __shared__ unsigned ubc[4];
  __shared__ float l4[4];
  __shared__ int ic[257];
  int tid = threadIdx.x;
  int lane = tid & 63, w = tid >> 6;
  const unsigned* g = gmax + (size_t)blockIdx.x * NE;
  for (int i = tid; i < NE; i += 256) enc[i] = g[i];
  __syncthreads();

  unsigned mx = 0;
  for (int i = tid; i < NE; i += 256) mx = enc[i] > mx ? enc[i] : mx;
  for (int o = 32; o > 0; o >>= 1) {
    unsigned other = (unsigned)__shfl_xor((int)mx, o);
    if (other > mx) mx = other;
  }
  if (lane == 0) ubc[w] = mx;
  __syncthreads();
  unsigned m1e = ubc[0];
  for (int t = 1; t < 4; ++t) m1e = ubc[t] > m1e ? ubc[t] : m1e;
  float m1 = decf(m1e);

  unsigned cur = 0;
  for (int bit = 31; bit >= 0; --bit) {
    unsigned cand = cur | (1u << bit);
    int c = 0;
    for (int i = tid; i < NE; i += 256) c += (enc[i] >= cand) ? 1 : 0;
    for (int o = 32; o > 0; o >>= 1) c += __shfl_xor(c, o);
    __syncthreads();
    if (lane == 0) ic[w] = c;
    __syncthreads();
    int tot = ic[0] + ic[1] + ic[2] + ic[3];
    if (tot >= KTOP) cur = cand;
  }

  float sd = 0.f, ssum = 0.f;
  for (int i = tid; i < NE; i += 256) {
    float e = expf(decf(enc[i]) - m1);
    sd += e;
    if (enc[i] >= cur) ssum += e;
  }
  for (int o = 32; o > 0; o >>= 1) { sd += __shfl_xor(sd, o); ssum += __shfl_xor(ssum, o); }
  __syncthreads();
  if (lane == 0) { l4[w] = sd; }
  __syncthreads();
  float SD = l4[0] + l4[1] + l4[2] + l4[3];
  __syncthreads();
  if (lane == 0) { l4[w] = ssum; }
  __syncthreads();
  float SS = l4[0] + l4[1] + l4[2] + l4[3];

  float alpha = alpha_p[0];
  float wd = alpha / SD;
  float ws_ = (1.0f - alpha) / SS;
  for (int i = tid; i < NE; i += 256) {
    float e = expf(decf(enc[i]) - m1);
    float wv = wd * e + ((enc[i] >= cur) ? ws_ * e : 0.0f);
    wout[(size_t)blockIdx.x * NE + i] = wv;
  }

  int myc = 0;
  for (int i = tid; i < NE; i += 256) myc += (enc[i] >= cur) ? 1 : 0;
  __syncthreads();
  ic[tid] = myc;
  __syncthreads();
  if (tid == 0) {
    int s = 0;
    for (int t = 0; t < 256; ++t) { int v = ic[t]; ic[t] = s; s += v; }
    ic[256] = s;
    cnt[blockIdx.x] = s;
  }
  __syncthreads();
  int off = ic[tid];
  for (int i = tid; i < NE; i += 256)
    if (enc[i] >= cur) idx[(size_t)blockIdx.x * NE + (off++)] = i;
}

// ---------------- K5: O = rmsnorm(weights @ En, on_w) ----------------
__global__ void out_o_k(const float* __restrict__ wts, const float* __restrict__ E,
                        const float* __restrict__ rinvE, const float* __restrict__ sn_w,
                        const float* __restrict__ on_w, const float* __restrict__ alpha_p,
                        const int* __restrict__ idx, const int* __restrict__ cnt,
                        float* __restrict__ O) {
  __shared__ float l4[4];
  int b = blockIdx.x, tid = threadIdx.x;
  float acc[4] = {0.f, 0.f, 0.f, 0.f};
  float alpha = alpha_p[0];
  if (alpha == 0.0f) {
    int nsel = cnt[b];
    for (int j = 0; j < nsel; ++j) {
      int n = idx[(size_t)b * NE + j];
      float wv = wts[(size_t)b * NE + n] * rinvE[n];
      const float* er = E + (size_t)n * D_DIM;
#pragma unroll
      for (int i = 0; i < 4; ++i) acc[i] += wv * er[tid + 256 * i];
    }
  } else {
    for (int n = 0; n < NE; ++n) {
      float wv = wts[(size_t)b * NE + n] * rinvE[n];
      const float* er = E + (size_t)n * D_DIM;
#pragma unroll
      for (int i = 0; i < 4; ++i) acc[i] += wv * er[tid + 256 * i];
    }
  }
  float ssq = 0.f;
#pragma unroll
  for (int i = 0; i < 4; ++i) {
    acc[i] *= sn_w[tid + 256 * i];
    ssq += acc[i] * acc[i];
  }
  for (int o = 32; o > 0; o >>= 1) ssq += __shfl_xor(ssq, o);
  int lane = tid & 63, w = tid >> 6;
  if (lane == 0) l4[w] = ssq;
  __syncthreads();
  float tot = l4[0] + l4[1] + l4[2] + l4[3];
  float r = rsqrtf(tot * (1.0f / D_DIM) + 1e-6f);
#pragma unroll
  for (int i = 0; i < 4; ++i)
    O[(size_t)b * D_DIM + tid + 256 * i] = acc[i] * r * on_w[tid + 256 * i];
}

}  // namespace

extern "C" void kernel_launch(void* const* d_in, const int* in_sizes, int n_in,
                              void* d_out, int out_size, void* d_ws, size_t ws_size,
                              hipStream_t stream) {
  const float* X     = (const float*)d_in[0];
  const float* alpha = (const float*)d_in[1];
  const float* E     = (const float*)d_in[2];
  const float* Wq    = (const float*)d_in[3];
  const float* Wk    = (const float*)d_in[4];
  const float* xn_w  = (const float*)d_in[5];
  const float* sn_w  = (const float*)d_in[6];
  const float* on_w  = (const float*)d_in[7];
  float* O    = (float*)d_out;                          // [16][1024]
  float* Wout = (float*)d_out + (size_t)BATCH * D_DIM;  // [16][4096]

  char* ws = (char*)d_ws;
  size_t off = 0;
  auto alloc = [&](size_t bytes) {
    char* p = ws + off;
    off += (bytes + 255) & ~(size_t)255;
    return p;
  };
  unsigned short* XH   = (unsigned short*)alloc((size_t)MCH * D_DIM * 2);   // per-chunk
  float*          Kmf  = (float*)alloc((size_t)NE * D_DIM * 4);
  unsigned short* PH   = (unsigned short*)alloc((size_t)NE * D_DIM * 2);
  unsigned short* PL   = (unsigned short*)alloc((size_t)NE * D_DIM * 2);
  unsigned short* WkH  = (unsigned short*)alloc((size_t)D_DIM * D_DIM * 2);
  unsigned short* WkL  = (unsigned short*)alloc((size_t)D_DIM * D_DIM * 2);
  unsigned short* WqTH = (unsigned short*)alloc((size_t)D_DIM * D_DIM * 2);
  unsigned short* WqTL = (unsigned short*)alloc((size_t)D_DIM * D_DIM * 2);
  unsigned short* cPH  = (unsigned short*)alloc((size_t)4 * CAND * D_DIM * 2);
  unsigned short* cPL  = (unsigned short*)alloc((size_t)4 * CAND * D_DIM * 2);
  float* rinvX = (float*)alloc((size_t)MX * 4);
  float* rinvE = (float*)alloc((size_t)NE * 4);
  unsigned* gmax  = (unsigned*)alloc((size_t)BATCH * NE * 4);
  unsigned* gmax2 = (unsigned*)alloc((size_t)4 * CAND * 4);
  int* candIdx = (int*)alloc((size_t)4 * CAND * 4);
  int* idx = (int*)alloc((size_t)BATCH * NE * 4);
  int* cnt = (int*)alloc((size_t)BATCH * 4);
  if (off > ws_size) return;  // needs ~55 MB scratch

  row_rinv_k<<<NE, 256, 0, stream>>>(E, rinvE);
  split_w_k<<<D_DIM, 256, 0, stream>>>(Wk, sn_w, WkH, WkL);
  split_wt_k<<<dim3(D_DIM / 32, D_DIM / 32), 256, 0, stream>>>(Wq, xn_w, WqTH, WqTL);

  // Km = (E*rinvE) @ (Wk*sn_w)^T  (fp32 out)
  gemm_a32_k<1><<<dim3(NE / 128, D_DIM / 128), 256, 0, stream>>>(
      E, rinvE, WkH, WkL, nullptr, nullptr, Kmf);
  // P' = Km @ WqT'^T  where WqT'[k,d] = Wq[d,k]*xn_w[k]  (split out)
  gemm_a32_k<0><<<dim3(NE / 128, D_DIM / 128), 256, 0, stream>>>(
      Kmf, nullptr, WqTH, WqTL, PH, PL, nullptr);

  hipMemsetAsync(gmax, 0, (size_t)BATCH * NE * 4, stream);

  for (int ch = 0; ch < MX / MCH; ++ch) {
    long m0 = (long)ch * MCH;
    int b4 = ch * 4;  // chunk holds batches b4..b4+3 entirely (2048 | 8192)
    const float* Xc = X + m0 * D_DIM;
    float* rXc = rinvX + m0;
    rinv_splitx_k<<<MCH, 256, 0, stream>>>(Xc, rXc, XH);
    gemm_scores1_k<<<dim3(MCH / 128, NE / 128), 256, 0, stream>>>(XH, PH, rXc, gmax, b4);
    cand_select_k<<<4, 256, 0, stream>>>(gmax, b4, candIdx, gmax2);
    gather_k<<<dim3(CAND, 4), 256, 0, stream>>>(PH, PL, candIdx, cPH, cPL);
    gemm_rescore_k<<<dim3(SEQ / 128, 1, 4), 256, 0, stream>>>(Xc, rXc, cPH, cPL, gmax2);
    scatter_k<<<4, CAND, 0, stream>>>(gmax2, candIdx, gmax, b4);
  }

  topk_weights_k<<<BATCH, 256, 0, stream>>>(gmax, alpha, Wout, idx, cnt);
  out_o_k<<<BATCH, 256, 0, stream>>>(Wout, E, rinvE, sn_w, on_w, alpha, idx, cnt, O);
}

// Round 6
// 696.928 us; speedup vs baseline: 1.7640x; 1.1998x over previous
//
#include <hip/hip_runtime.h>

// BasisAttention: B=16,S=2048,D=1024,N=4096,K_TOP=64. fp32 in/out.
// R2: XOR chunk-swizzle (conflicts 1.7e7 -> 0). R3 dbuf REVERTED.
// R4: approx(1-product bf16)-then-rescore(3-product) for scores/top-k.
// R5: scores = Xn @ (Km Wq)^T; Q-projection eliminated via associativity.
// R6: scores1 gets a counted-vmcnt 2-deep pipeline (3 LDS bufs, raw
//     s_barrier + s_waitcnt vmcnt(8), never drain-to-0 in loop);
//     rescore merged into ONE full-GPU dispatch at the end.

namespace {

constexpr int D_DIM = 1024;
constexpr int NE    = 4096;
constexpr int BATCH = 16;
constexpr int SEQ   = 2048;
constexpr int MX    = BATCH * SEQ;   // 32768
constexpr int MCH   = 8192;          // m-chunk (4 chunks, 4 batches each)
constexpr int KTOP  = 64;
constexpr int CAND  = 128;           // candidates per batch
constexpr int BK    = 32;
constexpr int NT    = D_DIM / BK;    // 32 K-steps

using f32x4  = __attribute__((ext_vector_type(4))) float;
using bf16x8 = __attribute__((ext_vector_type(8))) short;

__device__ inline unsigned encf(float f) {
  unsigned u = __float_as_uint(f);
  return (u & 0x80000000u) ? ~u : (u | 0x80000000u);
}
__device__ inline float decf(unsigned e) {
  unsigned u = (e & 0x80000000u) ? (e ^ 0x80000000u) : ~e;
  return __uint_as_float(u);
}

__device__ inline unsigned short f2bf(float f) {  // RNE float->bf16 bits
  unsigned u = __float_as_uint(f);
  unsigned lsb = (u >> 16) & 1u;
  u += 0x7fffu + lsb;
  return (unsigned short)(u >> 16);
}
__device__ inline float bf2f(unsigned short h) {
  return __uint_as_float(((unsigned)h) << 16);
}

__device__ inline void gload16(const void* gsrc, void* ldst) {
  __builtin_amdgcn_global_load_lds(
      (const __attribute__((address_space(1))) unsigned int*)gsrc,
      (__attribute__((address_space(3))) unsigned int*)ldst, 16, 0, 0);
}

// ---------------- K1: per-row rsqrt(mean(x^2)+eps) ----------------
__global__ void row_rinv_k(const float* __restrict__ X, float* __restrict__ rinv) {
  __shared__ float l4[4];
  int row = blockIdx.x;
  float4 v = ((const float4*)(X + (size_t)row * D_DIM))[threadIdx.x];
  float ss = v.x * v.x + v.y * v.y + v.z * v.z + v.w * v.w;
  for (int o = 32; o > 0; o >>= 1) ss += __shfl_xor(ss, o);
  int lane = threadIdx.x & 63, w = threadIdx.x >> 6;
  if (lane == 0) l4[w] = ss;
  __syncthreads();
  if (threadIdx.x == 0) {
    float t = l4[0] + l4[1] + l4[2] + l4[3];
    rinv[row] = rsqrtf(t * (1.0f / D_DIM) + 1e-6f);
  }
}

// ---------------- K1a: fused per-row rinv + bf16(X) ----------------
__global__ void rinv_splitx_k(const float* __restrict__ X, float* __restrict__ rinv,
                              unsigned short* __restrict__ XH) {
  __shared__ float l4[4];
  int row = blockIdx.x;
  float4 v = ((const float4*)(X + (size_t)row * D_DIM))[threadIdx.x];
  float ss = v.x * v.x + v.y * v.y + v.z * v.z + v.w * v.w;
  for (int o = 32; o > 0; o >>= 1) ss += __shfl_xor(ss, o);
  int lane = threadIdx.x & 63, w = threadIdx.x >> 6;
  if (lane == 0) l4[w] = ss;
  __syncthreads();
  if (threadIdx.x == 0) {
    float t = l4[0] + l4[1] + l4[2] + l4[3];
    rinv[row] = rsqrtf(t * (1.0f / D_DIM) + 1e-6f);
  }
  ushort4 h = make_ushort4(f2bf(v.x), f2bf(v.y), f2bf(v.z), f2bf(v.w));
  *(ushort4*)(XH + (size_t)row * D_DIM + threadIdx.x * 4) = h;
}

// ---------------- K1b: split W[n,k]*cw[k] into bf16 hi/lo ----------------
__global__ void split_w_k(const float* __restrict__ W, const float* __restrict__ cw,
                          unsigned short* __restrict__ H, unsigned short* __restrict__ L) {
  int row = blockIdx.x;
  int c0 = threadIdx.x * 4;
  float4 wv = *(const float4*)(W + (size_t)row * D_DIM + c0);
  float4 cv = *(const float4*)(cw + c0);
  float y[4] = {wv.x * cv.x, wv.y * cv.y, wv.z * cv.z, wv.w * cv.w};
  unsigned short h[4], l[4];
#pragma unroll
  for (int i = 0; i < 4; ++i) {
    h[i] = f2bf(y[i]);
    l[i] = f2bf(y[i] - bf2f(h[i]));
  }
  *(ushort4*)(H + (size_t)row * D_DIM + c0) = make_ushort4(h[0], h[1], h[2], h[3]);
  *(ushort4*)(L + (size_t)row * D_DIM + c0) = make_ushort4(l[0], l[1], l[2], l[3]);
}

// ---------------- K1c: transpose-split: out[k][d] = Wq[d][k]*cw[k] ----------------
__global__ void split_wt_k(const float* __restrict__ W, const float* __restrict__ cw,
                           unsigned short* __restrict__ H, unsigned short* __restrict__ L) {
  __shared__ float t[32][33];
  int k0 = blockIdx.x * 32, d0 = blockIdx.y * 32;
  int tx = threadIdx.x & 31, ty4 = (threadIdx.x >> 5) * 4;
#pragma unroll
  for (int i = 0; i < 4; ++i)
    t[ty4 + i][tx] = W[(size_t)(d0 + ty4 + i) * D_DIM + k0 + tx];
  __syncthreads();
#pragma unroll
  for (int i = 0; i < 4; ++i) {
    int a = ty4 + i;                       // local k
    float v = t[tx][a] * cw[k0 + a];       // W[d0+tx][k0+a]*cw
    unsigned short h = f2bf(v);
    H[(size_t)(k0 + a) * D_DIM + d0 + tx] = h;
    L[(size_t)(k0 + a) * D_DIM + d0 + tx] = f2bf(v - bf2f(h));
  }
}

// ---------------- K2: O = rowscale(A_f32) @ B(hi,lo)^T (3-product) ----------------
// FPOUT=0: split bf16 hi/lo output; FPOUT=1: fp32 output.
template <int FPOUT>
__global__ __launch_bounds__(256, 2) void gemm_a32_k(
    const float* __restrict__ A, const float* __restrict__ rinv,
    const unsigned short* __restrict__ BH, const unsigned short* __restrict__ BL,
    unsigned short* __restrict__ OH, unsigned short* __restrict__ OL,
    float* __restrict__ Of) {
  __shared__ __align__(16) float lA[128 * 32];        // XOR-swizzled (16B chunks)
  __shared__ __align__(16) unsigned short lBH[128 * 32];
  __shared__ __align__(16) unsigned short lBL[128 * 32];
  __shared__ float ldsR[128];

  int tid = threadIdx.x;
  int lane = tid & 63, wid = tid >> 6;
  int wr = wid >> 1, wc = wid & 1;
  int fr = lane & 15, fg = lane >> 4;
  long m0 = (long)blockIdx.x * 128;
  long n0 = (long)blockIdx.y * 128;

  if (tid < 128) ldsR[tid] = rinv ? rinv[m0 + tid] : 1.0f;

  f32x4 acc[4][4] = {};

  for (int kk = 0; kk < D_DIM; kk += BK) {
#pragma unroll
    for (int i = 0; i < 4; ++i) {
      int chunk = i * 256 + tid;
      int r = chunk >> 3, c = chunk & 7;
      int cs = c ^ (r & 7);
      const float* src = A + (m0 + r) * (long)D_DIM + kk + cs * 4;
      gload16(src, (void*)(lA + ((i * 256 + (tid & ~63)) << 2)));
    }
#pragma unroll
    for (int i = 0; i < 2; ++i) {
      int chunk = i * 256 + tid;
      int r = chunk >> 2, c = chunk & 3;
      int cs = c ^ ((r >> 1) & 3);
      long boff = (n0 + r) * (long)D_DIM + kk + cs * 8;
      int lo = (i * 256 + (tid & ~63)) << 3;
      gload16(BH + boff, (void*)(lBH + lo));
      gload16(BL + boff, (void*)(lBL + lo));
    }
    __syncthreads();

    bf16x8 aH[4], aL[4], bH[4], bL[4];
#pragma unroll
    for (int m = 0; m < 4; ++m) {
      int row = wr * 64 + m * 16 + fr;
      int rm = row & 7;
      f32x4 p0 = *(const f32x4*)(lA + row * 32 + (((fg * 2 + 0) ^ rm) * 4));
      f32x4 p1 = *(const f32x4*)(lA + row * 32 + (((fg * 2 + 1) ^ rm) * 4));
#pragma unroll
      for (int e = 0; e < 8; ++e) {
        float f = (e < 4) ? p0[e] : p1[e - 4];
        unsigned short h = f2bf(f);
        aH[m][e] = (short)h;
        aL[m][e] = (short)f2bf(f - bf2f(h));
      }
    }
#pragma unroll
    for (int n = 0; n < 4; ++n) {
      int row = wc * 64 + n * 16 + fr;
      int sc = fg ^ ((row >> 1) & 3);
      bH[n] = *(const bf16x8*)(lBH + row * 32 + sc * 8);
      bL[n] = *(const bf16x8*)(lBL + row * 32 + sc * 8);
    }
#pragma unroll
    for (int m = 0; m < 4; ++m)
#pragma unroll
      for (int n = 0; n < 4; ++n) {
        acc[m][n] = __builtin_amdgcn_mfma_f32_16x16x32_bf16(aH[m], bH[n], acc[m][n], 0, 0, 0);
        acc[m][n] = __builtin_amdgcn_mfma_f32_16x16x32_bf16(aH[m], bL[n], acc[m][n], 0, 0, 0);
        acc[m][n] = __builtin_amdgcn_mfma_f32_16x16x32_bf16(aL[m], bH[n], acc[m][n], 0, 0, 0);
      }
    __syncthreads();
  }

  // epilogue: scale by rinv[row]; store split bf16 or fp32.
  // C/D layout (m89-verified): col = lane&15, row = (lane>>4)*4 + j
#pragma unroll
  for (int m = 0; m < 4; ++m) {
#pragma unroll
    for (int j = 0; j < 4; ++j) {
      int rloc = wr * 64 + m * 16 + fg * 4 + j;
      float rv = ldsR[rloc];
      long grow = m0 + rloc;
#pragma unroll
      for (int n = 0; n < 4; ++n) {
        long gcol = n0 + wc * 64 + n * 16 + fr;
        float v = acc[m][n][j] * rv;
        if (FPOUT) {
          Of[grow * D_DIM + gcol] = v;
        } else {
          unsigned short h = f2bf(v);
          OH[grow * D_DIM + gcol] = h;
          OL[grow * D_DIM + gcol] = f2bf(v - bf2f(h));
        }
      }
    }
  }
}

// ---------------- K3a: APPROX scores XH @ PH^T + rowscale + col-max ----------------
// R6: 3-buffer LDS, 2-deep prefetch, raw s_barrier + counted vmcnt.
// 4 gload_lds per stage; vmcnt(8) leaves stages t+1,t+2 in flight.
__global__ __launch_bounds__(256, 2) void gemm_scores1_k(
    const unsigned short* __restrict__ XH, const unsigned short* __restrict__ PH,
    const float* __restrict__ rinvA, unsigned* __restrict__ gmax, int b_base) {
  __shared__ __align__(16) unsigned short lAH[3][128 * 32];
  __shared__ __align__(16) unsigned short lBH[3][128 * 32];
  __shared__ float ldsR[128];

  int tid = threadIdx.x;
  int lane = tid & 63, wid = tid >> 6;
  int wr = wid >> 1, wc = wid & 1;
  int fr = lane & 15, fg = lane >> 4;
  long m0 = (long)blockIdx.x * 128;
  long n0 = (long)blockIdx.y * 128;

  if (tid < 128) ldsR[tid] = rinvA[m0 + tid];

  f32x4 acc[4][4] = {};

  auto stage = [&](int buf, int t) {
    int kk = t * BK;
#pragma unroll
    for (int i = 0; i < 2; ++i) {
      int chunk = i * 256 + tid;
      int r = chunk >> 2, c = chunk & 3;
      int cs = c ^ ((r >> 1) & 3);
      long aoff = (m0 + r) * (long)D_DIM + kk + cs * 8;
      long boff = (n0 + r) * (long)D_DIM + kk + cs * 8;
      int lo = (i * 256 + (tid & ~63)) << 3;
      gload16(XH + aoff, (void*)(&lAH[buf][0] + lo));
      gload16(PH + boff, (void*)(&lBH[buf][0] + lo));
    }
  };

  // prologue: 2 stages in flight
  stage(0, 0);
  stage(1, 1);

  int bc = 0;                 // t % 3
  int bn = 2;                 // (t+2) % 3
  for (int t = 0; t < NT; ++t) {
    if (t + 2 < NT) stage(bn, t + 2);
    __builtin_amdgcn_sched_barrier(0);
    // wait for stage(t): 4 loads/stage, FIFO vmcnt (m135)
    if (t < NT - 2) {
      asm volatile("s_waitcnt vmcnt(8)" ::: "memory");
    } else if (t == NT - 2) {
      asm volatile("s_waitcnt vmcnt(4)" ::: "memory");
    } else {
      asm volatile("s_waitcnt vmcnt(0)" ::: "memory");
    }
    __builtin_amdgcn_s_barrier();   // all waves: tile t resident

    bf16x8 aH[4], bH[4];
#pragma unroll
    for (int m = 0; m < 4; ++m) {
      int row = wr * 64 + m * 16 + fr;
      int sc = fg ^ ((row >> 1) & 3);
      aH[m] = *(const bf16x8*)(&lAH[bc][0] + row * 32 + sc * 8);
    }
#pragma unroll
    for (int n = 0; n < 4; ++n) {
      int row = wc * 64 + n * 16 + fr;
      int sc = fg ^ ((row >> 1) & 3);
      bH[n] = *(const bf16x8*)(&lBH[bc][0] + row * 32 + sc * 8);
    }
#pragma unroll
    for (int m = 0; m < 4; ++m)
#pragma unroll
      for (int n = 0; n < 4; ++n)
        acc[m][n] = __builtin_amdgcn_mfma_f32_16x16x32_bf16(aH[m], bH[n], acc[m][n], 0, 0, 0);
    __builtin_amdgcn_s_barrier();   // all reads of buf[bc] done -> reusable
    bc = (bc == 2) ? 0 : bc + 1;
    bn = (bn == 2) ? 0 : bn + 1;
  }

  int b = b_base + (int)(m0 >> 11);
#pragma unroll
  for (int n = 0; n < 4; ++n) {
    float v = -3.0e38f;
#pragma unroll
    for (int m = 0; m < 4; ++m)
#pragma unroll
      for (int j = 0; j < 4; ++j) {
        float rv = ldsR[wr * 64 + m * 16 + fg * 4 + j];
        v = fmaxf(v, acc[m][n][j] * rv);
      }
    v = fmaxf(v, __shfl_xor(v, 16));
    v = fmaxf(v, __shfl_xor(v, 32));
    if (fg == 0) {
      long col = n0 + wc * 64 + n * 16 + fr;
      atomicMax(&gmax[(long)b * NE + col], encf(v * 0.03125f));
    }
  }
}

// ---------------- K3b: per-batch top-CAND candidate selection (+ zero gmax2) ----------------
__global__ void cand_select_k(const unsigned* __restrict__ gmax, int b_base,
                              int* __restrict__ candIdx, unsigned* __restrict__ gmax2) {
  __shared__ unsigned enc[NE];
  __shared__ int ic[257];
  int tid = threadIdx.x;
  int lane = tid & 63, w = tid >> 6;
  int zb = b_base + blockIdx.x;            // absolute batch
  if (tid < CAND) gmax2[zb * CAND + tid] = 0u;
  const unsigned* g = gmax + (size_t)zb * NE;
  for (int i = tid; i < NE; i += 256) enc[i] = g[i];
  __syncthreads();

  unsigned cur = 0;
  for (int bit = 31; bit >= 0; --bit) {
    unsigned cand = cur | (1u << bit);
    int c = 0;
    for (int i = tid; i < NE; i += 256) c += (enc[i] >= cand) ? 1 : 0;
    for (int o = 32; o > 0; o >>= 1) c += __shfl_xor(c, o);
    __syncthreads();
    if (lane == 0) ic[w] = c;
    __syncthreads();
    int tot = ic[0] + ic[1] + ic[2] + ic[3];
    if (tot >= CAND) cur = cand;
  }

  int myc = 0;
  for (int i = tid; i < NE; i += 256) myc += (enc[i] >= cur) ? 1 : 0;
  __syncthreads();
  ic[tid] = myc;
  __syncthreads();
  if (tid == 0) {
    int s = 0;
    for (int t = 0; t < 256; ++t) { int v = ic[t]; ic[t] = s; s += v; }
  }
  __syncthreads();
  int off = ic[tid];
  for (int i = tid; i < NE; i += 256)
    if (enc[i] >= cur) {
      if (off < CAND) candIdx[zb * CAND + off] = i;
      ++off;
    }
}

// ---------------- K3c: gather candidate P rows ----------------
__global__ void gather_k(const unsigned short* __restrict__ PH,
                         const unsigned short* __restrict__ PL,
                         const int* __restrict__ candIdx, int b_base,
                         unsigned short* __restrict__ cPH,
                         unsigned short* __restrict__ cPL) {
  int j = blockIdx.x;
  int zb = b_base + blockIdx.y;            // absolute batch
  int n = candIdx[zb * CAND + j];
  int t4 = threadIdx.x * 4;
  size_t dst = ((size_t)(zb * CAND + j)) * D_DIM + t4;
  size_t src = (size_t)n * D_DIM + t4;
  *(ushort4*)(cPH + dst) = *(const ushort4*)(PH + src);
  *(ushort4*)(cPL + dst) = *(const ushort4*)(PL + src);
}

// ---------------- K3d: EXACT rescore (merged, all 16 batches) ----------------
// grid (SEQ/128, 1, BATCH): z = absolute batch.
__global__ __launch_bounds__(256, 2) void gemm_rescore_k(
    const float* __restrict__ X, const float* __restrict__ rinvA,
    const unsigned short* __restrict__ cPH, const unsigned short* __restrict__ cPL,
    unsigned* __restrict__ gmax2) {
  __shared__ __align__(16) float lA[128 * 32];
  __shared__ __align__(16) unsigned short lBH[128 * 32], lBL[128 * 32];
  __shared__ float ldsR[128];

  int tid = threadIdx.x;
  int lane = tid & 63, wid = tid >> 6;
  int wr = wid >> 1, wc = wid & 1;
  int fr = lane & 15, fg = lane >> 4;
  int z = blockIdx.z;
  long m0 = (long)blockIdx.x * 128;
  long arow0 = (long)z * SEQ + m0;
  long brow0 = (long)z * CAND;

  if (tid < 128) ldsR[tid] = rinvA[arow0 + tid];

  f32x4 acc[4][4] = {};

  for (int kk = 0; kk < D_DIM; kk += BK) {
#pragma unroll
    for (int i = 0; i < 4; ++i) {
      int chunk = i * 256 + tid;
      int r = chunk >> 3, c = chunk & 7;
      int cs = c ^ (r & 7);
      const float* src = X + (arow0 + r) * (long)D_DIM + kk + cs * 4;
      gload16(src, (void*)(lA + ((i * 256 + (tid & ~63)) << 2)));
    }
#pragma unroll
    for (int i = 0; i < 2; ++i) {
      int chunk = i * 256 + tid;
      int r = chunk >> 2, c = chunk & 3;
      int cs = c ^ ((r >> 1) & 3);
      long boff = (brow0 + r) * (long)D_DIM + kk + cs * 8;
      int lo = (i * 256 + (tid & ~63)) << 3;
      gload16(cPH + boff, (void*)(lBH + lo));
      gload16(cPL + boff, (void*)(lBL + lo));
    }
    __syncthreads();

    bf16x8 aH[4], aL[4], bH[4], bL[4];
#pragma unroll
    for (int m = 0; m < 4; ++m) {
      int row = wr * 64 + m * 16 + fr;
      int rm = row & 7;
      f32x4 p0 = *(const f32x4*)(lA + row * 32 + (((fg * 2 + 0) ^ rm) * 4));
      f32x4 p1 = *(const f32x4*)(lA + row * 32 + (((fg * 2 + 1) ^ rm) * 4));
#pragma unroll
      for (int e = 0; e < 8; ++e) {
        float f = (e < 4) ? p0[e] : p1[e - 4];
        unsigned short h = f2bf(f);
        aH[m][e] = (short)h;
        aL[m][e] = (short)f2bf(f - bf2f(h));
      }
    }
#pragma unroll
    for (int n = 0; n < 4; ++n) {
      int row = wc * 64 + n * 16 + fr;
      int sc = fg ^ ((row >> 1) & 3);
      bH[n] = *(const bf16x8*)(lBH + row * 32 + sc * 8);
      bL[n] = *(const bf16x8*)(lBL + row * 32 + sc * 8);
    }
#pragma unroll
    for (int m = 0; m < 4; ++m)
#pragma unroll
      for (int n = 0; n < 4; ++n) {
        acc[m][n] = __builtin_amdgcn_mfma_f32_16x16x32_bf16(aH[m], bH[n], acc[m][n], 0, 0, 0);
        acc[m][n] = __builtin_amdgcn_mfma_f32_16x16x32_bf16(aH[m], bL[n], acc[m][n], 0, 0, 0);
        acc[m][n] = __builtin_amdgcn_mfma_f32_16x16x32_bf16(aL[m], bH[n], acc[m][n], 0, 0, 0);
      }
    __syncthreads();
  }

#pragma unroll
  for (int n = 0; n < 4; ++n) {
    float v = -3.0e38f;
#pragma unroll
    for (int m = 0; m < 4; ++m)
#pragma unroll
      for (int j = 0; j < 4; ++j) {
        float rv = ldsR[wr * 64 + m * 16 + fg * 4 + j];
        v = fmaxf(v, acc[m][n][j] * rv);
      }
    v = fmaxf(v, __shfl_xor(v, 16));
    v = fmaxf(v, __shfl_xor(v, 32));
    if (fg == 0) {
      int col = wc * 64 + n * 16 + fr;   // 0..127
      atomicMax(&gmax2[z * CAND + col], encf(v * 0.03125f));
    }
  }
}

// ---------------- K3e: scatter exact candidate values over approx gmax ----------------
__global__ void scatter_k(const unsigned* __restrict__ gmax2,
                          const int* __restrict__ candIdx,
                          unsigned* __restrict__ gmax) {
  int z = blockIdx.x, j = threadIdx.x;   // absolute batch, candidate
  int n = candIdx[z * CAND + j];
  gmax[(size_t)z * NE + n] = gmax2[z * CAND + j];
}

// ---------------- K4: per-batch exact top-64 cutoff + softmax weights ----------------
__global__ void topk_weights_k(const unsigned* __restrict__ gmax,
                               const float* __restrict__ alpha_p,
                               float* __restrict__ wout, int* __restrict__ idx,
                               int* __restrict__ cnt) {
  __shared__ unsigned enc[NE];
  __shared__ unsigned ubc[4];
  __shared__ float l4[4];
  __shared__ int ic[257];
  int tid = threadIdx.x;
  int lane = tid & 63, w = tid >> 6;
  const unsigned* g = gmax + (size_t)blockIdx.x * NE;
  for (int i = tid; i < NE; i += 256) enc[i] = g[i];
  __syncthreads();

  unsigned mx = 0;
  for (int i = tid; i < NE; i += 256) mx = enc[i] > mx ? enc[i] : mx;
  for (int o = 32; o > 0; o >>= 1) {
    unsigned other = (unsigned)__shfl_xor((int)mx, o);
    if (other > mx) mx = other;
  }
  if (lane == 0) ubc[w] = mx;
  __syncthreads();
  unsigned m1e = ubc[0];
  for (int t = 1; t < 4; ++t) m1e = ubc[t] > m1e ? ubc[t] : m1e;
  float m1 = decf(m1e);

  unsigned cur = 0;
  for (int bit = 31; bit >= 0; --bit) {
    unsigned cand = cur | (1u << bit);
    int c = 0;
    for (int i = tid; i < NE; i += 256) c += (enc[i] >= cand) ? 1 : 0;
    for (int o = 32; o > 0; o >>= 1) c += __shfl_xor(c, o);
    __syncthreads();
    if (lane == 0) ic[w] = c;
    __syncthreads();
    int tot = ic[0] + ic[1] + ic[2] + ic[3];
    if (tot >= KTOP) cur = cand;
  }

  float sd = 0.f, ssum = 0.f;
  for (int i = tid; i < NE; i += 256) {
    float e = expf(decf(enc[i]) - m1);
    sd += e;
    if (enc[i] >= cur) ssum += e;
  }
  for (int o = 32; o > 0; o >>= 1) { sd += __shfl_xor(sd, o); ssum += __shfl_xor(ssum, o); }
  __syncthreads();
  if (lane == 0) { l4[w] = sd; }
  __syncthreads();
  float SD = l4[0] + l4[1] + l4[2] + l4[3];
  __syncthreads();
  if (lane == 0) { l4[w] = ssum; }
  __syncthreads();
  float SS = l4[0] + l4[1] + l4[2] + l4[3];

  float alpha = alpha_p[0];
  float wd = alpha / SD;
  float ws_ = (1.0f - alpha) / SS;
  for (int i = tid; i < NE; i += 256) {
    float e = expf(decf(enc[i]) - m1);
    float wv = wd * e + ((enc[i] >= cur) ? ws_ * e : 0.0f);
    wout[(size_t)blockIdx.x * NE + i] = wv;
  }

  int myc = 0;
  for (int i = tid; i < NE; i += 256) myc += (enc[i] >= cur) ? 1 : 0;
  __syncthreads();
  ic[tid] = myc;
  __syncthreads();
  if (tid == 0) {
    int s = 0;
    for (int t = 0; t < 256; ++t) { int v = ic[t]; ic[t] = s; s += v; }
    ic[256] = s;
    cnt[blockIdx.x] = s;
  }
  __syncthreads();
  int off = ic[tid];
  for (int i = tid; i < NE; i += 256)
    if (enc[i] >= cur) idx[(size_t)blockIdx.x * NE + (off++)] = i;
}

// ---------------- K5: O = rmsnorm(weights @ En, on_w) ----------------
__global__ void out_o_k(const float* __restrict__ wts, const float* __restrict__ E,
                        const float* __restrict__ rinvE, const float* __restrict__ sn_w,
                        const float* __restrict__ on_w, const float* __restrict__ alpha_p,
                        const int* __restrict__ idx, const int* __restrict__ cnt,
                        float* __restrict__ O) {
  __shared__ float l4[4];
  int b = blockIdx.x, tid = threadIdx.x;
  float acc[4] = {0.f, 0.f, 0.f, 0.f};
  float alpha = alpha_p[0];
  if (alpha == 0.0f) {
    int nsel = cnt[b];
    for (int j = 0; j < nsel; ++j) {
      int n = idx[(size_t)b * NE + j];
      float wv = wts[(size_t)b * NE + n] * rinvE[n];
      const float* er = E + (size_t)n * D_DIM;
#pragma unroll
      for (int i = 0; i < 4; ++i) acc[i] += wv * er[tid + 256 * i];
    }
  } else {
    for (int n = 0; n < NE; ++n) {
      float wv = wts[(size_t)b * NE + n] * rinvE[n];
      const float* er = E + (size_t)n * D_DIM;
#pragma unroll
      for (int i = 0; i < 4; ++i) acc[i] += wv * er[tid + 256 * i];
    }
  }
  float ssq = 0.f;
#pragma unroll
  for (int i = 0; i < 4; ++i) {
    acc[i] *= sn_w[tid + 256 * i];
    ssq += acc[i] * acc[i];
  }
  for (int o = 32; o > 0; o >>= 1) ssq += __shfl_xor(ssq, o);
  int lane = tid & 63, w = tid >> 6;
  if (lane == 0) l4[w] = ssq;
  __syncthreads();
  float tot = l4[0] + l4[1] + l4[2] + l4[3];
  float r = rsqrtf(tot * (1.0f / D_DIM) + 1e-6f);
#pragma unroll
  for (int i = 0; i < 4; ++i)
    O[(size_t)b * D_DIM + tid + 256 * i] = acc[i] * r * on_w[tid + 256 * i];
}

}  // namespace

extern "C" void kernel_launch(void* const* d_in, const int* in_sizes, int n_in,
                              void* d_out, int out_size, void* d_ws, size_t ws_size,
                              hipStream_t stream) {
  const float* X     = (const float*)d_in[0];
  const float* alpha = (const float*)d_in[1];
  const float* E     = (const float*)d_in[2];
  const float* Wq    = (const float*)d_in[3];
  const float* Wk    = (const float*)d_in[4];
  const float* xn_w  = (const float*)d_in[5];
  const float* sn_w  = (const float*)d_in[6];
  const float* on_w  = (const float*)d_in[7];
  float* O    = (float*)d_out;                          // [16][1024]
  float* Wout = (float*)d_out + (size_t)BATCH * D_DIM;  // [16][4096]

  char* ws = (char*)d_ws;
  size_t off = 0;
  auto alloc = [&](size_t bytes) {
    char* p = ws + off;
    off += (bytes + 255) & ~(size_t)255;
    return p;
  };
  unsigned short* XH   = (unsigned short*)alloc((size_t)MCH * D_DIM * 2);   // per-chunk
  float*          Kmf  = (float*)alloc((size_t)NE * D_DIM * 4);
  unsigned short* PH   = (unsigned short*)alloc((size_t)NE * D_DIM * 2);
  unsigned short* PL   = (unsigned short*)alloc((size_t)NE * D_DIM * 2);
  unsigned short* WkH  = (unsigned short*)alloc((size_t)D_DIM * D_DIM * 2);
  unsigned short* WkL  = (unsigned short*)alloc((size_t)D_DIM * D_DIM * 2);
  unsigned short* WqTH = (unsigned short*)alloc((size_t)D_DIM * D_DIM * 2);
  unsigned short* WqTL = (unsigned short*)alloc((size_t)D_DIM * D_DIM * 2);
  unsigned short* cPH  = (unsigned short*)alloc((size_t)BATCH * CAND * D_DIM * 2);
  unsigned short* cPL  = (unsigned short*)alloc((size_t)BATCH * CAND * D_DIM * 2);
  float* rinvX = (float*)alloc((size_t)MX * 4);
  float* rinvE = (float*)alloc((size_t)NE * 4);
  unsigned* gmax  = (unsigned*)alloc((size_t)BATCH * NE * 4);
  unsigned* gmax2 = (unsigned*)alloc((size_t)BATCH * CAND * 4);
  int* candIdx = (int*)alloc((size_t)BATCH * CAND * 4);
  int* idx = (int*)alloc((size_t)BATCH * NE * 4);
  int* cnt = (int*)alloc((size_t)BATCH * 4);
  if (off > ws_size) return;  // needs ~60 MB scratch

  row_rinv_k<<<NE, 256, 0, stream>>>(E, rinvE);
  split_w_k<<<D_DIM, 256, 0, stream>>>(Wk, sn_w, WkH, WkL);
  split_wt_k<<<dim3(D_DIM / 32, D_DIM / 32), 256, 0, stream>>>(Wq, xn_w, WqTH, WqTL);

  // Km = (E*rinvE) @ (Wk*sn_w)^T  (fp32 out)
  gemm_a32_k<1><<<dim3(NE / 128, D_DIM / 128), 256, 0, stream>>>(
      E, rinvE, WkH, WkL, nullptr, nullptr, Kmf);
  // P' = Km @ WqT'^T  where WqT'[k,d] = Wq[d,k]*xn_w[k]  (split out)
  gemm_a32_k<0><<<dim3(NE / 128, D_DIM / 128), 256, 0, stream>>>(
      Kmf, nullptr, WqTH, WqTL, PH, PL, nullptr);

  hipMemsetAsync(gmax, 0, (size_t)BATCH * NE * 4, stream);

  for (int ch = 0; ch < MX / MCH; ++ch) {
    long m0 = (long)ch * MCH;
    int b4 = ch * 4;  // chunk holds batches b4..b4+3 entirely (2048 | 8192)
    const float* Xc = X + m0 * D_DIM;
    float* rXc = rinvX + m0;
    rinv_splitx_k<<<MCH, 256, 0, stream>>>(Xc, rXc, XH);
    gemm_scores1_k<<<dim3(MCH / 128, NE / 128), 256, 0, stream>>>(XH, PH, rXc, gmax, b4);
    cand_select_k<<<4, 256, 0, stream>>>(gmax, b4, candIdx, gmax2);
    gather_k<<<dim3(CAND, 4), 256, 0, stream>>>(PH, PL, candIdx, b4, cPH, cPL);
  }

  // merged exact rescore over all 16 batches (full-GPU: 256 blocks)
  gemm_rescore_k<<<dim3(SEQ / 128, 1, BATCH), 256, 0, stream>>>(
      X, rinvX, cPH, cPL, gmax2);
  scatter_k<<<BATCH, CAND, 0, stream>>>(gmax2, candIdx, gmax);

  topk_weights_k<<<BATCH, 256, 0, stream>>>(gmax, alpha, Wout, idx, cnt);
  out_o_k<<<BATCH, 256, 0, stream>>>(Wout, E, rinvE, sn_w, on_w, alpha, idx, cnt, O);
}

// Round 7
// 611.271 us; speedup vs baseline: 2.0112x; 1.1401x over previous
//
#include <hip/hip_runtime.h>

// BasisAttention: B=16,S=2048,D=1024,N=4096,K_TOP=64. fp32 in/out.
// R2: XOR chunk-swizzle. R4: approx-then-rescore. R5: scores = Xn@(Km Wq)^T.
// R6: merged rescore; counted-vmcnt on 128^2 was NEUTRAL (no room between barriers).
// R7: scores1 rewritten as 256^2/BK=64/8-wave phase-split pipeline (T2+T3+T4+T5):
//     LDS dbuf 128KB, 4 phases/K-tile (16 MFMA each), stage(t+2) after the
//     P3 read-closing barrier, vmcnt(8) at K-tile head (never 0 in loop),
//     lgkmcnt(0)+sched_barrier per phase, setprio around MFMA.

namespace {

constexpr int D_DIM = 1024;
constexpr int NE    = 4096;
constexpr int BATCH = 16;
constexpr int SEQ   = 2048;
constexpr int MX    = BATCH * SEQ;   // 32768
constexpr int MCH   = 8192;          // m-chunk (4 chunks, 4 batches each)
constexpr int KTOP  = 64;
constexpr int CAND  = 128;           // candidates per batch
constexpr int BK    = 32;

using f32x4  = __attribute__((ext_vector_type(4))) float;
using bf16x8 = __attribute__((ext_vector_type(8))) short;

__device__ inline unsigned encf(float f) {
  unsigned u = __float_as_uint(f);
  return (u & 0x80000000u) ? ~u : (u | 0x80000000u);
}
__device__ inline float decf(unsigned e) {
  unsigned u = (e & 0x80000000u) ? (e ^ 0x80000000u) : ~e;
  return __uint_as_float(u);
}

__device__ inline unsigned short f2bf(float f) {  // RNE float->bf16 bits
  unsigned u = __float_as_uint(f);
  unsigned lsb = (u >> 16) & 1u;
  u += 0x7fffu + lsb;
  return (unsigned short)(u >> 16);
}
__device__ inline float bf2f(unsigned short h) {
  return __uint_as_float(((unsigned)h) << 16);
}

__device__ inline void gload16(const void* gsrc, void* ldst) {
  __builtin_amdgcn_global_load_lds(
      (const __attribute__((address_space(1))) unsigned int*)gsrc,
      (__attribute__((address_space(3))) unsigned int*)ldst, 16, 0, 0);
}

#define LGK0_SB() do { asm volatile("s_waitcnt lgkmcnt(0)" ::: "memory"); \
                       __builtin_amdgcn_sched_barrier(0); } while (0)

// ---------------- K1: per-row rsqrt(mean(x^2)+eps) ----------------
__global__ void row_rinv_k(const float* __restrict__ X, float* __restrict__ rinv) {
  __shared__ float l4[4];
  int row = blockIdx.x;
  float4 v = ((const float4*)(X + (size_t)row * D_DIM))[threadIdx.x];
  float ss = v.x * v.x + v.y * v.y + v.z * v.z + v.w * v.w;
  for (int o = 32; o > 0; o >>= 1) ss += __shfl_xor(ss, o);
  int lane = threadIdx.x & 63, w = threadIdx.x >> 6;
  if (lane == 0) l4[w] = ss;
  __syncthreads();
  if (threadIdx.x == 0) {
    float t = l4[0] + l4[1] + l4[2] + l4[3];
    rinv[row] = rsqrtf(t * (1.0f / D_DIM) + 1e-6f);
  }
}

// ---------------- K1a: fused per-row rinv + bf16(X) ----------------
__global__ void rinv_splitx_k(const float* __restrict__ X, float* __restrict__ rinv,
                              unsigned short* __restrict__ XH) {
  __shared__ float l4[4];
  int row = blockIdx.x;
  float4 v = ((const float4*)(X + (size_t)row * D_DIM))[threadIdx.x];
  float ss = v.x * v.x + v.y * v.y + v.z * v.z + v.w * v.w;
  for (int o = 32; o > 0; o >>= 1) ss += __shfl_xor(ss, o);
  int lane = threadIdx.x & 63, w = threadIdx.x >> 6;
  if (lane == 0) l4[w] = ss;
  __syncthreads();
  if (threadIdx.x == 0) {
    float t = l4[0] + l4[1] + l4[2] + l4[3];
    rinv[row] = rsqrtf(t * (1.0f / D_DIM) + 1e-6f);
  }
  ushort4 h = make_ushort4(f2bf(v.x), f2bf(v.y), f2bf(v.z), f2bf(v.w));
  *(ushort4*)(XH + (size_t)row * D_DIM + threadIdx.x * 4) = h;
}

// ---------------- K1b: split W[n,k]*cw[k] into bf16 hi/lo ----------------
__global__ void split_w_k(const float* __restrict__ W, const float* __restrict__ cw,
                          unsigned short* __restrict__ H, unsigned short* __restrict__ L) {
  int row = blockIdx.x;
  int c0 = threadIdx.x * 4;
  float4 wv = *(const float4*)(W + (size_t)row * D_DIM + c0);
  float4 cv = *(const float4*)(cw + c0);
  float y[4] = {wv.x * cv.x, wv.y * cv.y, wv.z * cv.z, wv.w * cv.w};
  unsigned short h[4], l[4];
#pragma unroll
  for (int i = 0; i < 4; ++i) {
    h[i] = f2bf(y[i]);
    l[i] = f2bf(y[i] - bf2f(h[i]));
  }
  *(ushort4*)(H + (size_t)row * D_DIM + c0) = make_ushort4(h[0], h[1], h[2], h[3]);
  *(ushort4*)(L + (size_t)row * D_DIM + c0) = make_ushort4(l[0], l[1], l[2], l[3]);
}

// ---------------- K1c: transpose-split: out[k][d] = Wq[d][k]*cw[k] ----------------
__global__ void split_wt_k(const float* __restrict__ W, const float* __restrict__ cw,
                           unsigned short* __restrict__ H, unsigned short* __restrict__ L) {
  __shared__ float t[32][33];
  int k0 = blockIdx.x * 32, d0 = blockIdx.y * 32;
  int tx = threadIdx.x & 31, ty4 = (threadIdx.x >> 5) * 4;
#pragma unroll
  for (int i = 0; i < 4; ++i)
    t[ty4 + i][tx] = W[(size_t)(d0 + ty4 + i) * D_DIM + k0 + tx];
  __syncthreads();
#pragma unroll
  for (int i = 0; i < 4; ++i) {
    int a = ty4 + i;                       // local k
    float v = t[tx][a] * cw[k0 + a];       // W[d0+tx][k0+a]*cw
    unsigned short h = f2bf(v);
    H[(size_t)(k0 + a) * D_DIM + d0 + tx] = h;
    L[(size_t)(k0 + a) * D_DIM + d0 + tx] = f2bf(v - bf2f(h));
  }
}

// ---------------- K2: O = rowscale(A_f32) @ B(hi,lo)^T (3-product) ----------------
template <int FPOUT>
__global__ __launch_bounds__(256, 2) void gemm_a32_k(
    const float* __restrict__ A, const float* __restrict__ rinv,
    const unsigned short* __restrict__ BH, const unsigned short* __restrict__ BL,
    unsigned short* __restrict__ OH, unsigned short* __restrict__ OL,
    float* __restrict__ Of) {
  __shared__ __align__(16) float lA[128 * 32];        // XOR-swizzled (16B chunks)
  __shared__ __align__(16) unsigned short lBH[128 * 32];
  __shared__ __align__(16) unsigned short lBL[128 * 32];
  __shared__ float ldsR[128];

  int tid = threadIdx.x;
  int lane = tid & 63, wid = tid >> 6;
  int wr = wid >> 1, wc = wid & 1;
  int fr = lane & 15, fg = lane >> 4;
  long m0 = (long)blockIdx.x * 128;
  long n0 = (long)blockIdx.y * 128;

  if (tid < 128) ldsR[tid] = rinv ? rinv[m0 + tid] : 1.0f;

  f32x4 acc[4][4] = {};

  for (int kk = 0; kk < D_DIM; kk += BK) {
#pragma unroll
    for (int i = 0; i < 4; ++i) {
      int chunk = i * 256 + tid;
      int r = chunk >> 3, c = chunk & 7;
      int cs = c ^ (r & 7);
      const float* src = A + (m0 + r) * (long)D_DIM + kk + cs * 4;
      gload16(src, (void*)(lA + ((i * 256 + (tid & ~63)) << 2)));
    }
#pragma unroll
    for (int i = 0; i < 2; ++i) {
      int chunk = i * 256 + tid;
      int r = chunk >> 2, c = chunk & 3;
      int cs = c ^ ((r >> 1) & 3);
      long boff = (n0 + r) * (long)D_DIM + kk + cs * 8;
      int lo = (i * 256 + (tid & ~63)) << 3;
      gload16(BH + boff, (void*)(lBH + lo));
      gload16(BL + boff, (void*)(lBL + lo));
    }
    __syncthreads();

    bf16x8 aH[4], aL[4], bH[4], bL[4];
#pragma unroll
    for (int m = 0; m < 4; ++m) {
      int row = wr * 64 + m * 16 + fr;
      int rm = row & 7;
      f32x4 p0 = *(const f32x4*)(lA + row * 32 + (((fg * 2 + 0) ^ rm) * 4));
      f32x4 p1 = *(const f32x4*)(lA + row * 32 + (((fg * 2 + 1) ^ rm) * 4));
#pragma unroll
      for (int e = 0; e < 8; ++e) {
        float f = (e < 4) ? p0[e] : p1[e - 4];
        unsigned short h = f2bf(f);
        aH[m][e] = (short)h;
        aL[m][e] = (short)f2bf(f - bf2f(h));
      }
    }
#pragma unroll
    for (int n = 0; n < 4; ++n) {
      int row = wc * 64 + n * 16 + fr;
      int sc = fg ^ ((row >> 1) & 3);
      bH[n] = *(const bf16x8*)(lBH + row * 32 + sc * 8);
      bL[n] = *(const bf16x8*)(lBL + row * 32 + sc * 8);
    }
#pragma unroll
    for (int m = 0; m < 4; ++m)
#pragma unroll
      for (int n = 0; n < 4; ++n) {
        acc[m][n] = __builtin_amdgcn_mfma_f32_16x16x32_bf16(aH[m], bH[n], acc[m][n], 0, 0, 0);
        acc[m][n] = __builtin_amdgcn_mfma_f32_16x16x32_bf16(aH[m], bL[n], acc[m][n], 0, 0, 0);
        acc[m][n] = __builtin_amdgcn_mfma_f32_16x16x32_bf16(aL[m], bH[n], acc[m][n], 0, 0, 0);
      }
    __syncthreads();
  }

#pragma unroll
  for (int m = 0; m < 4; ++m) {
#pragma unroll
    for (int j = 0; j < 4; ++j) {
      int rloc = wr * 64 + m * 16 + fg * 4 + j;
      float rv = ldsR[rloc];
      long grow = m0 + rloc;
#pragma unroll
      for (int n = 0; n < 4; ++n) {
        long gcol = n0 + wc * 64 + n * 16 + fr;
        float v = acc[m][n][j] * rv;
        if (FPOUT) {
          Of[grow * D_DIM + gcol] = v;
        } else {
          unsigned short h = f2bf(v);
          OH[grow * D_DIM + gcol] = h;
          OL[grow * D_DIM + gcol] = f2bf(v - bf2f(h));
        }
      }
    }
  }
}

// ---------------- K3a: APPROX scores, 256^2 / BK=64 / 8-wave phase-split ----------------
// C tile 256x256; waves 2M x 4N, each 128x64; acc[8][4] f32x4.
// LDS: dbuf [2][256][64] bf16 per operand (128 KiB), swizzle chunk^=(row&7).
__global__ __launch_bounds__(512, 2) void gemm_scores1_k(
    const unsigned short* __restrict__ XH, const unsigned short* __restrict__ PH,
    const float* __restrict__ rinvA, unsigned* __restrict__ gmax, int b_base) {
  __shared__ __align__(16) unsigned short lA[2][256 * 64];
  __shared__ __align__(16) unsigned short lB[2][256 * 64];
  __shared__ float ldsR[256];

  int tid = threadIdx.x;                 // 0..511
  int lane = tid & 63, wid = tid >> 6;   // 8 waves
  int wr = wid >> 2;                     // 0..1  (M half)
  int wcn = wid & 3;                     // 0..3  (N quarter)
  int fr = lane & 15, fg = lane >> 4;
  long m0 = (long)blockIdx.x * 256;
  long n0 = (long)blockIdx.y * 256;

  if (tid < 256) ldsR[tid] = rinvA[m0 + tid];

  // stage one full K-tile (A: 2 half-tiles, B: 2 half-tiles; 8 gload16/thread)
  auto stageTile = [&](int buf, int kt) {
    int kk = kt * 64;
#pragma unroll
    for (int h = 0; h < 2; ++h)
#pragma unroll
      for (int i = 0; i < 2; ++i) {
        int chunk = h * 1024 + i * 512 + tid;      // /2048 chunks of 16B
        int r = chunk >> 3, c = chunk & 7;
        int cs = c ^ (r & 7);                      // pre-swizzled source
        gload16(XH + (m0 + r) * (long)D_DIM + kk + cs * 8,
                (void*)(&lA[buf][0] + ((h * 1024 + i * 512 + (tid & ~63)) << 3)));
      }
#pragma unroll
    for (int h = 0; h < 2; ++h)
#pragma unroll
      for (int i = 0; i < 2; ++i) {
        int chunk = h * 1024 + i * 512 + tid;
        int r = chunk >> 3, c = chunk & 7;
        int cs = c ^ (r & 7);
        gload16(PH + (n0 + r) * (long)D_DIM + kk + cs * 8,
                (void*)(&lB[buf][0] + ((h * 1024 + i * 512 + (tid & ~63)) << 3)));
      }
  };

  f32x4 acc[8][4] = {};

  stageTile(0, 0);
  stageTile(1, 1);
  asm volatile("s_waitcnt lgkmcnt(0)" ::: "memory");  // ldsR writes visible at barrier

  bf16x8 aF[4][2], bF[4][2];

  for (int kt = 0; kt < 16; ++kt) {
    int cur = kt & 1;
    const unsigned short* As = &lA[cur][0];
    const unsigned short* Bs = &lB[cur][0];

    // K-tile head: wait for buf[cur]'s loads (leave next tile's 8 in flight)
    if (kt < 15) {
      asm volatile("s_waitcnt vmcnt(8)" ::: "memory");
    } else {
      asm volatile("s_waitcnt vmcnt(0)" ::: "memory");
    }
    __builtin_amdgcn_s_barrier();

    // ---- P1: read A[m 0..3] + B[n 0..1]; MFMA quadrant (m0-3, n0-1)
#pragma unroll
    for (int mi = 0; mi < 4; ++mi)
#pragma unroll
      for (int ks = 0; ks < 2; ++ks) {
        int row = wr * 128 + mi * 16 + fr;
        int ck = (ks * 4 + fg) ^ (row & 7);
        aF[mi][ks] = *(const bf16x8*)(As + row * 64 + ck * 8);
      }
#pragma unroll
    for (int ni = 0; ni < 2; ++ni)
#pragma unroll
      for (int ks = 0; ks < 2; ++ks) {
        int row = wcn * 64 + ni * 16 + fr;
        int ck = (ks * 4 + fg) ^ (row & 7);
        bF[ni][ks] = *(const bf16x8*)(Bs + row * 64 + ck * 8);
      }
    LGK0_SB();
    __builtin_amdgcn_s_setprio(1);
#pragma unroll
    for (int mi = 0; mi < 4; ++mi)
#pragma unroll
      for (int ni = 0; ni < 2; ++ni)
#pragma unroll
        for (int ks = 0; ks < 2; ++ks)
          acc[mi][ni] = __builtin_amdgcn_mfma_f32_16x16x32_bf16(
              aF[mi][ks], bF[ni][ks], acc[mi][ni], 0, 0, 0);
    __builtin_amdgcn_s_setprio(0);

    // ---- P2: read B[n 2..3]; MFMA quadrant (m0-3, n2-3)
#pragma unroll
    for (int ni = 2; ni < 4; ++ni)
#pragma unroll
      for (int ks = 0; ks < 2; ++ks) {
        int row = wcn * 64 + ni * 16 + fr;
        int ck = (ks * 4 + fg) ^ (row & 7);
        bF[ni][ks] = *(const bf16x8*)(Bs + row * 64 + ck * 8);
      }
    LGK0_SB();
    __builtin_amdgcn_s_setprio(1);
#pragma unroll
    for (int mi = 0; mi < 4; ++mi)
#pragma unroll
      for (int ni = 2; ni < 4; ++ni)
#pragma unroll
        for (int ks = 0; ks < 2; ++ks)
          acc[mi][ni] = __builtin_amdgcn_mfma_f32_16x16x32_bf16(
              aF[mi][ks], bF[ni][ks], acc[mi][ni], 0, 0, 0);
    __builtin_amdgcn_s_setprio(0);

    // ---- P3: read A[m 4..7] (overwrites aF); barrier closes ALL reads of
    //          buf[cur]; then stage(kt+2 -> buf[cur]); MFMA (m4-7, n2-3)
#pragma unroll
    for (int mi = 0; mi < 4; ++mi)
#pragma unroll
      for (int ks = 0; ks < 2; ++ks) {
        int row = wr * 128 + (mi + 4) * 16 + fr;
        int ck = (ks * 4 + fg) ^ (row & 7);
        aF[mi][ks] = *(const bf16x8*)(As + row * 64 + ck * 8);
      }
    LGK0_SB();
    __builtin_amdgcn_s_barrier();          // everyone done reading buf[cur]
    if (kt + 2 < 16) stageTile(cur, kt + 2);
    __builtin_amdgcn_s_setprio(1);
#pragma unroll
    for (int mi = 0; mi < 4; ++mi)
#pragma unroll
      for (int ni = 2; ni < 4; ++ni)
#pragma unroll
        for (int ks = 0; ks < 2; ++ks)
          acc[mi + 4][ni] = __builtin_amdgcn_mfma_f32_16x16x32_bf16(
              aF[mi][ks], bF[ni][ks], acc[mi + 4][ni], 0, 0, 0);
    __builtin_amdgcn_s_setprio(0);

    // ---- P4: MFMA (m4-7, n0-1), register-only
    __builtin_amdgcn_s_setprio(1);
#pragma unroll
    for (int mi = 0; mi < 4; ++mi)
#pragma unroll
      for (int ni = 0; ni < 2; ++ni)
#pragma unroll
        for (int ks = 0; ks < 2; ++ks)
          acc[mi + 4][ni] = __builtin_amdgcn_mfma_f32_16x16x32_bf16(
              aF[mi][ks], bF[ni][ks], acc[mi + 4][ni], 0, 0, 0);
    __builtin_amdgcn_s_setprio(0);
  }

  // epilogue: rinv per-row, column max over 256 rows, atomicMax.
  int b = b_base + (int)(m0 >> 11);
#pragma unroll
  for (int ni = 0; ni < 4; ++ni) {
    float v = -3.0e38f;
#pragma unroll
    for (int mi = 0; mi < 8; ++mi)
#pragma unroll
      for (int j = 0; j < 4; ++j) {
        int row = wr * 128 + mi * 16 + fg * 4 + j;
        v = fmaxf(v, acc[mi][ni][j] * ldsR[row]);
      }
    v = fmaxf(v, __shfl_xor(v, 16));
    v = fmaxf(v, __shfl_xor(v, 32));
    if (fg == 0) {
      long col = n0 + wcn * 64 + ni * 16 + fr;
      atomicMax(&gmax[(long)b * NE + col], encf(v * 0.03125f));
    }
  }
}

// ---------------- K3b: per-batch top-CAND candidate selection (+ zero gmax2) ----------------
__global__ void cand_select_k(const unsigned* __restrict__ gmax, int b_base,
                              int* __restrict__ candIdx, unsigned* __restrict__ gmax2) {
  __shared__ unsigned enc[NE];
  __shared__ int ic[257];
  int tid = threadIdx.x;
  int lane = tid & 63, w = tid >> 6;
  int zb = b_base + blockIdx.x;            // absolute batch
  if (tid < CAND) gmax2[zb * CAND + tid] = 0u;
  const unsigned* g = gmax + (size_t)zb * NE;
  for (int i = tid; i < NE; i += 256) enc[i] = g[i];
  __syncthreads();

  unsigned cur = 0;
  for (int bit = 31; bit >= 0; --bit) {
    unsigned cand = cur | (1u << bit);
    int c = 0;
    for (int i = tid; i < NE; i += 256) c += (enc[i] >= cand) ? 1 : 0;
    for (int o = 32; o > 0; o >>= 1) c += __shfl_xor(c, o);
    __syncthreads();
    if (lane == 0) ic[w] = c;
    __syncthreads();
    int tot = ic[0] + ic[1] + ic[2] + ic[3];
    if (tot >= CAND) cur = cand;
  }

  int myc = 0;
  for (int i = tid; i < NE; i += 256) myc += (enc[i] >= cur) ? 1 : 0;
  __syncthreads();
  ic[tid] = myc;
  __syncthreads();
  if (tid == 0) {
    int s = 0;
    for (int t = 0; t < 256; ++t) { int v = ic[t]; ic[t] = s; s += v; }
  }
  __syncthreads();
  int off = ic[tid];
  for (int i = tid; i < NE; i += 256)
    if (enc[i] >= cur) {
      if (off < CAND) candIdx[zb * CAND + off] = i;
      ++off;
    }
}

// ---------------- K3c: gather candidate P rows ----------------
__global__ void gather_k(const unsigned short* __restrict__ PH,
                         const unsigned short* __restrict__ PL,
                         const int* __restrict__ candIdx, int b_base,
                         unsigned short* __restrict__ cPH,
                         unsigned short* __restrict__ cPL) {
  int j = blockIdx.x;
  int zb = b_base + blockIdx.y;            // absolute batch
  int n = candIdx[zb * CAND + j];
  int t4 = threadIdx.x * 4;
  size_t dst = ((size_t)(zb * CAND + j)) * D_DIM + t4;
  size_t src = (size_t)n * D_DIM + t4;
  *(ushort4*)(cPH + dst) = *(const ushort4*)(PH + src);
  *(ushort4*)(cPL + dst) = *(const ushort4*)(PL + src);
}

// ---------------- K3d: EXACT rescore (merged, all 16 batches) ----------------
__global__ __launch_bounds__(256, 2) void gemm_rescore_k(
    const float* __restrict__ X, const float* __restrict__ rinvA,
    const unsigned short* __restrict__ cPH, const unsigned short* __restrict__ cPL,
    unsigned* __restrict__ gmax2) {
  __shared__ __align__(16) float lA[128 * 32];
  __shared__ __align__(16) unsigned short lBH[128 * 32], lBL[128 * 32];
  __shared__ float ldsR[128];

  int tid = threadIdx.x;
  int lane = tid & 63, wid = tid >> 6;
  int wr = wid >> 1, wc = wid & 1;
  int fr = lane & 15, fg = lane >> 4;
  int z = blockIdx.z;
  long m0 = (long)blockIdx.x * 128;
  long arow0 = (long)z * SEQ + m0;
  long brow0 = (long)z * CAND;

  if (tid < 128) ldsR[tid] = rinvA[arow0 + tid];

  f32x4 acc[4][4] = {};

  for (int kk = 0; kk < D_DIM; kk += BK) {
#pragma unroll
    for (int i = 0; i < 4; ++i) {
      int chunk = i * 256 + tid;
      int r = chunk >> 3, c = chunk & 7;
      int cs = c ^ (r & 7);
      const float* src = X + (arow0 + r) * (long)D_DIM + kk + cs * 4;
      gload16(src, (void*)(lA + ((i * 256 + (tid & ~63)) << 2)));
    }
#pragma unroll
    for (int i = 0; i < 2; ++i) {
      int chunk = i * 256 + tid;
      int r = chunk >> 2, c = chunk & 3;
      int cs = c ^ ((r >> 1) & 3);
      long boff = (brow0 + r) * (long)D_DIM + kk + cs * 8;
      int lo = (i * 256 + (tid & ~63)) << 3;
      gload16(cPH + boff, (void*)(lBH + lo));
      gload16(cPL + boff, (void*)(lBL + lo));
    }
    __syncthreads();

    bf16x8 aH[4], aL[4], bH[4], bL[4];
#pragma unroll
    for (int m = 0; m < 4; ++m) {
      int row = wr * 64 + m * 16 + fr;
      int rm = row & 7;
      f32x4 p0 = *(const f32x4*)(lA + row * 32 + (((fg * 2 + 0) ^ rm) * 4));
      f32x4 p1 = *(const f32x4*)(lA + row * 32 + (((fg * 2 + 1) ^ rm) * 4));
#pragma unroll
      for (int e = 0; e < 8; ++e) {
        float f = (e < 4) ? p0[e] : p1[e - 4];
        unsigned short h = f2bf(f);
        aH[m][e] = (short)h;
        aL[m][e] = (short)f2bf(f - bf2f(h));
      }
    }
#pragma unroll
    for (int n = 0; n < 4; ++n) {
      int row = wc * 64 + n * 16 + fr;
      int sc = fg ^ ((row >> 1) & 3);
      bH[n] = *(const bf16x8*)(lBH + row * 32 + sc * 8);
      bL[n] = *(const bf16x8*)(lBL + row * 32 + sc * 8);
    }
#pragma unroll
    for (int m = 0; m < 4; ++m)
#pragma unroll
      for (int n = 0; n < 4; ++n) {
        acc[m][n] = __builtin_amdgcn_mfma_f32_16x16x32_bf16(aH[m], bH[n], acc[m][n], 0, 0, 0);
        acc[m][n] = __builtin_amdgcn_mfma_f32_16x16x32_bf16(aH[m], bL[n], acc[m][n], 0, 0, 0);
        acc[m][n] = __builtin_amdgcn_mfma_f32_16x16x32_bf16(aL[m], bH[n], acc[m][n], 0, 0, 0);
      }
    __syncthreads();
  }

#pragma unroll
  for (int n = 0; n < 4; ++n) {
    float v = -3.0e38f;
#pragma unroll
    for (int m = 0; m < 4; ++m)
#pragma unroll
      for (int j = 0; j < 4; ++j) {
        float rv = ldsR[wr * 64 + m * 16 + fg * 4 + j];
        v = fmaxf(v, acc[m][n][j] * rv);
      }
    v = fmaxf(v, __shfl_xor(v, 16));
    v = fmaxf(v, __shfl_xor(v, 32));
    if (fg == 0) {
      int col = wc * 64 + n * 16 + fr;   // 0..127
      atomicMax(&gmax2[z * CAND + col], encf(v * 0.03125f));
    }
  }
}

// ---------------- K3e: scatter exact candidate values over approx gmax ----------------
__global__ void scatter_k(const unsigned* __restrict__ gmax2,
                          const int* __restrict__ candIdx,
                          unsigned* __restrict__ gmax) {
  int z = blockIdx.x, j = threadIdx.x;   // absolute batch, candidate
  int n = candIdx[z * CAND + j];
  gmax[(size_t)z * NE + n] = gmax2[z * CAND + j];
}

// ---------------- K4: per-batch exact top-64 cutoff + softmax weights ----------------
__global__ void topk_weights_k(const unsigned* __restrict__ gmax,
                               const float* __restrict__ alpha_p,
                               float* __restrict__ wout, int* __restrict__ idx,
                               int* __restrict__ cnt) {
  __shared__ unsigned enc[NE];
  __shared__ unsigned ubc[4];
  __shared__ float l4[4];
  __shared__ int ic[257];
  int tid = threadIdx.x;
  int lane = tid & 63, w = tid >> 6;
  const unsigned* g = gmax + (size_t)blockIdx.x * NE;
  for (int i = tid; i < NE; i += 256) enc[i] = g[i];
  __syncthreads();

  unsigned mx = 0;
  for (int i = tid; i < NE; i += 256) mx = enc[i] > mx ? enc[i] : mx;
  for (int o = 32; o > 0; o >>= 1) {
    unsigned other = (unsigned)__shfl_xor((int)mx, o);
    if (other > mx) mx = other;
  }
  if (lane == 0) ubc[w] = mx;
  __syncthreads();
  unsigned m1e = ubc[0];
  for (int t = 1; t < 4; ++t) m1e = ubc[t] > m1e ? ubc[t] : m1e;
  float m1 = decf(m1e);

  unsigned cur = 0;
  for (int bit = 31; bit >= 0; --bit) {
    unsigned cand = cur | (1u << bit);
    int c = 0;
    for (int i = tid; i < NE; i += 256) c += (enc[i] >= cand) ? 1 : 0;
    for (int o = 32; o > 0; o >>= 1) c += __shfl_xor(c, o);
    __syncthreads();
    if (lane == 0) ic[w] = c;
    __syncthreads();
    int tot = ic[0] + ic[1] + ic[2] + ic[3];
    if (tot >= KTOP) cur = cand;
  }

  float sd = 0.f, ssum = 0.f;
  for (int i = tid; i < NE; i += 256) {
    float e = expf(decf(enc[i]) - m1);
    sd += e;
    if (enc[i] >= cur) ssum += e;
  }
  for (int o = 32; o > 0; o >>= 1) { sd += __shfl_xor(sd, o); ssum += __shfl_xor(ssum, o); }
  __syncthreads();
  if (lane == 0) { l4[w] = sd; }
  __syncthreads();
  float SD = l4[0] + l4[1] + l4[2] + l4[3];
  __syncthreads();
  if (lane == 0) { l4[w] = ssum; }
  __syncthreads();
  float SS = l4[0] + l4[1] + l4[2] + l4[3];

  float alpha = alpha_p[0];
  float wd = alpha / SD;
  float ws_ = (1.0f - alpha) / SS;
  for (int i = tid; i < NE; i += 256) {
    float e = expf(decf(enc[i]) - m1);
    float wv = wd * e + ((enc[i] >= cur) ? ws_ * e : 0.0f);
    wout[(size_t)blockIdx.x * NE + i] = wv;
  }

  int myc = 0;
  for (int i = tid; i < NE; i += 256) myc += (enc[i] >= cur) ? 1 : 0;
  __syncthreads();
  ic[tid] = myc;
  __syncthreads();
  if (tid == 0) {
    int s = 0;
    for (int t = 0; t < 256; ++t) { int v = ic[t]; ic[t] = s; s += v; }
    ic[256] = s;
    cnt[blockIdx.x] = s;
  }
  __syncthreads();
  int off = ic[tid];
  for (int i = tid; i < NE; i += 256)
    if (enc[i] >= cur) idx[(size_t)blockIdx.x * NE + (off++)] = i;
}

// ---------------- K5: O = rmsnorm(weights @ En, on_w) ----------------
__global__ void out_o_k(const float* __restrict__ wts, const float* __restrict__ E,
                        const float* __restrict__ rinvE, const float* __restrict__ sn_w,
                        const float* __restrict__ on_w, const float* __restrict__ alpha_p,
                        const int* __restrict__ idx, const int* __restrict__ cnt,
                        float* __restrict__ O) {
  __shared__ float l4[4];
  int b = blockIdx.x, tid = threadIdx.x;
  float acc[4] = {0.f, 0.f, 0.f, 0.f};
  float alpha = alpha_p[0];
  if (alpha == 0.0f) {
    int nsel = cnt[b];
    for (int j = 0; j < nsel; ++j) {
      int n = idx[(size_t)b * NE + j];
      float wv = wts[(size_t)b * NE + n] * rinvE[n];
      const float* er = E + (size_t)n * D_DIM;
#pragma unroll
      for (int i = 0; i < 4; ++i) acc[i] += wv * er[tid + 256 * i];
    }
  } else {
    for (int n = 0; n < NE; ++n) {
      float wv = wts[(size_t)b * NE + n] * rinvE[n];
      const float* er = E + (size_t)n * D_DIM;
#pragma unroll
      for (int i = 0; i < 4; ++i) acc[i] += wv * er[tid + 256 * i];
    }
  }
  float ssq = 0.f;
#pragma unroll
  for (int i = 0; i < 4; ++i) {
    acc[i] *= sn_w[tid + 256 * i];
    ssq += acc[i] * acc[i];
  }
  for (int o = 32; o > 0; o >>= 1) ssq += __shfl_xor(ssq, o);
  int lane = tid & 63, w = tid >> 6;
  if (lane == 0) l4[w] = ssq;
  __syncthreads();
  float tot = l4[0] + l4[1] + l4[2] + l4[3];
  float r = rsqrtf(tot * (1.0f / D_DIM) + 1e-6f);
#pragma unroll
  for (int i = 0; i < 4; ++i)
    O[(size_t)b * D_DIM + tid + 256 * i] = acc[i] * r * on_w[tid + 256 * i];
}

}  // namespace

extern "C" void kernel_launch(void* const* d_in, const int* in_sizes, int n_in,
                              void* d_out, int out_size, void* d_ws, size_t ws_size,
                              hipStream_t stream) {
  const float* X     = (const float*)d_in[0];
  const float* alpha = (const float*)d_in[1];
  const float* E     = (const float*)d_in[2];
  const float* Wq    = (const float*)d_in[3];
  const float* Wk    = (const float*)d_in[4];
  const float* xn_w  = (const float*)d_in[5];
  const float* sn_w  = (const float*)d_in[6];
  const float* on_w  = (const float*)d_in[7];
  float* O    = (float*)d_out;                          // [16][1024]
  float* Wout = (float*)d_out + (size_t)BATCH * D_DIM;  // [16][4096]

  char* ws = (char*)d_ws;
  size_t off = 0;
  auto alloc = [&](size_t bytes) {
    char* p = ws + off;
    off += (bytes + 255) & ~(size_t)255;
    return p;
  };
  unsigned short* XH   = (unsigned short*)alloc((size_t)MCH * D_DIM * 2);   // per-chunk
  float*          Kmf  = (float*)alloc((size_t)NE * D_DIM * 4);
  unsigned short* PH   = (unsigned short*)alloc((size_t)NE * D_DIM * 2);
  unsigned short* PL   = (unsigned short*)alloc((size_t)NE * D_DIM * 2);
  unsigned short* WkH  = (unsigned short*)alloc((size_t)D_DIM * D_DIM * 2);
  unsigned short* WkL  = (unsigned short*)alloc((size_t)D_DIM * D_DIM * 2);
  unsigned short* WqTH = (unsigned short*)alloc((size_t)D_DIM * D_DIM * 2);
  unsigned short* WqTL = (unsigned short*)alloc((size_t)D_DIM * D_DIM * 2);
  unsigned short* cPH  = (unsigned short*)alloc((size_t)BATCH * CAND * D_DIM * 2);
  unsigned short* cPL  = (unsigned short*)alloc((size_t)BATCH * CAND * D_DIM * 2);
  float* rinvX = (float*)alloc((size_t)MX * 4);
  float* rinvE = (float*)alloc((size_t)NE * 4);
  unsigned* gmax  = (unsigned*)alloc((size_t)BATCH * NE * 4);
  unsigned* gmax2 = (unsigned*)alloc((size_t)BATCH * CAND * 4);
  int* candIdx = (int*)alloc((size_t)BATCH * CAND * 4);
  int* idx = (int*)alloc((size_t)BATCH * NE * 4);
  int* cnt = (int*)alloc((size_t)BATCH * 4);
  if (off > ws_size) return;  // needs ~60 MB scratch

  row_rinv_k<<<NE, 256, 0, stream>>>(E, rinvE);
  split_w_k<<<D_DIM, 256, 0, stream>>>(Wk, sn_w, WkH, WkL);
  split_wt_k<<<dim3(D_DIM / 32, D_DIM / 32), 256, 0, stream>>>(Wq, xn_w, WqTH, WqTL);

  // Km = (E*rinvE) @ (Wk*sn_w)^T  (fp32 out)
  gemm_a32_k<1><<<dim3(NE / 128, D_DIM / 128), 256, 0, stream>>>(
      E, rinvE, WkH, WkL, nullptr, nullptr, Kmf);
  // P' = Km @ WqT'^T  where WqT'[k,d] = Wq[d,k]*xn_w[k]  (split out)
  gemm_a32_k<0><<<dim3(NE / 128, D_DIM / 128), 256, 0, stream>>>(
      Kmf, nullptr, WqTH, WqTL, PH, PL, nullptr);

  hipMemsetAsync(gmax, 0, (size_t)BATCH * NE * 4, stream);

  for (int ch = 0; ch < MX / MCH; ++ch) {
    long m0 = (long)ch * MCH;
    int b4 = ch * 4;  // chunk holds batches b4..b4+3 entirely (2048 | 8192)
    const float* Xc = X + m0 * D_DIM;
    float* rXc = rinvX + m0;
    rinv_splitx_k<<<MCH, 256, 0, stream>>>(Xc, rXc, XH);
    gemm_scores1_k<<<dim3(MCH / 256, NE / 256), 512, 0, stream>>>(XH, PH, rXc, gmax, b4);
    cand_select_k<<<4, 256, 0, stream>>>(gmax, b4, candIdx, gmax2);
    gather_k<<<dim3(CAND, 4), 256, 0, stream>>>(PH, PL, candIdx, b4, cPH, cPL);
  }

  // merged exact rescore over all 16 batches (full-GPU: 256 blocks)
  gemm_rescore_k<<<dim3(SEQ / 128, 1, BATCH), 256, 0, stream>>>(
      X, rinvX, cPH, cPL, gmax2);
  scatter_k<<<BATCH, CAND, 0, stream>>>(gmax2, candIdx, gmax);

  topk_weights_k<<<BATCH, 256, 0, stream>>>(gmax, alpha, Wout, idx, cnt);
  out_o_k<<<BATCH, 256, 0, stream>>>(Wout, E, rinvE, sn_w, on_w, alpha, idx, cnt, O);
}

// Round 8
// 512.971 us; speedup vs baseline: 2.3966x; 1.1916x over previous
//
#include <hip/hip_runtime.h>

// BasisAttention: B=16,S=2048,D=1024,N=4096,K_TOP=64. fp32 in/out.
// R2: XOR chunk-swizzle. R4: approx-then-rescore. R5: scores = Xn@(Km Wq)^T.
// R7: scores1 = 256^2/BK=64/8-wave phase-split pipeline (T2+T3+T4+T5).
// R8: (a) weight-chain fusion: P' = (E*rinvE) @ W2T^T with
//         W2T[j,d] = xn_w[j] * sum_k Wq[k,j]*(Wk[k,d]*sn_w[d])  (1024^2 GEMM)
//         -> removes the 4096-row Km GEMM entirely.
//     (b) de-chunked M: single rinv_splitx (XH=64MB in ws), single scores1
//         dispatch (2048 blocks) with bijective XCD swizzle (T1).

namespace {

constexpr int D_DIM = 1024;
constexpr int NE    = 4096;
constexpr int BATCH = 16;
constexpr int SEQ   = 2048;
constexpr int MX    = BATCH * SEQ;   // 32768
constexpr int KTOP  = 64;
constexpr int CAND  = 128;           // candidates per batch
constexpr int BK    = 32;

using f32x4  = __attribute__((ext_vector_type(4))) float;
using bf16x8 = __attribute__((ext_vector_type(8))) short;

__device__ inline unsigned encf(float f) {
  unsigned u = __float_as_uint(f);
  return (u & 0x80000000u) ? ~u : (u | 0x80000000u);
}
__device__ inline float decf(unsigned e) {
  unsigned u = (e & 0x80000000u) ? (e ^ 0x80000000u) : ~e;
  return __uint_as_float(u);
}

__device__ inline unsigned short f2bf(float f) {  // RNE float->bf16 bits
  unsigned u = __float_as_uint(f);
  unsigned lsb = (u >> 16) & 1u;
  u += 0x7fffu + lsb;
  return (unsigned short)(u >> 16);
}
__device__ inline float bf2f(unsigned short h) {
  return __uint_as_float(((unsigned)h) << 16);
}

__device__ inline void gload16(const void* gsrc, void* ldst) {
  __builtin_amdgcn_global_load_lds(
      (const __attribute__((address_space(1))) unsigned int*)gsrc,
      (__attribute__((address_space(3))) unsigned int*)ldst, 16, 0, 0);
}

#define LGK0_SB() do { asm volatile("s_waitcnt lgkmcnt(0)" ::: "memory"); \
                       __builtin_amdgcn_sched_barrier(0); } while (0)

// ---------------- K1: per-row rsqrt(mean(x^2)+eps) ----------------
__global__ void row_rinv_k(const float* __restrict__ X, float* __restrict__ rinv) {
  __shared__ float l4[4];
  int row = blockIdx.x;
  float4 v = ((const float4*)(X + (size_t)row * D_DIM))[threadIdx.x];
  float ss = v.x * v.x + v.y * v.y + v.z * v.z + v.w * v.w;
  for (int o = 32; o > 0; o >>= 1) ss += __shfl_xor(ss, o);
  int lane = threadIdx.x & 63, w = threadIdx.x >> 6;
  if (lane == 0) l4[w] = ss;
  __syncthreads();
  if (threadIdx.x == 0) {
    float t = l4[0] + l4[1] + l4[2] + l4[3];
    rinv[row] = rsqrtf(t * (1.0f / D_DIM) + 1e-6f);
  }
}

// ---------------- K1a: fused per-row rinv + bf16(X) ----------------
__global__ void rinv_splitx_k(const float* __restrict__ X, float* __restrict__ rinv,
                              unsigned short* __restrict__ XH) {
  __shared__ float l4[4];
  int row = blockIdx.x;
  float4 v = ((const float4*)(X + (size_t)row * D_DIM))[threadIdx.x];
  float ss = v.x * v.x + v.y * v.y + v.z * v.z + v.w * v.w;
  for (int o = 32; o > 0; o >>= 1) ss += __shfl_xor(ss, o);
  int lane = threadIdx.x & 63, w = threadIdx.x >> 6;
  if (lane == 0) l4[w] = ss;
  __syncthreads();
  if (threadIdx.x == 0) {
    float t = l4[0] + l4[1] + l4[2] + l4[3];
    rinv[row] = rsqrtf(t * (1.0f / D_DIM) + 1e-6f);
  }
  ushort4 h = make_ushort4(f2bf(v.x), f2bf(v.y), f2bf(v.z), f2bf(v.w));
  *(ushort4*)(XH + (size_t)row * D_DIM + threadIdx.x * 4) = h;
}

// ---------------- K1c: transpose-split: out[r][c] = W[c][r]*cw[r], bf16 hi/lo ----------------
__global__ void split_wt_k(const float* __restrict__ W, const float* __restrict__ cw,
                           unsigned short* __restrict__ H, unsigned short* __restrict__ L) {
  __shared__ float t[32][33];
  int k0 = blockIdx.x * 32, d0 = blockIdx.y * 32;
  int tx = threadIdx.x & 31, ty4 = (threadIdx.x >> 5) * 4;
#pragma unroll
  for (int i = 0; i < 4; ++i)
    t[ty4 + i][tx] = W[(size_t)(d0 + ty4 + i) * D_DIM + k0 + tx];
  __syncthreads();
#pragma unroll
  for (int i = 0; i < 4; ++i) {
    int a = ty4 + i;
    float v = t[tx][a] * cw[k0 + a];       // out[k0+a][d0+tx] = W[d0+tx][k0+a]*cw[k0+a]
    unsigned short h = f2bf(v);
    H[(size_t)(k0 + a) * D_DIM + d0 + tx] = h;
    L[(size_t)(k0 + a) * D_DIM + d0 + tx] = f2bf(v - bf2f(h));
  }
}

// ---------------- K1d: fp32 transpose: T[r][c] = W[c][r] ----------------
__global__ void transpose_k(const float* __restrict__ W, float* __restrict__ T) {
  __shared__ float t[32][33];
  int x0 = blockIdx.x * 32, y0 = blockIdx.y * 32;
  int tx = threadIdx.x & 31, ty4 = (threadIdx.x >> 5) * 4;
#pragma unroll
  for (int i = 0; i < 4; ++i)
    t[ty4 + i][tx] = W[(size_t)(y0 + ty4 + i) * D_DIM + x0 + tx];
  __syncthreads();
#pragma unroll
  for (int i = 0; i < 4; ++i)
    T[(size_t)(x0 + ty4 + i) * D_DIM + y0 + tx] = t[tx][ty4 + i];
}

// ---------------- K2: O = rowscale(A_f32) @ B(hi,lo)^T (3-product) ----------------
// FPOUT=0: split bf16 hi/lo output; FPOUT=1: fp32 output.
template <int FPOUT>
__global__ __launch_bounds__(256, 2) void gemm_a32_k(
    const float* __restrict__ A, const float* __restrict__ rinv,
    const unsigned short* __restrict__ BH, const unsigned short* __restrict__ BL,
    unsigned short* __restrict__ OH, unsigned short* __restrict__ OL,
    float* __restrict__ Of) {
  __shared__ __align__(16) float lA[128 * 32];        // XOR-swizzled (16B chunks)
  __shared__ __align__(16) unsigned short lBH[128 * 32];
  __shared__ __align__(16) unsigned short lBL[128 * 32];
  __shared__ float ldsR[128];

  int tid = threadIdx.x;
  int lane = tid & 63, wid = tid >> 6;
  int wr = wid >> 1, wc = wid & 1;
  int fr = lane & 15, fg = lane >> 4;
  long m0 = (long)blockIdx.x * 128;
  long n0 = (long)blockIdx.y * 128;

  if (tid < 128) ldsR[tid] = rinv ? rinv[m0 + tid] : 1.0f;

  f32x4 acc[4][4] = {};

  for (int kk = 0; kk < D_DIM; kk += BK) {
#pragma unroll
    for (int i = 0; i < 4; ++i) {
      int chunk = i * 256 + tid;
      int r = chunk >> 3, c = chunk & 7;
      int cs = c ^ (r & 7);
      const float* src = A + (m0 + r) * (long)D_DIM + kk + cs * 4;
      gload16(src, (void*)(lA + ((i * 256 + (tid & ~63)) << 2)));
    }
#pragma unroll
    for (int i = 0; i < 2; ++i) {
      int chunk = i * 256 + tid;
      int r = chunk >> 2, c = chunk & 3;
      int cs = c ^ ((r >> 1) & 3);
      long boff = (n0 + r) * (long)D_DIM + kk + cs * 8;
      int lo = (i * 256 + (tid & ~63)) << 3;
      gload16(BH + boff, (void*)(lBH + lo));
      gload16(BL + boff, (void*)(lBL + lo));
    }
    __syncthreads();

    bf16x8 aH[4], aL[4], bH[4], bL[4];
#pragma unroll
    for (int m = 0; m < 4; ++m) {
      int row = wr * 64 + m * 16 + fr;
      int rm = row & 7;
      f32x4 p0 = *(const f32x4*)(lA + row * 32 + (((fg * 2 + 0) ^ rm) * 4));
      f32x4 p1 = *(const f32x4*)(lA + row * 32 + (((fg * 2 + 1) ^ rm) * 4));
#pragma unroll
      for (int e = 0; e < 8; ++e) {
        float f = (e < 4) ? p0[e] : p1[e - 4];
        unsigned short h = f2bf(f);
        aH[m][e] = (short)h;
        aL[m][e] = (short)f2bf(f - bf2f(h));
      }
    }
#pragma unroll
    for (int n = 0; n < 4; ++n) {
      int row = wc * 64 + n * 16 + fr;
      int sc = fg ^ ((row >> 1) & 3);
      bH[n] = *(const bf16x8*)(lBH + row * 32 + sc * 8);
      bL[n] = *(const bf16x8*)(lBL + row * 32 + sc * 8);
    }
#pragma unroll
    for (int m = 0; m < 4; ++m)
#pragma unroll
      for (int n = 0; n < 4; ++n) {
        acc[m][n] = __builtin_amdgcn_mfma_f32_16x16x32_bf16(aH[m], bH[n], acc[m][n], 0, 0, 0);
        acc[m][n] = __builtin_amdgcn_mfma_f32_16x16x32_bf16(aH[m], bL[n], acc[m][n], 0, 0, 0);
        acc[m][n] = __builtin_amdgcn_mfma_f32_16x16x32_bf16(aL[m], bH[n], acc[m][n], 0, 0, 0);
      }
    __syncthreads();
  }

#pragma unroll
  for (int m = 0; m < 4; ++m) {
#pragma unroll
    for (int j = 0; j < 4; ++j) {
      int rloc = wr * 64 + m * 16 + fg * 4 + j;
      float rv = ldsR[rloc];
      long grow = m0 + rloc;
#pragma unroll
      for (int n = 0; n < 4; ++n) {
        long gcol = n0 + wc * 64 + n * 16 + fr;
        float v = acc[m][n][j] * rv;
        if (FPOUT) {
          Of[grow * D_DIM + gcol] = v;
        } else {
          unsigned short h = f2bf(v);
          OH[grow * D_DIM + gcol] = h;
          OL[grow * D_DIM + gcol] = f2bf(v - bf2f(h));
        }
      }
    }
  }
}

// ---------------- K3a: APPROX scores, 256^2 / BK=64 / 8-wave phase-split ----------------
// Single dispatch over all M; 1D grid 2048 with bijective XCD swizzle:
// blocks on one XCD share the B (P) column panel.
__global__ __launch_bounds__(512, 2) void gemm_scores1_k(
    const unsigned short* __restrict__ XH, const unsigned short* __restrict__ PH,
    const float* __restrict__ rinvA, unsigned* __restrict__ gmax) {
  __shared__ __align__(16) unsigned short lA[2][256 * 64];
  __shared__ __align__(16) unsigned short lB[2][256 * 64];
  __shared__ float ldsR[256];

  int tid = threadIdx.x;                 // 0..511
  int lane = tid & 63, wid = tid >> 6;   // 8 waves
  int wr = wid >> 2;                     // 0..1  (M half)
  int wcn = wid & 3;                     // 0..3  (N quarter)
  int fr = lane & 15, fg = lane >> 4;

  // T1: grid 2048 = 8 XCDs x 256; same-XCD blocks iterate M with fixed N panel.
  int id = blockIdx.x;
  int swz = (id & 7) * 256 + (id >> 3);
  int tile_n = swz >> 7;                 // 0..15
  int tile_m = swz & 127;                // 0..127
  long m0 = (long)tile_m * 256;
  long n0 = (long)tile_n * 256;

  if (tid < 256) ldsR[tid] = rinvA[m0 + tid];

  auto stageTile = [&](int buf, int kt) {
    int kk = kt * 64;
#pragma unroll
    for (int h = 0; h < 2; ++h)
#pragma unroll
      for (int i = 0; i < 2; ++i) {
        int chunk = h * 1024 + i * 512 + tid;      // 2048 chunks of 16B
        int r = chunk >> 3, c = chunk & 7;
        int cs = c ^ (r & 7);                      // pre-swizzled source
        gload16(XH + (m0 + r) * (long)D_DIM + kk + cs * 8,
                (void*)(&lA[buf][0] + ((h * 1024 + i * 512 + (tid & ~63)) << 3)));
      }
#pragma unroll
    for (int h = 0; h < 2; ++h)
#pragma unroll
      for (int i = 0; i < 2; ++i) {
        int chunk = h * 1024 + i * 512 + tid;
        int r = chunk >> 3, c = chunk & 7;
        int cs = c ^ (r & 7);
        gload16(PH + (n0 + r) * (long)D_DIM + kk + cs * 8,
                (void*)(&lB[buf][0] + ((h * 1024 + i * 512 + (tid & ~63)) << 3)));
      }
  };

  f32x4 acc[8][4] = {};

  stageTile(0, 0);
  stageTile(1, 1);
  asm volatile("s_waitcnt lgkmcnt(0)" ::: "memory");  // ldsR visible at barrier

  bf16x8 aF[4][2], bF[4][2];

  for (int kt = 0; kt < 16; ++kt) {
    int cur = kt & 1;
    const unsigned short* As = &lA[cur][0];
    const unsigned short* Bs = &lB[cur][0];

    if (kt < 15) {
      asm volatile("s_waitcnt vmcnt(8)" ::: "memory");
    } else {
      asm volatile("s_waitcnt vmcnt(0)" ::: "memory");
    }
    __builtin_amdgcn_s_barrier();

    // ---- P1: read A[m 0..3] + B[n 0..1]; MFMA (m0-3, n0-1)
#pragma unroll
    for (int mi = 0; mi < 4; ++mi)
#pragma unroll
      for (int ks = 0; ks < 2; ++ks) {
        int row = wr * 128 + mi * 16 + fr;
        int ck = (ks * 4 + fg) ^ (row & 7);
        aF[mi][ks] = *(const bf16x8*)(As + row * 64 + ck * 8);
      }
#pragma unroll
    for (int ni = 0; ni < 2; ++ni)
#pragma unroll
      for (int ks = 0; ks < 2; ++ks) {
        int row = wcn * 64 + ni * 16 + fr;
        int ck = (ks * 4 + fg) ^ (row & 7);
        bF[ni][ks] = *(const bf16x8*)(Bs + row * 64 + ck * 8);
      }
    LGK0_SB();
    __builtin_amdgcn_s_setprio(1);
#pragma unroll
    for (int mi = 0; mi < 4; ++mi)
#pragma unroll
      for (int ni = 0; ni < 2; ++ni)
#pragma unroll
        for (int ks = 0; ks < 2; ++ks)
          acc[mi][ni] = __builtin_amdgcn_mfma_f32_16x16x32_bf16(
              aF[mi][ks], bF[ni][ks], acc[mi][ni], 0, 0, 0);
    __builtin_amdgcn_s_setprio(0);

    // ---- P2: read B[n 2..3]; MFMA (m0-3, n2-3)
#pragma unroll
    for (int ni = 2; ni < 4; ++ni)
#pragma unroll
      for (int ks = 0; ks < 2; ++ks) {
        int row = wcn * 64 + ni * 16 + fr;
        int ck = (ks * 4 + fg) ^ (row & 7);
        bF[ni][ks] = *(const bf16x8*)(Bs + row * 64 + ck * 8);
      }
    LGK0_SB();
    __builtin_amdgcn_s_setprio(1);
#pragma unroll
    for (int mi = 0; mi < 4; ++mi)
#pragma unroll
      for (int ni = 2; ni < 4; ++ni)
#pragma unroll
        for (int ks = 0; ks < 2; ++ks)
          acc[mi][ni] = __builtin_amdgcn_mfma_f32_16x16x32_bf16(
              aF[mi][ks], bF[ni][ks], acc[mi][ni], 0, 0, 0);
    __builtin_amdgcn_s_setprio(0);

    // ---- P3: read A[m 4..7]; barrier closes all reads of buf[cur];
    //          stage(kt+2 -> buf[cur]); MFMA (m4-7, n2-3)
#pragma unroll
    for (int mi = 0; mi < 4; ++mi)
#pragma unroll
      for (int ks = 0; ks < 2; ++ks) {
        int row = wr * 128 + (mi + 4) * 16 + fr;
        int ck = (ks * 4 + fg) ^ (row & 7);
        aF[mi][ks] = *(const bf16x8*)(As + row * 64 + ck * 8);
      }
    LGK0_SB();
    __builtin_amdgcn_s_barrier();
    if (kt + 2 < 16) stageTile(cur, kt + 2);
    __builtin_amdgcn_s_setprio(1);
#pragma unroll
    for (int mi = 0; mi < 4; ++mi)
#pragma unroll
      for (int ni = 2; ni < 4; ++ni)
#pragma unroll
        for (int ks = 0; ks < 2; ++ks)
          acc[mi + 4][ni] = __builtin_amdgcn_mfma_f32_16x16x32_bf16(
              aF[mi][ks], bF[ni][ks], acc[mi + 4][ni], 0, 0, 0);
    __builtin_amdgcn_s_setprio(0);

    // ---- P4: MFMA (m4-7, n0-1), register-only
    __builtin_amdgcn_s_setprio(1);
#pragma unroll
    for (int mi = 0; mi < 4; ++mi)
#pragma unroll
      for (int ni = 0; ni < 2; ++ni)
#pragma unroll
        for (int ks = 0; ks < 2; ++ks)
          acc[mi + 4][ni] = __builtin_amdgcn_mfma_f32_16x16x32_bf16(
              aF[mi][ks], bF[ni][ks], acc[mi + 4][ni], 0, 0, 0);
    __builtin_amdgcn_s_setprio(0);
  }

  // epilogue: rinv per-row, column max over 256 rows, atomicMax.
  int b = (int)(m0 >> 11);
#pragma unroll
  for (int ni = 0; ni < 4; ++ni) {
    float v = -3.0e38f;
#pragma unroll
    for (int mi = 0; mi < 8; ++mi)
#pragma unroll
      for (int j = 0; j < 4; ++j) {
        int row = wr * 128 + mi * 16 + fg * 4 + j;
        v = fmaxf(v, acc[mi][ni][j] * ldsR[row]);
      }
    v = fmaxf(v, __shfl_xor(v, 16));
    v = fmaxf(v, __shfl_xor(v, 32));
    if (fg == 0) {
      long col = n0 + wcn * 64 + ni * 16 + fr;
      atomicMax(&gmax[(long)b * NE + col], encf(v * 0.03125f));
    }
  }
}

// ---------------- K3b: per-batch top-CAND candidate selection (+ zero gmax2) ----------------
__global__ void cand_select_k(const unsigned* __restrict__ gmax,
                              int* __restrict__ candIdx, unsigned* __restrict__ gmax2) {
  __shared__ unsigned enc[NE];
  __shared__ int ic[257];
  int tid = threadIdx.x;
  int lane = tid & 63, w = tid >> 6;
  int zb = blockIdx.x;                     // absolute batch
  if (tid < CAND) gmax2[zb * CAND + tid] = 0u;
  const unsigned* g = gmax + (size_t)zb * NE;
  for (int i = tid; i < NE; i += 256) enc[i] = g[i];
  __syncthreads();

  unsigned cur = 0;
  for (int bit = 31; bit >= 0; --bit) {
    unsigned cand = cur | (1u << bit);
    int c = 0;
    for (int i = tid; i < NE; i += 256) c += (enc[i] >= cand) ? 1 : 0;
    for (int o = 32; o > 0; o >>= 1) c += __shfl_xor(c, o);
    __syncthreads();
    if (lane == 0) ic[w] = c;
    __syncthreads();
    int tot = ic[0] + ic[1] + ic[2] + ic[3];
    if (tot >= CAND) cur = cand;
  }

  int myc = 0;
  for (int i = tid; i < NE; i += 256) myc += (enc[i] >= cur) ? 1 : 0;
  __syncthreads();
  ic[tid] = myc;
  __syncthreads();
  if (tid == 0) {
    int s = 0;
    for (int t = 0; t < 256; ++t) { int v = ic[t]; ic[t] = s; s += v; }
  }
  __syncthreads();
  int off = ic[tid];
  for (int i = tid; i < NE; i += 256)
    if (enc[i] >= cur) {
      if (off < CAND) candIdx[zb * CAND + off] = i;
      ++off;
    }
}

// ---------------- K3c: gather candidate P rows ----------------
__global__ void gather_k(const unsigned short* __restrict__ PH,
                         const unsigned short* __restrict__ PL,
                         const int* __restrict__ candIdx,
                         unsigned short* __restrict__ cPH,
                         unsigned short* __restrict__ cPL) {
  int j = blockIdx.x;
  int zb = blockIdx.y;                     // absolute batch
  int n = candIdx[zb * CAND + j];
  int t4 = threadIdx.x * 4;
  size_t dst = ((size_t)(zb * CAND + j)) * D_DIM + t4;
  size_t src = (size_t)n * D_DIM + t4;
  *(ushort4*)(cPH + dst) = *(const ushort4*)(PH + src);
  *(ushort4*)(cPL + dst) = *(const ushort4*)(PL + src);
}

// ---------------- K3d: EXACT rescore (all 16 batches) ----------------
__global__ __launch_bounds__(256, 2) void gemm_rescore_k(
    const float* __restrict__ X, const float* __restrict__ rinvA,
    const unsigned short* __restrict__ cPH, const unsigned short* __restrict__ cPL,
    unsigned* __restrict__ gmax2) {
  __shared__ __align__(16) float lA[128 * 32];
  __shared__ __align__(16) unsigned short lBH[128 * 32], lBL[128 * 32];
  __shared__ float ldsR[128];

  int tid = threadIdx.x;
  int lane = tid & 63, wid = tid >> 6;
  int wr = wid >> 1, wc = wid & 1;
  int fr = lane & 15, fg = lane >> 4;
  int z = blockIdx.z;
  long m0 = (long)blockIdx.x * 128;
  long arow0 = (long)z * SEQ + m0;
  long brow0 = (long)z * CAND;

  if (tid < 128) ldsR[tid] = rinvA[arow0 + tid];

  f32x4 acc[4][4] = {};

  for (int kk = 0; kk < D_DIM; kk += BK) {
#pragma unroll
    for (int i = 0; i < 4; ++i) {
      int chunk = i * 256 + tid;
      int r = chunk >> 3, c = chunk & 7;
      int cs = c ^ (r & 7);
      const float* src = X + (arow0 + r) * (long)D_DIM + kk + cs * 4;
      gload16(src, (void*)(lA + ((i * 256 + (tid & ~63)) << 2)));
    }
#pragma unroll
    for (int i = 0; i < 2; ++i) {
      int chunk = i * 256 + tid;
      int r = chunk >> 2, c = chunk & 3;
      int cs = c ^ ((r >> 1) & 3);
      long boff = (brow0 + r) * (long)D_DIM + kk + cs * 8;
      int lo = (i * 256 + (tid & ~63)) << 3;
      gload16(cPH + boff, (void*)(lBH + lo));
      gload16(cPL + boff, (void*)(lBL + lo));
    }
    __syncthreads();

    bf16x8 aH[4], aL[4], bH[4], bL[4];
#pragma unroll
    for (int m = 0; m < 4; ++m) {
      int row = wr * 64 + m * 16 + fr;
      int rm = row & 7;
      f32x4 p0 = *(const f32x4*)(lA + row * 32 + (((fg * 2 + 0) ^ rm) * 4));
      f32x4 p1 = *(const f32x4*)(lA + row * 32 + (((fg * 2 + 1) ^ rm) * 4));
#pragma unroll
      for (int e = 0; e < 8; ++e) {
        float f = (e < 4) ? p0[e] : p1[e - 4];
        unsigned short h = f2bf(f);
        aH[m][e] = (short)h;
        aL[m][e] = (short)f2bf(f - bf2f(h));
      }
    }
#pragma unroll
    for (int n = 0; n < 4; ++n) {
      int row = wc * 64 + n * 16 + fr;
      int sc = fg ^ ((row >> 1) & 3);
      bH[n] = *(const bf16x8*)(lBH + row * 32 + sc * 8);
      bL[n] = *(const bf16x8*)(lBL + row * 32 + sc * 8);
    }
#pragma unroll
    for (int m = 0; m < 4; ++m)
#pragma unroll
      for (int n = 0; n < 4; ++n) {
        acc[m][n] = __builtin_amdgcn_mfma_f32_16x16x32_bf16(aH[m], bH[n], acc[m][n], 0, 0, 0);
        acc[m][n] = __builtin_amdgcn_mfma_f32_16x16x32_bf16(aH[m], bL[n], acc[m][n], 0, 0, 0);
        acc[m][n] = __builtin_amdgcn_mfma_f32_16x16x32_bf16(aL[m], bH[n], acc[m][n], 0, 0, 0);
      }
    __syncthreads();
  }

#pragma unroll
  for (int n = 0; n < 4; ++n) {
    float v = -3.0e38f;
#pragma unroll
    for (int m = 0; m < 4; ++m)
#pragma unroll
      for (int j = 0; j < 4; ++j) {
        float rv = ldsR[wr * 64 + m * 16 + fg * 4 + j];
        v = fmaxf(v, acc[m][n][j] * rv);
      }
    v = fmaxf(v, __shfl_xor(v, 16));
    v = fmaxf(v, __shfl_xor(v, 32));
    if (fg == 0) {
      int col = wc * 64 + n * 16 + fr;   // 0..127
      atomicMax(&gmax2[z * CAND + col], encf(v * 0.03125f));
    }
  }
}

// ---------------- K3e: scatter exact candidate values over approx gmax ----------------
__global__ void scatter_k(const unsigned* __restrict__ gmax2,
                          const int* __restrict__ candIdx,
                          unsigned* __restrict__ gmax) {
  int z = blockIdx.x, j = threadIdx.x;   // absolute batch, candidate
  int n = candIdx[z * CAND + j];
  gmax[(size_t)z * NE + n] = gmax2[z * CAND + j];
}

// ---------------- K4: per-batch exact top-64 cutoff + softmax weights ----------------
__global__ void topk_weights_k(const unsigned* __restrict__ gmax,
                               const float* __restrict__ alpha_p,
                               float* __restrict__ wout, int* __restrict__ idx,
                               int* __restrict__ cnt) {
  __shared__ unsigned enc[NE];
  __shared__ unsigned ubc[4];
  __shared__ float l4[4];
  __shared__ int ic[257];
  int tid = threadIdx.x;
  int lane = tid & 63, w = tid >> 6;
  const unsigned* g = gmax + (size_t)blockIdx.x * NE;
  for (int i = tid; i < NE; i += 256) enc[i] = g[i];
  __syncthreads();

  unsigned mx = 0;
  for (int i = tid; i < NE; i += 256) mx = enc[i] > mx ? enc[i] : mx;
  for (int o = 32; o > 0; o >>= 1) {
    unsigned other = (unsigned)__shfl_xor((int)mx, o);
    if (other > mx) mx = other;
  }
  if (lane == 0) ubc[w] = mx;
  __syncthreads();
  unsigned m1e = ubc[0];
  for (int t = 1; t < 4; ++t) m1e = ubc[t] > m1e ? ubc[t] : m1e;
  float m1 = decf(m1e);

  unsigned cur = 0;
  for (int bit = 31; bit >= 0; --bit) {
    unsigned cand = cur | (1u << bit);
    int c = 0;
    for (int i = tid; i < NE; i += 256) c += (enc[i] >= cand) ? 1 : 0;
    for (int o = 32; o > 0; o >>= 1) c += __shfl_xor(c, o);
    __syncthreads();
    if (lane == 0) ic[w] = c;
    __syncthreads();
    int tot = ic[0] + ic[1] + ic[2] + ic[3];
    if (tot >= KTOP) cur = cand;
  }

  float sd = 0.f, ssum = 0.f;
  for (int i = tid; i < NE; i += 256) {
    float e = expf(decf(enc[i]) - m1);
    sd += e;
    if (enc[i] >= cur) ssum += e;
  }
  for (int o = 32; o > 0; o >>= 1) { sd += __shfl_xor(sd, o); ssum += __shfl_xor(ssum, o); }
  __syncthreads();
  if (lane == 0) { l4[w] = sd; }
  __syncthreads();
  float SD = l4[0] + l4[1] + l4[2] + l4[3];
  __syncthreads();
  if (lane == 0) { l4[w] = ssum; }
  __syncthreads();
  float SS = l4[0] + l4[1] + l4[2] + l4[3];

  float alpha = alpha_p[0];
  float wd = alpha / SD;
  float ws_ = (1.0f - alpha) / SS;
  for (int i = tid; i < NE; i += 256) {
    float e = expf(decf(enc[i]) - m1);
    float wv = wd * e + ((enc[i] >= cur) ? ws_ * e : 0.0f);
    wout[(size_t)blockIdx.x * NE + i] = wv;
  }

  int myc = 0;
  for (int i = tid; i < NE; i += 256) myc += (enc[i] >= cur) ? 1 : 0;
  __syncthreads();
  ic[tid] = myc;
  __syncthreads();
  if (tid == 0) {
    int s = 0;
    for (int t = 0; t < 256; ++t) { int v = ic[t]; ic[t] = s; s += v; }
    ic[256] = s;
    cnt[blockIdx.x] = s;
  }
  __syncthreads();
  int off = ic[tid];
  for (int i = tid; i < NE; i += 256)
    if (enc[i] >= cur) idx[(size_t)blockIdx.x * NE + (off++)] = i;
}

// ---------------- K5: O = rmsnorm(weights @ En, on_w) ----------------
__global__ void out_o_k(const float* __restrict__ wts, const float* __restrict__ E,
                        const float* __restrict__ rinvE, const float* __restrict__ sn_w,
                        const float* __restrict__ on_w, const float* __restrict__ alpha_p,
                        const int* __restrict__ idx, const int* __restrict__ cnt,
                        float* __restrict__ O) {
  __shared__ float l4[4];
  int b = blockIdx.x, tid = threadIdx.x;
  float acc[4] = {0.f, 0.f, 0.f, 0.f};
  float alpha = alpha_p[0];
  if (alpha == 0.0f) {
    int nsel = cnt[b];
    for (int j = 0; j < nsel; ++j) {
      int n = idx[(size_t)b * NE + j];
      float wv = wts[(size_t)b * NE + n] * rinvE[n];
      const float* er = E + (size_t)n * D_DIM;
#pragma unroll
      for (int i = 0; i < 4; ++i) acc[i] += wv * er[tid + 256 * i];
    }
  } else {
    for (int n = 0; n < NE; ++n) {
      float wv = wts[(size_t)b * NE + n] * rinvE[n];
      const float* er = E + (size_t)n * D_DIM;
#pragma unroll
      for (int i = 0; i < 4; ++i) acc[i] += wv * er[tid + 256 * i];
    }
  }
  float ssq = 0.f;
#pragma unroll
  for (int i = 0; i < 4; ++i) {
    acc[i] *= sn_w[tid + 256 * i];
    ssq += acc[i] * acc[i];
  }
  for (int o = 32; o > 0; o >>= 1) ssq += __shfl_xor(ssq, o);
  int lane = tid & 63, w = tid >> 6;
  if (lane == 0) l4[w] = ssq;
  __syncthreads();
  float tot = l4[0] + l4[1] + l4[2] + l4[3];
  float r = rsqrtf(tot * (1.0f / D_DIM) + 1e-6f);
#pragma unroll
  for (int i = 0; i < 4; ++i)
    O[(size_t)b * D_DIM + tid + 256 * i] = acc[i] * r * on_w[tid + 256 * i];
}

}  // namespace

extern "C" void kernel_launch(void* const* d_in, const int* in_sizes, int n_in,
                              void* d_out, int out_size, void* d_ws, size_t ws_size,
                              hipStream_t stream) {
  const float* X     = (const float*)d_in[0];
  const float* alpha = (const float*)d_in[1];
  const float* E     = (const float*)d_in[2];
  const float* Wq    = (const float*)d_in[3];
  const float* Wk    = (const float*)d_in[4];
  const float* xn_w  = (const float*)d_in[5];
  const float* sn_w  = (const float*)d_in[6];
  const float* on_w  = (const float*)d_in[7];
  float* O    = (float*)d_out;                          // [16][1024]
  float* Wout = (float*)d_out + (size_t)BATCH * D_DIM;  // [16][4096]

  char* ws = (char*)d_ws;
  size_t off = 0;
  auto alloc = [&](size_t bytes) {
    char* p = ws + off;
    off += (bytes + 255) & ~(size_t)255;
    return p;
  };
  unsigned short* XH    = (unsigned short*)alloc((size_t)MX * D_DIM * 2);   // 64 MB
  float*          WqTf  = (float*)alloc((size_t)D_DIM * D_DIM * 4);
  unsigned short* WkTH  = (unsigned short*)alloc((size_t)D_DIM * D_DIM * 2);
  unsigned short* WkTL  = (unsigned short*)alloc((size_t)D_DIM * D_DIM * 2);
  unsigned short* W2TH  = (unsigned short*)alloc((size_t)D_DIM * D_DIM * 2);
  unsigned short* W2TL  = (unsigned short*)alloc((size_t)D_DIM * D_DIM * 2);
  unsigned short* PH    = (unsigned short*)alloc((size_t)NE * D_DIM * 2);
  unsigned short* PL    = (unsigned short*)alloc((size_t)NE * D_DIM * 2);
  unsigned short* cPH   = (unsigned short*)alloc((size_t)BATCH * CAND * D_DIM * 2);
  unsigned short* cPL   = (unsigned short*)alloc((size_t)BATCH * CAND * D_DIM * 2);
  float* rinvX = (float*)alloc((size_t)MX * 4);
  float* rinvE = (float*)alloc((size_t)NE * 4);
  unsigned* gmax  = (unsigned*)alloc((size_t)BATCH * NE * 4);
  unsigned* gmax2 = (unsigned*)alloc((size_t)BATCH * CAND * 4);
  int* candIdx = (int*)alloc((size_t)BATCH * CAND * 4);
  int* idx = (int*)alloc((size_t)BATCH * NE * 4);
  int* cnt = (int*)alloc((size_t)BATCH * 4);
  if (off > ws_size) return;  // needs ~100 MB scratch

  hipMemsetAsync(gmax, 0, (size_t)BATCH * NE * 4, stream);

  row_rinv_k<<<NE, 256, 0, stream>>>(E, rinvE);
  transpose_k<<<dim3(D_DIM / 32, D_DIM / 32), 256, 0, stream>>>(Wq, WqTf);
  // WkT'[d][k] = Wk[k][d]*sn_w[d]  (split bf16)
  split_wt_k<<<dim3(D_DIM / 32, D_DIM / 32), 256, 0, stream>>>(Wk, sn_w, WkTH, WkTL);
  // W2T[j][d] = xn_w[j] * sum_k WqT[j,k] * WkT'[d,k]   (1024^2, 3-product)
  gemm_a32_k<0><<<dim3(8, 8), 256, 0, stream>>>(
      WqTf, xn_w, WkTH, WkTL, W2TH, W2TL, nullptr);
  // P'[n][j] = sum_d (E[n,d]*rinvE[n]) * W2T[j,d]      (4096x1024, 3-product)
  gemm_a32_k<0><<<dim3(NE / 128, D_DIM / 128), 256, 0, stream>>>(
      E, rinvE, W2TH, W2TL, PH, PL, nullptr);

  // all-M: rinv + bf16(X)
  rinv_splitx_k<<<MX, 256, 0, stream>>>(X, rinvX, XH);
  // approx scores, single dispatch (2048 blocks, XCD-swizzled)
  gemm_scores1_k<<<(MX / 256) * (NE / 256), 512, 0, stream>>>(XH, PH, rinvX, gmax);

  cand_select_k<<<BATCH, 256, 0, stream>>>(gmax, candIdx, gmax2);
  gather_k<<<dim3(CAND, BATCH), 256, 0, stream>>>(PH, PL, candIdx, cPH, cPL);
  gemm_rescore_k<<<dim3(SEQ / 128, 1, BATCH), 256, 0, stream>>>(
      X, rinvX, cPH, cPL, gmax2);
  scatter_k<<<BATCH, CAND, 0, stream>>>(gmax2, candIdx, gmax);

  topk_weights_k<<<BATCH, 256, 0, stream>>>(gmax, alpha, Wout, idx, cnt);
  out_o_k<<<BATCH, 256, 0, stream>>>(Wout, E, rinvE, sn_w, on_w, alpha, idx, cnt, O);
}

// Round 9
// 511.428 us; speedup vs baseline: 2.4038x; 1.0030x over previous
//
#include <hip/hip_runtime.h>

// BasisAttention: B=16,S=2048,D=1024,N=4096,K_TOP=64. fp32 in/out.
// R2: XOR chunk-swizzle. R4: approx-then-rescore. R5: scores = Xn@(Km Wq)^T.
// R7: scores1 = 256^2/BK=64/8-wave phase-split pipeline (T2+T3+T4+T5).
// R8: weight-chain fusion (W2T 1024^2 GEMM); de-chunked single scores1 dispatch.
// R9: XCD swizzle DIRECTION fixed: R8 gave each XCD an N-panel x all-M ->
//     every XCD streamed all 64MB of XH (FETCH 542MB). Now m-strip-per-XCD,
//     n-fast: same-XCD blocks share the XH strip in L2 (A >> B).

namespace {

constexpr int D_DIM = 1024;
constexpr int NE    = 4096;
constexpr int BATCH = 16;
constexpr int SEQ   = 2048;
constexpr int MX    = BATCH * SEQ;   // 32768
constexpr int KTOP  = 64;
constexpr int CAND  = 128;           // candidates per batch
constexpr int BK    = 32;

using f32x4  = __attribute__((ext_vector_type(4))) float;
using bf16x8 = __attribute__((ext_vector_type(8))) short;

__device__ inline unsigned encf(float f) {
  unsigned u = __float_as_uint(f);
  return (u & 0x80000000u) ? ~u : (u | 0x80000000u);
}
__device__ inline float decf(unsigned e) {
  unsigned u = (e & 0x80000000u) ? (e ^ 0x80000000u) : ~e;
  return __uint_as_float(u);
}

__device__ inline unsigned short f2bf(float f) {  // RNE float->bf16 bits
  unsigned u = __float_as_uint(f);
  unsigned lsb = (u >> 16) & 1u;
  u += 0x7fffu + lsb;
  return (unsigned short)(u >> 16);
}
__device__ inline float bf2f(unsigned short h) {
  return __uint_as_float(((unsigned)h) << 16);
}

__device__ inline void gload16(const void* gsrc, void* ldst) {
  __builtin_amdgcn_global_load_lds(
      (const __attribute__((address_space(1))) unsigned int*)gsrc,
      (__attribute__((address_space(3))) unsigned int*)ldst, 16, 0, 0);
}

#define LGK0_SB() do { asm volatile("s_waitcnt lgkmcnt(0)" ::: "memory"); \
                       __builtin_amdgcn_sched_barrier(0); } while (0)

// ---------------- K1: per-row rsqrt(mean(x^2)+eps) ----------------
__global__ void row_rinv_k(const float* __restrict__ X, float* __restrict__ rinv) {
  __shared__ float l4[4];
  int row = blockIdx.x;
  float4 v = ((const float4*)(X + (size_t)row * D_DIM))[threadIdx.x];
  float ss = v.x * v.x + v.y * v.y + v.z * v.z + v.w * v.w;
  for (int o = 32; o > 0; o >>= 1) ss += __shfl_xor(ss, o);
  int lane = threadIdx.x & 63, w = threadIdx.x >> 6;
  if (lane == 0) l4[w] = ss;
  __syncthreads();
  if (threadIdx.x == 0) {
    float t = l4[0] + l4[1] + l4[2] + l4[3];
    rinv[row] = rsqrtf(t * (1.0f / D_DIM) + 1e-6f);
  }
}

// ---------------- K1a: fused per-row rinv + bf16(X) ----------------
__global__ void rinv_splitx_k(const float* __restrict__ X, float* __restrict__ rinv,
                              unsigned short* __restrict__ XH) {
  __shared__ float l4[4];
  int row = blockIdx.x;
  float4 v = ((const float4*)(X + (size_t)row * D_DIM))[threadIdx.x];
  float ss = v.x * v.x + v.y * v.y + v.z * v.z + v.w * v.w;
  for (int o = 32; o > 0; o >>= 1) ss += __shfl_xor(ss, o);
  int lane = threadIdx.x & 63, w = threadIdx.x >> 6;
  if (lane == 0) l4[w] = ss;
  __syncthreads();
  if (threadIdx.x == 0) {
    float t = l4[0] + l4[1] + l4[2] + l4[3];
    rinv[row] = rsqrtf(t * (1.0f / D_DIM) + 1e-6f);
  }
  ushort4 h = make_ushort4(f2bf(v.x), f2bf(v.y), f2bf(v.z), f2bf(v.w));
  *(ushort4*)(XH + (size_t)row * D_DIM + threadIdx.x * 4) = h;
}

// ---------------- K1c: transpose-split: out[r][c] = W[c][r]*cw[r], bf16 hi/lo ----------------
__global__ void split_wt_k(const float* __restrict__ W, const float* __restrict__ cw,
                           unsigned short* __restrict__ H, unsigned short* __restrict__ L) {
  __shared__ float t[32][33];
  int k0 = blockIdx.x * 32, d0 = blockIdx.y * 32;
  int tx = threadIdx.x & 31, ty4 = (threadIdx.x >> 5) * 4;
#pragma unroll
  for (int i = 0; i < 4; ++i)
    t[ty4 + i][tx] = W[(size_t)(d0 + ty4 + i) * D_DIM + k0 + tx];
  __syncthreads();
#pragma unroll
  for (int i = 0; i < 4; ++i) {
    int a = ty4 + i;
    float v = t[tx][a] * cw[k0 + a];       // out[k0+a][d0+tx] = W[d0+tx][k0+a]*cw[k0+a]
    unsigned short h = f2bf(v);
    H[(size_t)(k0 + a) * D_DIM + d0 + tx] = h;
    L[(size_t)(k0 + a) * D_DIM + d0 + tx] = f2bf(v - bf2f(h));
  }
}

// ---------------- K1d: fp32 transpose: T[r][c] = W[c][r] ----------------
__global__ void transpose_k(const float* __restrict__ W, float* __restrict__ T) {
  __shared__ float t[32][33];
  int x0 = blockIdx.x * 32, y0 = blockIdx.y * 32;
  int tx = threadIdx.x & 31, ty4 = (threadIdx.x >> 5) * 4;
#pragma unroll
  for (int i = 0; i < 4; ++i)
    t[ty4 + i][tx] = W[(size_t)(y0 + ty4 + i) * D_DIM + x0 + tx];
  __syncthreads();
#pragma unroll
  for (int i = 0; i < 4; ++i)
    T[(size_t)(x0 + ty4 + i) * D_DIM + y0 + tx] = t[tx][ty4 + i];
}

// ---------------- K2: O = rowscale(A_f32) @ B(hi,lo)^T (3-product) ----------------
// FPOUT=0: split bf16 hi/lo output; FPOUT=1: fp32 output.
template <int FPOUT>
__global__ __launch_bounds__(256, 2) void gemm_a32_k(
    const float* __restrict__ A, const float* __restrict__ rinv,
    const unsigned short* __restrict__ BH, const unsigned short* __restrict__ BL,
    unsigned short* __restrict__ OH, unsigned short* __restrict__ OL,
    float* __restrict__ Of) {
  __shared__ __align__(16) float lA[128 * 32];        // XOR-swizzled (16B chunks)
  __shared__ __align__(16) unsigned short lBH[128 * 32];
  __shared__ __align__(16) unsigned short lBL[128 * 32];
  __shared__ float ldsR[128];

  int tid = threadIdx.x;
  int lane = tid & 63, wid = tid >> 6;
  int wr = wid >> 1, wc = wid & 1;
  int fr = lane & 15, fg = lane >> 4;
  long m0 = (long)blockIdx.x * 128;
  long n0 = (long)blockIdx.y * 128;

  if (tid < 128) ldsR[tid] = rinv ? rinv[m0 + tid] : 1.0f;

  f32x4 acc[4][4] = {};

  for (int kk = 0; kk < D_DIM; kk += BK) {
#pragma unroll
    for (int i = 0; i < 4; ++i) {
      int chunk = i * 256 + tid;
      int r = chunk >> 3, c = chunk & 7;
      int cs = c ^ (r & 7);
      const float* src = A + (m0 + r) * (long)D_DIM + kk + cs * 4;
      gload16(src, (void*)(lA + ((i * 256 + (tid & ~63)) << 2)));
    }
#pragma unroll
    for (int i = 0; i < 2; ++i) {
      int chunk = i * 256 + tid;
      int r = chunk >> 2, c = chunk & 3;
      int cs = c ^ ((r >> 1) & 3);
      long boff = (n0 + r) * (long)D_DIM + kk + cs * 8;
      int lo = (i * 256 + (tid & ~63)) << 3;
      gload16(BH + boff, (void*)(lBH + lo));
      gload16(BL + boff, (void*)(lBL + lo));
    }
    __syncthreads();

    bf16x8 aH[4], aL[4], bH[4], bL[4];
#pragma unroll
    for (int m = 0; m < 4; ++m) {
      int row = wr * 64 + m * 16 + fr;
      int rm = row & 7;
      f32x4 p0 = *(const f32x4*)(lA + row * 32 + (((fg * 2 + 0) ^ rm) * 4));
      f32x4 p1 = *(const f32x4*)(lA + row * 32 + (((fg * 2 + 1) ^ rm) * 4));
#pragma unroll
      for (int e = 0; e < 8; ++e) {
        float f = (e < 4) ? p0[e] : p1[e - 4];
        unsigned short h = f2bf(f);
        aH[m][e] = (short)h;
        aL[m][e] = (short)f2bf(f - bf2f(h));
      }
    }
#pragma unroll
    for (int n = 0; n < 4; ++n) {
      int row = wc * 64 + n * 16 + fr;
      int sc = fg ^ ((row >> 1) & 3);
      bH[n] = *(const bf16x8*)(lBH + row * 32 + sc * 8);
      bL[n] = *(const bf16x8*)(lBL + row * 32 + sc * 8);
    }
#pragma unroll
    for (int m = 0; m < 4; ++m)
#pragma unroll
      for (int n = 0; n < 4; ++n) {
        acc[m][n] = __builtin_amdgcn_mfma_f32_16x16x32_bf16(aH[m], bH[n], acc[m][n], 0, 0, 0);
        acc[m][n] = __builtin_amdgcn_mfma_f32_16x16x32_bf16(aH[m], bL[n], acc[m][n], 0, 0, 0);
        acc[m][n] = __builtin_amdgcn_mfma_f32_16x16x32_bf16(aL[m], bH[n], acc[m][n], 0, 0, 0);
      }
    __syncthreads();
  }

#pragma unroll
  for (int m = 0; m < 4; ++m) {
#pragma unroll
    for (int j = 0; j < 4; ++j) {
      int rloc = wr * 64 + m * 16 + fg * 4 + j;
      float rv = ldsR[rloc];
      long grow = m0 + rloc;
#pragma unroll
      for (int n = 0; n < 4; ++n) {
        long gcol = n0 + wc * 64 + n * 16 + fr;
        float v = acc[m][n][j] * rv;
        if (FPOUT) {
          Of[grow * D_DIM + gcol] = v;
        } else {
          unsigned short h = f2bf(v);
          OH[grow * D_DIM + gcol] = h;
          OL[grow * D_DIM + gcol] = f2bf(v - bf2f(h));
        }
      }
    }
  }
}

// ---------------- K3a: APPROX scores, 256^2 / BK=64 / 8-wave phase-split ----------------
// Single dispatch; m-strip-per-XCD swizzle (A-sharing): xcd owns 16 m-tiles,
// iterates n fast so concurrent same-XCD blocks share the XH strip in L2.
__global__ __launch_bounds__(512, 2) void gemm_scores1_k(
    const unsigned short* __restrict__ XH, const unsigned short* __restrict__ PH,
    const float* __restrict__ rinvA, unsigned* __restrict__ gmax) {
  __shared__ __align__(16) unsigned short lA[2][256 * 64];
  __shared__ __align__(16) unsigned short lB[2][256 * 64];
  __shared__ float ldsR[256];

  int tid = threadIdx.x;                 // 0..511
  int lane = tid & 63, wid = tid >> 6;   // 8 waves
  int wr = wid >> 2;                     // 0..1  (M half)
  int wcn = wid & 3;                     // 0..3  (N quarter)
  int fr = lane & 15, fg = lane >> 4;

  // R9 swizzle: xcd = id&7 owns m-tiles [xcd*16, xcd*16+16); n varies fastest.
  int id = blockIdx.x;
  int xcd = id & 7;
  int r = id >> 3;                       // 0..255
  int tile_m = xcd * 16 + (r >> 4);      // 0..127
  int tile_n = r & 15;                   // 0..15
  long m0 = (long)tile_m * 256;
  long n0 = (long)tile_n * 256;

  if (tid < 256) ldsR[tid] = rinvA[m0 + tid];

  auto stageTile = [&](int buf, int kt) {
    int kk = kt * 64;
#pragma unroll
    for (int h = 0; h < 2; ++h)
#pragma unroll
      for (int i = 0; i < 2; ++i) {
        int chunk = h * 1024 + i * 512 + tid;      // 2048 chunks of 16B
        int r2 = chunk >> 3, c = chunk & 7;
        int cs = c ^ (r2 & 7);                     // pre-swizzled source
        gload16(XH + (m0 + r2) * (long)D_DIM + kk + cs * 8,
                (void*)(&lA[buf][0] + ((h * 1024 + i * 512 + (tid & ~63)) << 3)));
      }
#pragma unroll
    for (int h = 0; h < 2; ++h)
#pragma unroll
      for (int i = 0; i < 2; ++i) {
        int chunk = h * 1024 + i * 512 + tid;
        int r2 = chunk >> 3, c = chunk & 7;
        int cs = c ^ (r2 & 7);
        gload16(PH + (n0 + r2) * (long)D_DIM + kk + cs * 8,
                (void*)(&lB[buf][0] + ((h * 1024 + i * 512 + (tid & ~63)) << 3)));
      }
  };

  f32x4 acc[8][4] = {};

  stageTile(0, 0);
  stageTile(1, 1);
  asm volatile("s_waitcnt lgkmcnt(0)" ::: "memory");  // ldsR visible at barrier

  bf16x8 aF[4][2], bF[4][2];

  for (int kt = 0; kt < 16; ++kt) {
    int cur = kt & 1;
    const unsigned short* As = &lA[cur][0];
    const unsigned short* Bs = &lB[cur][0];

    if (kt < 15) {
      asm volatile("s_waitcnt vmcnt(8)" ::: "memory");
    } else {
      asm volatile("s_waitcnt vmcnt(0)" ::: "memory");
    }
    __builtin_amdgcn_s_barrier();

    // ---- P1: read A[m 0..3] + B[n 0..1]; MFMA (m0-3, n0-1)
#pragma unroll
    for (int mi = 0; mi < 4; ++mi)
#pragma unroll
      for (int ks = 0; ks < 2; ++ks) {
        int row = wr * 128 + mi * 16 + fr;
        int ck = (ks * 4 + fg) ^ (row & 7);
        aF[mi][ks] = *(const bf16x8*)(As + row * 64 + ck * 8);
      }
#pragma unroll
    for (int ni = 0; ni < 2; ++ni)
#pragma unroll
      for (int ks = 0; ks < 2; ++ks) {
        int row = wcn * 64 + ni * 16 + fr;
        int ck = (ks * 4 + fg) ^ (row & 7);
        bF[ni][ks] = *(const bf16x8*)(Bs + row * 64 + ck * 8);
      }
    LGK0_SB();
    __builtin_amdgcn_s_setprio(1);
#pragma unroll
    for (int mi = 0; mi < 4; ++mi)
#pragma unroll
      for (int ni = 0; ni < 2; ++ni)
#pragma unroll
        for (int ks = 0; ks < 2; ++ks)
          acc[mi][ni] = __builtin_amdgcn_mfma_f32_16x16x32_bf16(
              aF[mi][ks], bF[ni][ks], acc[mi][ni], 0, 0, 0);
    __builtin_amdgcn_s_setprio(0);

    // ---- P2: read B[n 2..3]; MFMA (m0-3, n2-3)
#pragma unroll
    for (int ni = 2; ni < 4; ++ni)
#pragma unroll
      for (int ks = 0; ks < 2; ++ks) {
        int row = wcn * 64 + ni * 16 + fr;
        int ck = (ks * 4 + fg) ^ (row & 7);
        bF[ni][ks] = *(const bf16x8*)(Bs + row * 64 + ck * 8);
      }
    LGK0_SB();
    __builtin_amdgcn_s_setprio(1);
#pragma unroll
    for (int mi = 0; mi < 4; ++mi)
#pragma unroll
      for (int ni = 2; ni < 4; ++ni)
#pragma unroll
        for (int ks = 0; ks < 2; ++ks)
          acc[mi][ni] = __builtin_amdgcn_mfma_f32_16x16x32_bf16(
              aF[mi][ks], bF[ni][ks], acc[mi][ni], 0, 0, 0);
    __builtin_amdgcn_s_setprio(0);

    // ---- P3: read A[m 4..7]; barrier closes all reads of buf[cur];
    //          stage(kt+2 -> buf[cur]); MFMA (m4-7, n2-3)
#pragma unroll
    for (int mi = 0; mi < 4; ++mi)
#pragma unroll
      for (int ks = 0; ks < 2; ++ks) {
        int row = wr * 128 + (mi + 4) * 16 + fr;
        int ck = (ks * 4 + fg) ^ (row & 7);
        aF[mi][ks] = *(const bf16x8*)(As + row * 64 + ck * 8);
      }
    LGK0_SB();
    __builtin_amdgcn_s_barrier();
    if (kt + 2 < 16) stageTile(cur, kt + 2);
    __builtin_amdgcn_s_setprio(1);
#pragma unroll
    for (int mi = 0; mi < 4; ++mi)
#pragma unroll
      for (int ni = 2; ni < 4; ++ni)
#pragma unroll
        for (int ks = 0; ks < 2; ++ks)
          acc[mi + 4][ni] = __builtin_amdgcn_mfma_f32_16x16x32_bf16(
              aF[mi][ks], bF[ni][ks], acc[mi + 4][ni], 0, 0, 0);
    __builtin_amdgcn_s_setprio(0);

    // ---- P4: MFMA (m4-7, n0-1), register-only
    __builtin_amdgcn_s_setprio(1);
#pragma unroll
    for (int mi = 0; mi < 4; ++mi)
#pragma unroll
      for (int ni = 0; ni < 2; ++ni)
#pragma unroll
        for (int ks = 0; ks < 2; ++ks)
          acc[mi + 4][ni] = __builtin_amdgcn_mfma_f32_16x16x32_bf16(
              aF[mi][ks], bF[ni][ks], acc[mi + 4][ni], 0, 0, 0);
    __builtin_amdgcn_s_setprio(0);
  }

  // epilogue: rinv per-row, column max over 256 rows, atomicMax.
  int b = (int)(m0 >> 11);
#pragma unroll
  for (int ni = 0; ni < 4; ++ni) {
    float v = -3.0e38f;
#pragma unroll
    for (int mi = 0; mi < 8; ++mi)
#pragma unroll
      for (int j = 0; j < 4; ++j) {
        int row = wr * 128 + mi * 16 + fg * 4 + j;
        v = fmaxf(v, acc[mi][ni][j] * ldsR[row]);
      }
    v = fmaxf(v, __shfl_xor(v, 16));
    v = fmaxf(v, __shfl_xor(v, 32));
    if (fg == 0) {
      long col = n0 + wcn * 64 + ni * 16 + fr;
      atomicMax(&gmax[(long)b * NE + col], encf(v * 0.03125f));
    }
  }
}

// ---------------- K3b: per-batch top-CAND candidate selection (+ zero gmax2) ----------------
__global__ void cand_select_k(const unsigned* __restrict__ gmax,
                              int* __restrict__ candIdx, unsigned* __restrict__ gmax2) {
  __shared__ unsigned enc[NE];
  __shared__ int ic[257];
  int tid = threadIdx.x;
  int lane = tid & 63, w = tid >> 6;
  int zb = blockIdx.x;                     // absolute batch
  if (tid < CAND) gmax2[zb * CAND + tid] = 0u;
  const unsigned* g = gmax + (size_t)zb * NE;
  for (int i = tid; i < NE; i += 256) enc[i] = g[i];
  __syncthreads();

  unsigned cur = 0;
  for (int bit = 31; bit >= 0; --bit) {
    unsigned cand = cur | (1u << bit);
    int c = 0;
    for (int i = tid; i < NE; i += 256) c += (enc[i] >= cand) ? 1 : 0;
    for (int o = 32; o > 0; o >>= 1) c += __shfl_xor(c, o);
    __syncthreads();
    if (lane == 0) ic[w] = c;
    __syncthreads();
    int tot = ic[0] + ic[1] + ic[2] + ic[3];
    if (tot >= CAND) cur = cand;
  }

  int myc = 0;
  for (int i = tid; i < NE; i += 256) myc += (enc[i] >= cur) ? 1 : 0;
  __syncthreads();
  ic[tid] = myc;
  __syncthreads();
  if (tid == 0) {
    int s = 0;
    for (int t = 0; t < 256; ++t) { int v = ic[t]; ic[t] = s; s += v; }
  }
  __syncthreads();
  int off = ic[tid];
  for (int i = tid; i < NE; i += 256)
    if (enc[i] >= cur) {
      if (off < CAND) candIdx[zb * CAND + off] = i;
      ++off;
    }
}

// ---------------- K3c: gather candidate P rows ----------------
__global__ void gather_k(const unsigned short* __restrict__ PH,
                         const unsigned short* __restrict__ PL,
                         const int* __restrict__ candIdx,
                         unsigned short* __restrict__ cPH,
                         unsigned short* __restrict__ cPL) {
  int j = blockIdx.x;
  int zb = blockIdx.y;                     // absolute batch
  int n = candIdx[zb * CAND + j];
  int t4 = threadIdx.x * 4;
  size_t dst = ((size_t)(zb * CAND + j)) * D_DIM + t4;
  size_t src = (size_t)n * D_DIM + t4;
  *(ushort4*)(cPH + dst) = *(const ushort4*)(PH + src);
  *(ushort4*)(cPL + dst) = *(const ushort4*)(PL + src);
}

// ---------------- K3d: EXACT rescore (all 16 batches) ----------------
__global__ __launch_bounds__(256, 2) void gemm_rescore_k(
    const float* __restrict__ X, const float* __restrict__ rinvA,
    const unsigned short* __restrict__ cPH, const unsigned short* __restrict__ cPL,
    unsigned* __restrict__ gmax2) {
  __shared__ __align__(16) float lA[128 * 32];
  __shared__ __align__(16) unsigned short lBH[128 * 32], lBL[128 * 32];
  __shared__ float ldsR[128];

  int tid = threadIdx.x;
  int lane = tid & 63, wid = tid >> 6;
  int wr = wid >> 1, wc = wid & 1;
  int fr = lane & 15, fg = lane >> 4;
  int z = blockIdx.z;
  long m0 = (long)blockIdx.x * 128;
  long arow0 = (long)z * SEQ + m0;
  long brow0 = (long)z * CAND;

  if (tid < 128) ldsR[tid] = rinvA[arow0 + tid];

  f32x4 acc[4][4] = {};

  for (int kk = 0; kk < D_DIM; kk += BK) {
#pragma unroll
    for (int i = 0; i < 4; ++i) {
      int chunk = i * 256 + tid;
      int r = chunk >> 3, c = chunk & 7;
      int cs = c ^ (r & 7);
      const float* src = X + (arow0 + r) * (long)D_DIM + kk + cs * 4;
      gload16(src, (void*)(lA + ((i * 256 + (tid & ~63)) << 2)));
    }
#pragma unroll
    for (int i = 0; i < 2; ++i) {
      int chunk = i * 256 + tid;
      int r = chunk >> 2, c = chunk & 3;
      int cs = c ^ ((r >> 1) & 3);
      long boff = (brow0 + r) * (long)D_DIM + kk + cs * 8;
      int lo = (i * 256 + (tid & ~63)) << 3;
      gload16(cPH + boff, (void*)(lBH + lo));
      gload16(cPL + boff, (void*)(lBL + lo));
    }
    __syncthreads();

    bf16x8 aH[4], aL[4], bH[4], bL[4];
#pragma unroll
    for (int m = 0; m < 4; ++m) {
      int row = wr * 64 + m * 16 + fr;
      int rm = row & 7;
      f32x4 p0 = *(const f32x4*)(lA + row * 32 + (((fg * 2 + 0) ^ rm) * 4));
      f32x4 p1 = *(const f32x4*)(lA + row * 32 + (((fg * 2 + 1) ^ rm) * 4));
#pragma unroll
      for (int e = 0; e < 8; ++e) {
        float f = (e < 4) ? p0[e] : p1[e - 4];
        unsigned short h = f2bf(f);
        aH[m][e] = (short)h;
        aL[m][e] = (short)f2bf(f - bf2f(h));
      }
    }
#pragma unroll
    for (int n = 0; n < 4; ++n) {
      int row = wc * 64 + n * 16 + fr;
      int sc = fg ^ ((row >> 1) & 3);
      bH[n] = *(const bf16x8*)(lBH + row * 32 + sc * 8);
      bL[n] = *(const bf16x8*)(lBL + row * 32 + sc * 8);
    }
#pragma unroll
    for (int m = 0; m < 4; ++m)
#pragma unroll
      for (int n = 0; n < 4; ++n) {
        acc[m][n] = __builtin_amdgcn_mfma_f32_16x16x32_bf16(aH[m], bH[n], acc[m][n], 0, 0, 0);
        acc[m][n] = __builtin_amdgcn_mfma_f32_16x16x32_bf16(aH[m], bL[n], acc[m][n], 0, 0, 0);
        acc[m][n] = __builtin_amdgcn_mfma_f32_16x16x32_bf16(aL[m], bH[n], acc[m][n], 0, 0, 0);
      }
    __syncthreads();
  }

#pragma unroll
  for (int n = 0; n < 4; ++n) {
    float v = -3.0e38f;
#pragma unroll
    for (int m = 0; m < 4; ++m)
#pragma unroll
      for (int j = 0; j < 4; ++j) {
        float rv = ldsR[wr * 64 + m * 16 + fg * 4 + j];
        v = fmaxf(v, acc[m][n][j] * rv);
      }
    v = fmaxf(v, __shfl_xor(v, 16));
    v = fmaxf(v, __shfl_xor(v, 32));
    if (fg == 0) {
      int col = wc * 64 + n * 16 + fr;   // 0..127
      atomicMax(&gmax2[z * CAND + col], encf(v * 0.03125f));
    }
  }
}

// ---------------- K3e: scatter exact candidate values over approx gmax ----------------
__global__ void scatter_k(const unsigned* __restrict__ gmax2,
                          const int* __restrict__ candIdx,
                          unsigned* __restrict__ gmax) {
  int z = blockIdx.x, j = threadIdx.x;   // absolute batch, candidate
  int n = candIdx[z * CAND + j];
  gmax[(size_t)z * NE + n] = gmax2[z * CAND + j];
}

// ---------------- K4: per-batch exact top-64 cutoff + softmax weights ----------------
__global__ void topk_weights_k(const unsigned* __restrict__ gmax,
                               const float* __restrict__ alpha_p,
                               float* __restrict__ wout, int* __restrict__ idx,
                               int* __restrict__ cnt) {
  __shared__ unsigned enc[NE];
  __shared__ unsigned ubc[4];
  __shared__ float l4[4];
  __shared__ int ic[257];
  int tid = threadIdx.x;
  int lane = tid & 63, w = tid >> 6;
  const unsigned* g = gmax + (size_t)blockIdx.x * NE;
  for (int i = tid; i < NE; i += 256) enc[i] = g[i];
  __syncthreads();

  unsigned mx = 0;
  for (int i = tid; i < NE; i += 256) mx = enc[i] > mx ? enc[i] : mx;
  for (int o = 32; o > 0; o >>= 1) {
    unsigned other = (unsigned)__shfl_xor((int)mx, o);
    if (other > mx) mx = other;
  }
  if (lane == 0) ubc[w] = mx;
  __syncthreads();
  unsigned m1e = ubc[0];
  for (int t = 1; t < 4; ++t) m1e = ubc[t] > m1e ? ubc[t] : m1e;
  float m1 = decf(m1e);

  unsigned cur = 0;
  for (int bit = 31; bit >= 0; --bit) {
    unsigned cand = cur | (1u << bit);
    int c = 0;
    for (int i = tid; i < NE; i += 256) c += (enc[i] >= cand) ? 1 : 0;
    for (int o = 32; o > 0; o >>= 1) c += __shfl_xor(c, o);
    __syncthreads();
    if (lane == 0) ic[w] = c;
    __syncthreads();
    int tot = ic[0] + ic[1] + ic[2] + ic[3];
    if (tot >= KTOP) cur = cand;
  }

  float sd = 0.f, ssum = 0.f;
  for (int i = tid; i < NE; i += 256) {
    float e = expf(decf(enc[i]) - m1);
    sd += e;
    if (enc[i] >= cur) ssum += e;
  }
  for (int o = 32; o > 0; o >>= 1) { sd += __shfl_xor(sd, o); ssum += __shfl_xor(ssum, o); }
  __syncthreads();
  if (lane == 0) { l4[w] = sd; }
  __syncthreads();
  float SD = l4[0] + l4[1] + l4[2] + l4[3];
  __syncthreads();
  if (lane == 0) { l4[w] = ssum; }
  __syncthreads();
  float SS = l4[0] + l4[1] + l4[2] + l4[3];

  float alpha = alpha_p[0];
  float wd = alpha / SD;
  float ws_ = (1.0f - alpha) / SS;
  for (int i = tid; i < NE; i += 256) {
    float e = expf(decf(enc[i]) - m1);
    float wv = wd * e + ((enc[i] >= cur) ? ws_ * e : 0.0f);
    wout[(size_t)blockIdx.x * NE + i] = wv;
  }

  int myc = 0;
  for (int i = tid; i < NE; i += 256) myc += (enc[i] >= cur) ? 1 : 0;
  __syncthreads();
  ic[tid] = myc;
  __syncthreads();
  if (tid == 0) {
    int s = 0;
    for (int t = 0; t < 256; ++t) { int v = ic[t]; ic[t] = s; s += v; }
    ic[256] = s;
    cnt[blockIdx.x] = s;
  }
  __syncthreads();
  int off = ic[tid];
  for (int i = tid; i < NE; i += 256)
    if (enc[i] >= cur) idx[(size_t)blockIdx.x * NE + (off++)] = i;
}

// ---------------- K5: O = rmsnorm(weights @ En, on_w) ----------------
__global__ void out_o_k(const float* __restrict__ wts, const float* __restrict__ E,
                        const float* __restrict__ rinvE, const float* __restrict__ sn_w,
                        const float* __restrict__ on_w, const float* __restrict__ alpha_p,
                        const int* __restrict__ idx, const int* __restrict__ cnt,
                        float* __restrict__ O) {
  __shared__ float l4[4];
  int b = blockIdx.x, tid = threadIdx.x;
  float acc[4] = {0.f, 0.f, 0.f, 0.f};
  float alpha = alpha_p[0];
  if (alpha == 0.0f) {
    int nsel = cnt[b];
    for (int j = 0; j < nsel; ++j) {
      int n = idx[(size_t)b * NE + j];
      float wv = wts[(size_t)b * NE + n] * rinvE[n];
      const float* er = E + (size_t)n * D_DIM;
#pragma unroll
      for (int i = 0; i < 4; ++i) acc[i] += wv * er[tid + 256 * i];
    }
  } else {
    for (int n = 0; n < NE; ++n) {
      float wv = wts[(size_t)b * NE + n] * rinvE[n];
      const float* er = E + (size_t)n * D_DIM;
#pragma unroll
      for (int i = 0; i < 4; ++i) acc[i] += wv * er[tid + 256 * i];
    }
  }
  float ssq = 0.f;
#pragma unroll
  for (int i = 0; i < 4; ++i) {
    acc[i] *= sn_w[tid + 256 * i];
    ssq += acc[i] * acc[i];
  }
  for (int o = 32; o > 0; o >>= 1) ssq += __shfl_xor(ssq, o);
  int lane = tid & 63, w = tid >> 6;
  if (lane == 0) l4[w] = ssq;
  __syncthreads();
  float tot = l4[0] + l4[1] + l4[2] + l4[3];
  float r = rsqrtf(tot * (1.0f / D_DIM) + 1e-6f);
#pragma unroll
  for (int i = 0; i < 4; ++i)
    O[(size_t)b * D_DIM + tid + 256 * i] = acc[i] * r * on_w[tid + 256 * i];
}

}  // namespace

extern "C" void kernel_launch(void* const* d_in, const int* in_sizes, int n_in,
                              void* d_out, int out_size, void* d_ws, size_t ws_size,
                              hipStream_t stream) {
  const float* X     = (const float*)d_in[0];
  const float* alpha = (const float*)d_in[1];
  const float* E     = (const float*)d_in[2];
  const float* Wq    = (const float*)d_in[3];
  const float* Wk    = (const float*)d_in[4];
  const float* xn_w  = (const float*)d_in[5];
  const float* sn_w  = (const float*)d_in[6];
  const float* on_w  = (const float*)d_in[7];
  float* O    = (float*)d_out;                          // [16][1024]
  float* Wout = (float*)d_out + (size_t)BATCH * D_DIM;  // [16][4096]

  char* ws = (char*)d_ws;
  size_t off = 0;
  auto alloc = [&](size_t bytes) {
    char* p = ws + off;
    off += (bytes + 255) & ~(size_t)255;
    return p;
  };
  unsigned short* XH    = (unsigned short*)alloc((size_t)MX * D_DIM * 2);   // 64 MB
  float*          WqTf  = (float*)alloc((size_t)D_DIM * D_DIM * 4);
  unsigned short* WkTH  = (unsigned short*)alloc((size_t)D_DIM * D_DIM * 2);
  unsigned short* WkTL  = (unsigned short*)alloc((size_t)D_DIM * D_DIM * 2);
  unsigned short* W2TH  = (unsigned short*)alloc((size_t)D_DIM * D_DIM * 2);
  unsigned short* W2TL  = (unsigned short*)alloc((size_t)D_DIM * D_DIM * 2);
  unsigned short* PH    = (unsigned short*)alloc((size_t)NE * D_DIM * 2);
  unsigned short* PL    = (unsigned short*)alloc((size_t)NE * D_DIM * 2);
  unsigned short* cPH   = (unsigned short*)alloc((size_t)BATCH * CAND * D_DIM * 2);
  unsigned short* cPL   = (unsigned short*)alloc((size_t)BATCH * CAND * D_DIM * 2);
  float* rinvX = (float*)alloc((size_t)MX * 4);
  float* rinvE = (float*)alloc((size_t)NE * 4);
  unsigned* gmax  = (unsigned*)alloc((size_t)BATCH * NE * 4);
  unsigned* gmax2 = (unsigned*)alloc((size_t)BATCH * CAND * 4);
  int* candIdx = (int*)alloc((size_t)BATCH * CAND * 4);
  int* idx = (int*)alloc((size_t)BATCH * NE * 4);
  int* cnt = (int*)alloc((size_t)BATCH * 4);
  if (off > ws_size) return;  // needs ~100 MB scratch

  hipMemsetAsync(gmax, 0, (size_t)BATCH * NE * 4, stream);

  row_rinv_k<<<NE, 256, 0, stream>>>(E, rinvE);
  transpose_k<<<dim3(D_DIM / 32, D_DIM / 32), 256, 0, stream>>>(Wq, WqTf);
  // WkT'[d][k] = Wk[k][d]*sn_w[d]  (split bf16)
  split_wt_k<<<dim3(D_DIM / 32, D_DIM / 32), 256, 0, stream>>>(Wk, sn_w, WkTH, WkTL);
  // W2T[j][d] = xn_w[j] * sum_k WqT[j,k] * WkT'[d,k]   (1024^2, 3-product)
  gemm_a32_k<0><<<dim3(8, 8), 256, 0, stream>>>(
      WqTf, xn_w, WkTH, WkTL, W2TH, W2TL, nullptr);
  // P'[n][j] = sum_d (E[n,d]*rinvE[n]) * W2T[j,d]      (4096x1024, 3-product)
  gemm_a32_k<0><<<dim3(NE / 128, D_DIM / 128), 256, 0, stream>>>(
      E, rinvE, W2TH, W2TL, PH, PL, nullptr);

  // all-M: rinv + bf16(X)
  rinv_splitx_k<<<MX, 256, 0, stream>>>(X, rinvX, XH);
  // approx scores, single dispatch (2048 blocks, m-strip-per-XCD swizzle)
  gemm_scores1_k<<<(MX / 256) * (NE / 256), 512, 0, stream>>>(XH, PH, rinvX, gmax);

  cand_select_k<<<BATCH, 256, 0, stream>>>(gmax, candIdx, gmax2);
  gather_k<<<dim3(CAND, BATCH), 256, 0, stream>>>(PH, PL, candIdx, cPH, cPL);
  gemm_rescore_k<<<dim3(SEQ / 128, 1, BATCH), 256, 0, stream>>>(
      X, rinvX, cPH, cPL, gmax2);
  scatter_k<<<BATCH, CAND, 0, stream>>>(gmax2, candIdx, gmax);

  topk_weights_k<<<BATCH, 256, 0, stream>>>(gmax, alpha, Wout, idx, cnt);
  out_o_k<<<BATCH, 256, 0, stream>>>(Wout, E, rinvE, sn_w, on_w, alpha, idx, cnt, O);
}

// Round 10
// 438.338 us; speedup vs baseline: 2.8046x; 1.1667x over previous
//
#include <hip/hip_runtime.h>

// BasisAttention: B=16,S=2048,D=1024,N=4096,K_TOP=64. fp32 in/out.
// R4: approx-then-rescore. R5: scores = Xn@(Km Wq)^T. R7: 256^2 8-wave
// phase-split pipeline. R8: weight-chain fusion + single dispatch.
// R9: m-strip-per-XCD swizzle (FETCH 542->295MB).
// R10: approx pass in INT8 (mfma_i32_16x16x64_i8, 2x rate, half LDS/fetch
//      bytes; LDS 66KB -> 2 blocks/CU). Per-row absmax quant of Xn and P;
//      score err ~0.004 rms vs 0.063 rank gap (15 sigma). Exact bf16-split
//      rescore path unchanged.

namespace {

constexpr int D_DIM = 1024;
constexpr int NE    = 4096;
constexpr int BATCH = 16;
constexpr int SEQ   = 2048;
constexpr int MX    = BATCH * SEQ;   // 32768
constexpr int KTOP  = 64;
constexpr int CAND  = 128;           // candidates per batch
constexpr int BK    = 32;

using f32x4  = __attribute__((ext_vector_type(4))) float;
using bf16x8 = __attribute__((ext_vector_type(8))) short;
using i32x4  = __attribute__((ext_vector_type(4))) int;

__device__ inline unsigned encf(float f) {
  unsigned u = __float_as_uint(f);
  return (u & 0x80000000u) ? ~u : (u | 0x80000000u);
}
__device__ inline float decf(unsigned e) {
  unsigned u = (e & 0x80000000u) ? (e ^ 0x80000000u) : ~e;
  return __uint_as_float(u);
}

__device__ inline unsigned short f2bf(float f) {  // RNE float->bf16 bits
  unsigned u = __float_as_uint(f);
  unsigned lsb = (u >> 16) & 1u;
  u += 0x7fffu + lsb;
  return (unsigned short)(u >> 16);
}
__device__ inline float bf2f(unsigned short h) {
  return __uint_as_float(((unsigned)h) << 16);
}

__device__ inline void gload16(const void* gsrc, void* ldst) {
  __builtin_amdgcn_global_load_lds(
      (const __attribute__((address_space(1))) unsigned int*)gsrc,
      (__attribute__((address_space(3))) unsigned int*)ldst, 16, 0, 0);
}

#define LGK0_SB() do { asm volatile("s_waitcnt lgkmcnt(0)" ::: "memory"); \
                       __builtin_amdgcn_sched_barrier(0); } while (0)

// ---------------- K1: per-row rsqrt(mean(x^2)+eps) ----------------
__global__ void row_rinv_k(const float* __restrict__ X, float* __restrict__ rinv) {
  __shared__ float l4[4];
  int row = blockIdx.x;
  float4 v = ((const float4*)(X + (size_t)row * D_DIM))[threadIdx.x];
  float ss = v.x * v.x + v.y * v.y + v.z * v.z + v.w * v.w;
  for (int o = 32; o > 0; o >>= 1) ss += __shfl_xor(ss, o);
  int lane = threadIdx.x & 63, w = threadIdx.x >> 6;
  if (lane == 0) l4[w] = ss;
  __syncthreads();
  if (threadIdx.x == 0) {
    float t = l4[0] + l4[1] + l4[2] + l4[3];
    rinv[row] = rsqrtf(t * (1.0f / D_DIM) + 1e-6f);
  }
}

// ---------------- K1a: fused per-row rinv + int8 quant of X ----------------
// XQ[row] = round(127*x/amax);  sxr[row] = rinv*amax/127;  rinv[row] kept for rescore.
__global__ void rinv_quantx_k(const float* __restrict__ X, float* __restrict__ rinv,
                              float* __restrict__ sxr, int* __restrict__ XQ) {
  __shared__ float l4[4], m4[4];
  int row = blockIdx.x;
  float4 v = ((const float4*)(X + (size_t)row * D_DIM))[threadIdx.x];
  float ss = v.x * v.x + v.y * v.y + v.z * v.z + v.w * v.w;
  float am = fmaxf(fmaxf(fabsf(v.x), fabsf(v.y)), fmaxf(fabsf(v.z), fabsf(v.w)));
  for (int o = 32; o > 0; o >>= 1) {
    ss += __shfl_xor(ss, o);
    am = fmaxf(am, __shfl_xor(am, o));
  }
  int lane = threadIdx.x & 63, w = threadIdx.x >> 6;
  if (lane == 0) { l4[w] = ss; m4[w] = am; }
  __syncthreads();
  float t  = l4[0] + l4[1] + l4[2] + l4[3];
  float amax = fmaxf(fmaxf(m4[0], m4[1]), fmaxf(m4[2], m4[3]));
  amax = fmaxf(amax, 1e-30f);
  float ri = rsqrtf(t * (1.0f / D_DIM) + 1e-6f);
  if (threadIdx.x == 0) {
    rinv[row] = ri;
    sxr[row]  = ri * amax * (1.0f / 127.0f);
  }
  float qs = 127.0f / amax;
  int q0 = (int)rintf(v.x * qs) & 0xff;
  int q1 = (int)rintf(v.y * qs) & 0xff;
  int q2 = (int)rintf(v.z * qs) & 0xff;
  int q3 = (int)rintf(v.w * qs) & 0xff;
  XQ[(size_t)row * 256 + threadIdx.x] = q0 | (q1 << 8) | (q2 << 16) | (q3 << 24);
}

// ---------------- K1e: int8 quant of P rows (from bf16 hi/lo) ----------------
__global__ void quant_p_k(const unsigned short* __restrict__ PH,
                          const unsigned short* __restrict__ PL,
                          float* __restrict__ sp, int* __restrict__ PQ) {
  __shared__ float m4[4];
  int row = blockIdx.x;
  ushort4 h = *(const ushort4*)(PH + (size_t)row * D_DIM + threadIdx.x * 4);
  ushort4 l = *(const ushort4*)(PL + (size_t)row * D_DIM + threadIdx.x * 4);
  float p0 = bf2f(h.x) + bf2f(l.x);
  float p1 = bf2f(h.y) + bf2f(l.y);
  float p2 = bf2f(h.z) + bf2f(l.z);
  float p3 = bf2f(h.w) + bf2f(l.w);
  float am = fmaxf(fmaxf(fabsf(p0), fabsf(p1)), fmaxf(fabsf(p2), fabsf(p3)));
  for (int o = 32; o > 0; o >>= 1) am = fmaxf(am, __shfl_xor(am, o));
  int lane = threadIdx.x & 63, w = threadIdx.x >> 6;
  if (lane == 0) m4[w] = am;
  __syncthreads();
  float amax = fmaxf(fmaxf(m4[0], m4[1]), fmaxf(m4[2], m4[3]));
  amax = fmaxf(amax, 1e-30f);
  if (threadIdx.x == 0) sp[row] = amax * (1.0f / 127.0f);
  float qs = 127.0f / amax;
  int q0 = (int)rintf(p0 * qs) & 0xff;
  int q1 = (int)rintf(p1 * qs) & 0xff;
  int q2 = (int)rintf(p2 * qs) & 0xff;
  int q3 = (int)rintf(p3 * qs) & 0xff;
  PQ[(size_t)row * 256 + threadIdx.x] = q0 | (q1 << 8) | (q2 << 16) | (q3 << 24);
}

// ---------------- K1c: transpose-split: out[r][c] = W[c][r]*cw[r], bf16 hi/lo ----------------
__global__ void split_wt_k(const float* __restrict__ W, const float* __restrict__ cw,
                           unsigned short* __restrict__ H, unsigned short* __restrict__ L) {
  __shared__ float t[32][33];
  int k0 = blockIdx.x * 32, d0 = blockIdx.y * 32;
  int tx = threadIdx.x & 31, ty4 = (threadIdx.x >> 5) * 4;
#pragma unroll
  for (int i = 0; i < 4; ++i)
    t[ty4 + i][tx] = W[(size_t)(d0 + ty4 + i) * D_DIM + k0 + tx];
  __syncthreads();
#pragma unroll
  for (int i = 0; i < 4; ++i) {
    int a = ty4 + i;
    float v = t[tx][a] * cw[k0 + a];
    unsigned short h = f2bf(v);
    H[(size_t)(k0 + a) * D_DIM + d0 + tx] = h;
    L[(size_t)(k0 + a) * D_DIM + d0 + tx] = f2bf(v - bf2f(h));
  }
}

// ---------------- K1d: fp32 transpose: T[r][c] = W[c][r] ----------------
__global__ void transpose_k(const float* __restrict__ W, float* __restrict__ T) {
  __shared__ float t[32][33];
  int x0 = blockIdx.x * 32, y0 = blockIdx.y * 32;
  int tx = threadIdx.x & 31, ty4 = (threadIdx.x >> 5) * 4;
#pragma unroll
  for (int i = 0; i < 4; ++i)
    t[ty4 + i][tx] = W[(size_t)(y0 + ty4 + i) * D_DIM + x0 + tx];
  __syncthreads();
#pragma unroll
  for (int i = 0; i < 4; ++i)
    T[(size_t)(x0 + ty4 + i) * D_DIM + y0 + tx] = t[tx][ty4 + i];
}

// ---------------- K2: O = rowscale(A_f32) @ B(hi,lo)^T (3-product) ----------------
template <int FPOUT>
__global__ __launch_bounds__(256, 2) void gemm_a32_k(
    const float* __restrict__ A, const float* __restrict__ rinv,
    const unsigned short* __restrict__ BH, const unsigned short* __restrict__ BL,
    unsigned short* __restrict__ OH, unsigned short* __restrict__ OL,
    float* __restrict__ Of) {
  __shared__ __align__(16) float lA[128 * 32];
  __shared__ __align__(16) unsigned short lBH[128 * 32];
  __shared__ __align__(16) unsigned short lBL[128 * 32];
  __shared__ float ldsR[128];

  int tid = threadIdx.x;
  int lane = tid & 63, wid = tid >> 6;
  int wr = wid >> 1, wc = wid & 1;
  int fr = lane & 15, fg = lane >> 4;
  long m0 = (long)blockIdx.x * 128;
  long n0 = (long)blockIdx.y * 128;

  if (tid < 128) ldsR[tid] = rinv ? rinv[m0 + tid] : 1.0f;

  f32x4 acc[4][4] = {};

  for (int kk = 0; kk < D_DIM; kk += BK) {
#pragma unroll
    for (int i = 0; i < 4; ++i) {
      int chunk = i * 256 + tid;
      int r = chunk >> 3, c = chunk & 7;
      int cs = c ^ (r & 7);
      const float* src = A + (m0 + r) * (long)D_DIM + kk + cs * 4;
      gload16(src, (void*)(lA + ((i * 256 + (tid & ~63)) << 2)));
    }
#pragma unroll
    for (int i = 0; i < 2; ++i) {
      int chunk = i * 256 + tid;
      int r = chunk >> 2, c = chunk & 3;
      int cs = c ^ ((r >> 1) & 3);
      long boff = (n0 + r) * (long)D_DIM + kk + cs * 8;
      int lo = (i * 256 + (tid & ~63)) << 3;
      gload16(BH + boff, (void*)(lBH + lo));
      gload16(BL + boff, (void*)(lBL + lo));
    }
    __syncthreads();

    bf16x8 aH[4], aL[4], bH[4], bL[4];
#pragma unroll
    for (int m = 0; m < 4; ++m) {
      int row = wr * 64 + m * 16 + fr;
      int rm = row & 7;
      f32x4 p0 = *(const f32x4*)(lA + row * 32 + (((fg * 2 + 0) ^ rm) * 4));
      f32x4 p1 = *(const f32x4*)(lA + row * 32 + (((fg * 2 + 1) ^ rm) * 4));
#pragma unroll
      for (int e = 0; e < 8; ++e) {
        float f = (e < 4) ? p0[e] : p1[e - 4];
        unsigned short h = f2bf(f);
        aH[m][e] = (short)h;
        aL[m][e] = (short)f2bf(f - bf2f(h));
      }
    }
#pragma unroll
    for (int n = 0; n < 4; ++n) {
      int row = wc * 64 + n * 16 + fr;
      int sc = fg ^ ((row >> 1) & 3);
      bH[n] = *(const bf16x8*)(lBH + row * 32 + sc * 8);
      bL[n] = *(const bf16x8*)(lBL + row * 32 + sc * 8);
    }
#pragma unroll
    for (int m = 0; m < 4; ++m)
#pragma unroll
      for (int n = 0; n < 4; ++n) {
        acc[m][n] = __builtin_amdgcn_mfma_f32_16x16x32_bf16(aH[m], bH[n], acc[m][n], 0, 0, 0);
        acc[m][n] = __builtin_amdgcn_mfma_f32_16x16x32_bf16(aH[m], bL[n], acc[m][n], 0, 0, 0);
        acc[m][n] = __builtin_amdgcn_mfma_f32_16x16x32_bf16(aL[m], bH[n], acc[m][n], 0, 0, 0);
      }
    __syncthreads();
  }

#pragma unroll
  for (int m = 0; m < 4; ++m) {
#pragma unroll
    for (int j = 0; j < 4; ++j) {
      int rloc = wr * 64 + m * 16 + fg * 4 + j;
      float rv = ldsR[rloc];
      long grow = m0 + rloc;
#pragma unroll
      for (int n = 0; n < 4; ++n) {
        long gcol = n0 + wc * 64 + n * 16 + fr;
        float v = acc[m][n][j] * rv;
        if (FPOUT) {
          Of[grow * D_DIM + gcol] = v;
        } else {
          unsigned short h = f2bf(v);
          OH[grow * D_DIM + gcol] = h;
          OL[grow * D_DIM + gcol] = f2bf(v - bf2f(h));
        }
      }
    }
  }
}

// ---------------- K3a: APPROX scores INT8, 256^2 / BK=64 / 8-wave phase-split ----------------
// score = sxr[row]*sp[col]*dot_i32(XQ[row], PQ[col]).  LDS 66KB -> 2 blocks/CU.
__global__ __launch_bounds__(512, 2) void gemm_scores1_k(
    const signed char* __restrict__ XQ, const signed char* __restrict__ PQ,
    const float* __restrict__ sxr, const float* __restrict__ sp,
    unsigned* __restrict__ gmax) {
  __shared__ __align__(16) signed char lA[2][256 * 64];
  __shared__ __align__(16) signed char lB[2][256 * 64];
  __shared__ float ldsR[256];

  int tid = threadIdx.x;                 // 0..511
  int lane = tid & 63, wid = tid >> 6;   // 8 waves
  int wr = wid >> 2;                     // 0..1  (M half)
  int wcn = wid & 3;                     // 0..3  (N quarter)
  int fr = lane & 15, fg = lane >> 4;

  // m-strip-per-XCD swizzle (R9)
  int id = blockIdx.x;
  int xcd = id & 7;
  int r = id >> 3;
  int tile_m = xcd * 16 + (r >> 4);      // 0..127
  int tile_n = r & 15;                   // 0..15
  long m0 = (long)tile_m * 256;
  long n0 = (long)tile_n * 256;

  if (tid < 256) ldsR[tid] = sxr[m0 + tid];

  // stage one K-tile: A 256x64B = 1024 chunks, B same; 4 gload16/thread.
  auto stageTile = [&](int buf, int kt) {
    int kk = kt * 64;
#pragma unroll
    for (int i = 0; i < 2; ++i) {
      int chunk = i * 512 + tid;
      int r2 = chunk >> 2, c = chunk & 3;
      int cs = c ^ ((r2 >> 1) & 3);            // pre-swizzled source
      gload16(XQ + (m0 + r2) * (long)D_DIM + kk + cs * 16,
              (void*)(&lA[buf][0] + ((i * 512 + (tid & ~63)) << 4)));
    }
#pragma unroll
    for (int i = 0; i < 2; ++i) {
      int chunk = i * 512 + tid;
      int r2 = chunk >> 2, c = chunk & 3;
      int cs = c ^ ((r2 >> 1) & 3);
      gload16(PQ + (n0 + r2) * (long)D_DIM + kk + cs * 16,
              (void*)(&lB[buf][0] + ((i * 512 + (tid & ~63)) << 4)));
    }
  };

  i32x4 acc[8][4] = {};

  stageTile(0, 0);
  stageTile(1, 1);
  asm volatile("s_waitcnt lgkmcnt(0)" ::: "memory");  // ldsR visible at barrier

  i32x4 aF[4], bF[4];

  for (int kt = 0; kt < 16; ++kt) {
    int cur = kt & 1;
    const signed char* As = &lA[cur][0];
    const signed char* Bs = &lB[cur][0];

    if (kt < 15) {
      asm volatile("s_waitcnt vmcnt(4)" ::: "memory");
    } else {
      asm volatile("s_waitcnt vmcnt(0)" ::: "memory");
    }
    __builtin_amdgcn_s_barrier();

    // ---- P1: read A[m0..3] + B[n0..1]; MFMA (m0-3, n0-1)
#pragma unroll
    for (int mi = 0; mi < 4; ++mi) {
      int row = wr * 128 + mi * 16 + fr;
      int ck = fg ^ ((row >> 1) & 3);
      aF[mi] = *(const i32x4*)(As + row * 64 + ck * 16);
    }
#pragma unroll
    for (int ni = 0; ni < 2; ++ni) {
      int row = wcn * 64 + ni * 16 + fr;
      int ck = fg ^ ((row >> 1) & 3);
      bF[ni] = *(const i32x4*)(Bs + row * 64 + ck * 16);
    }
    LGK0_SB();
    __builtin_amdgcn_s_setprio(1);
#pragma unroll
    for (int mi = 0; mi < 4; ++mi)
#pragma unroll
      for (int ni = 0; ni < 2; ++ni)
        acc[mi][ni] = __builtin_amdgcn_mfma_i32_16x16x64_i8(
            aF[mi], bF[ni], acc[mi][ni], 0, 0, 0);
    __builtin_amdgcn_s_setprio(0);

    // ---- P2: read B[n2..3]; MFMA (m0-3, n2-3)
#pragma unroll
    for (int ni = 2; ni < 4; ++ni) {
      int row = wcn * 64 + ni * 16 + fr;
      int ck = fg ^ ((row >> 1) & 3);
      bF[ni] = *(const i32x4*)(Bs + row * 64 + ck * 16);
    }
    LGK0_SB();
    __builtin_amdgcn_s_setprio(1);
#pragma unroll
    for (int mi = 0; mi < 4; ++mi)
#pragma unroll
      for (int ni = 2; ni < 4; ++ni)
        acc[mi][ni] = __builtin_amdgcn_mfma_i32_16x16x64_i8(
            aF[mi], bF[ni], acc[mi][ni], 0, 0, 0);
    __builtin_amdgcn_s_setprio(0);

    // ---- P3: read A[m4..7]; barrier closes all reads of buf[cur];
    //          stage(kt+2 -> buf[cur]); MFMA (m4-7, n2-3)
#pragma unroll
    for (int mi = 0; mi < 4; ++mi) {
      int row = wr * 128 + (mi + 4) * 16 + fr;
      int ck = fg ^ ((row >> 1) & 3);
      aF[mi] = *(const i32x4*)(As + row * 64 + ck * 16);
    }
    LGK0_SB();
    __builtin_amdgcn_s_barrier();
    if (kt + 2 < 16) stageTile(cur, kt + 2);
    __builtin_amdgcn_s_setprio(1);
#pragma unroll
    for (int mi = 0; mi < 4; ++mi)
#pragma unroll
      for (int ni = 2; ni < 4; ++ni)
        acc[mi + 4][ni] = __builtin_amdgcn_mfma_i32_16x16x64_i8(
            aF[mi], bF[ni], acc[mi + 4][ni], 0, 0, 0);
    __builtin_amdgcn_s_setprio(0);

    // ---- P4: MFMA (m4-7, n0-1), register-only
    __builtin_amdgcn_s_setprio(1);
#pragma unroll
    for (int mi = 0; mi < 4; ++mi)
#pragma unroll
      for (int ni = 0; ni < 2; ++ni)
        acc[mi + 4][ni] = __builtin_amdgcn_mfma_i32_16x16x64_i8(
            aF[mi], bF[ni], acc[mi + 4][ni], 0, 0, 0);
    __builtin_amdgcn_s_setprio(0);
  }

  // epilogue: v = acc*sxr[row]*sp[col]; column max over 256 rows; atomicMax.
  int b = (int)(m0 >> 11);
#pragma unroll
  for (int ni = 0; ni < 4; ++ni) {
    long col = n0 + wcn * 64 + ni * 16 + fr;
    float spc = sp[col];
    float v = -3.0e38f;
#pragma unroll
    for (int mi = 0; mi < 8; ++mi)
#pragma unroll
      for (int j = 0; j < 4; ++j) {
        int row = wr * 128 + mi * 16 + fg * 4 + j;
        v = fmaxf(v, (float)acc[mi][ni][j] * ldsR[row]);
      }
    v *= spc;
    v = fmaxf(v, __shfl_xor(v, 16));
    v = fmaxf(v, __shfl_xor(v, 32));
    if (fg == 0) {
      atomicMax(&gmax[(long)b * NE + col], encf(v * 0.03125f));
    }
  }
}

// ---------------- K3b: per-batch top-CAND candidate selection (+ zero gmax2) ----------------
__global__ void cand_select_k(const unsigned* __restrict__ gmax,
                              int* __restrict__ candIdx, unsigned* __restrict__ gmax2) {
  __shared__ unsigned enc[NE];
  __shared__ int ic[257];
  int tid = threadIdx.x;
  int lane = tid & 63, w = tid >> 6;
  int zb = blockIdx.x;
  if (tid < CAND) gmax2[zb * CAND + tid] = 0u;
  const unsigned* g = gmax + (size_t)zb * NE;
  for (int i = tid; i < NE; i += 256) enc[i] = g[i];
  __syncthreads();

  unsigned cur = 0;
  for (int bit = 31; bit >= 0; --bit) {
    unsigned cand = cur | (1u << bit);
    int c = 0;
    for (int i = tid; i < NE; i += 256) c += (enc[i] >= cand) ? 1 : 0;
    for (int o = 32; o > 0; o >>= 1) c += __shfl_xor(c, o);
    __syncthreads();
    if (lane == 0) ic[w] = c;
    __syncthreads();
    int tot = ic[0] + ic[1] + ic[2] + ic[3];
    if (tot >= CAND) cur = cand;
  }

  int myc = 0;
  for (int i = tid; i < NE; i += 256) myc += (enc[i] >= cur) ? 1 : 0;
  __syncthreads();
  ic[tid] = myc;
  __syncthreads();
  if (tid == 0) {
    int s = 0;
    for (int t = 0; t < 256; ++t) { int v = ic[t]; ic[t] = s; s += v; }
  }
  __syncthreads();
  int off = ic[tid];
  for (int i = tid; i < NE; i += 256)
    if (enc[i] >= cur) {
      if (off < CAND) candIdx[zb * CAND + off] = i;
      ++off;
    }
}

// ---------------- K3c: gather candidate P rows ----------------
__global__ void gather_k(const unsigned short* __restrict__ PH,
                         const unsigned short* __restrict__ PL,
                         const int* __restrict__ candIdx,
                         unsigned short* __restrict__ cPH,
                         unsigned short* __restrict__ cPL) {
  int j = blockIdx.x;
  int zb = blockIdx.y;
  int n = candIdx[zb * CAND + j];
  int t4 = threadIdx.x * 4;
  size_t dst = ((size_t)(zb * CAND + j)) * D_DIM + t4;
  size_t src = (size_t)n * D_DIM + t4;
  *(ushort4*)(cPH + dst) = *(const ushort4*)(PH + src);
  *(ushort4*)(cPL + dst) = *(const ushort4*)(PL + src);
}

// ---------------- K3d: EXACT rescore (all 16 batches) ----------------
__global__ __launch_bounds__(256, 2) void gemm_rescore_k(
    const float* __restrict__ X, const float* __restrict__ rinvA,
    const unsigned short* __restrict__ cPH, const unsigned short* __restrict__ cPL,
    unsigned* __restrict__ gmax2) {
  __shared__ __align__(16) float lA[128 * 32];
  __shared__ __align__(16) unsigned short lBH[128 * 32], lBL[128 * 32];
  __shared__ float ldsR[128];

  int tid = threadIdx.x;
  int lane = tid & 63, wid = tid >> 6;
  int wr = wid >> 1, wc = wid & 1;
  int fr = lane & 15, fg = lane >> 4;
  int z = blockIdx.z;
  long m0 = (long)blockIdx.x * 128;
  long arow0 = (long)z * SEQ + m0;
  long brow0 = (long)z * CAND;

  if (tid < 128) ldsR[tid] = rinvA[arow0 + tid];

  f32x4 acc[4][4] = {};

  for (int kk = 0; kk < D_DIM; kk += BK) {
#pragma unroll
    for (int i = 0; i < 4; ++i) {
      int chunk = i * 256 + tid;
      int r = chunk >> 3, c = chunk & 7;
      int cs = c ^ (r & 7);
      const float* src = X + (arow0 + r) * (long)D_DIM + kk + cs * 4;
      gload16(src, (void*)(lA + ((i * 256 + (tid & ~63)) << 2)));
    }
#pragma unroll
    for (int i = 0; i < 2; ++i) {
      int chunk = i * 256 + tid;
      int r = chunk >> 2, c = chunk & 3;
      int cs = c ^ ((r >> 1) & 3);
      long boff = (brow0 + r) * (long)D_DIM + kk + cs * 8;
      int lo = (i * 256 + (tid & ~63)) << 3;
      gload16(cPH + boff, (void*)(lBH + lo));
      gload16(cPL + boff, (void*)(lBL + lo));
    }
    __syncthreads();

    bf16x8 aH[4], aL[4], bH[4], bL[4];
#pragma unroll
    for (int m = 0; m < 4; ++m) {
      int row = wr * 64 + m * 16 + fr;
      int rm = row & 7;
      f32x4 p0 = *(const f32x4*)(lA + row * 32 + (((fg * 2 + 0) ^ rm) * 4));
      f32x4 p1 = *(const f32x4*)(lA + row * 32 + (((fg * 2 + 1) ^ rm) * 4));
#pragma unroll
      for (int e = 0; e < 8; ++e) {
        float f = (e < 4) ? p0[e] : p1[e - 4];
        unsigned short h = f2bf(f);
        aH[m][e] = (short)h;
        aL[m][e] = (short)f2bf(f - bf2f(h));
      }
    }
#pragma unroll
    for (int n = 0; n < 4; ++n) {
      int row = wc * 64 + n * 16 + fr;
      int sc = fg ^ ((row >> 1) & 3);
      bH[n] = *(const bf16x8*)(lBH + row * 32 + sc * 8);
      bL[n] = *(const bf16x8*)(lBL + row * 32 + sc * 8);
    }
#pragma unroll
    for (int m = 0; m < 4; ++m)
#pragma unroll
      for (int n = 0; n < 4; ++n) {
        acc[m][n] = __builtin_amdgcn_mfma_f32_16x16x32_bf16(aH[m], bH[n], acc[m][n], 0, 0, 0);
        acc[m][n] = __builtin_amdgcn_mfma_f32_16x16x32_bf16(aH[m], bL[n], acc[m][n], 0, 0, 0);
        acc[m][n] = __builtin_amdgcn_mfma_f32_16x16x32_bf16(aL[m], bH[n], acc[m][n], 0, 0, 0);
      }
    __syncthreads();
  }

#pragma unroll
  for (int n = 0; n < 4; ++n) {
    float v = -3.0e38f;
#pragma unroll
    for (int m = 0; m < 4; ++m)
#pragma unroll
      for (int j = 0; j < 4; ++j) {
        float rv = ldsR[wr * 64 + m * 16 + fg * 4 + j];
        v = fmaxf(v, acc[m][n][j] * rv);
      }
    v = fmaxf(v, __shfl_xor(v, 16));
    v = fmaxf(v, __shfl_xor(v, 32));
    if (fg == 0) {
      int col = wc * 64 + n * 16 + fr;
      atomicMax(&gmax2[z * CAND + col], encf(v * 0.03125f));
    }
  }
}

// ---------------- K3e: scatter exact candidate values over approx gmax ----------------
__global__ void scatter_k(const unsigned* __restrict__ gmax2,
                          const int* __restrict__ candIdx,
                          unsigned* __restrict__ gmax) {
  int z = blockIdx.x, j = threadIdx.x;
  int n = candIdx[z * CAND + j];
  gmax[(size_t)z * NE + n] = gmax2[z * CAND + j];
}

// ---------------- K4: per-batch exact top-64 cutoff + softmax weights ----------------
__global__ void topk_weights_k(const unsigned* __restrict__ gmax,
                               const float* __restrict__ alpha_p,
                               float* __restrict__ wout, int* __restrict__ idx,
                               int* __restrict__ cnt) {
  __shared__ unsigned enc[NE];
  __shared__ unsigned ubc[4];
  __shared__ float l4[4];
  __shared__ int ic[257];
  int tid = threadIdx.x;
  int lane = tid & 63, w = tid >> 6;
  const unsigned* g = gmax + (size_t)blockIdx.x * NE;
  for (int i = tid; i < NE; i += 256) enc[i] = g[i];
  __syncthreads();

  unsigned mx = 0;
  for (int i = tid; i < NE; i += 256) mx = enc[i] > mx ? enc[i] : mx;
  for (int o = 32; o > 0; o >>= 1) {
    unsigned other = (unsigned)__shfl_xor((int)mx, o);
    if (other > mx) mx = other;
  }
  if (lane == 0) ubc[w] = mx;
  __syncthreads();
  unsigned m1e = ubc[0];
  for (int t = 1; t < 4; ++t) m1e = ubc[t] > m1e ? ubc[t] : m1e;
  float m1 = decf(m1e);

  unsigned cur = 0;
  for (int bit = 31; bit >= 0; --bit) {
    unsigned cand = cur | (1u << bit);
    int c = 0;
    for (int i = tid; i < NE; i += 256) c += (enc[i] >= cand) ? 1 : 0;
    for (int o = 32; o > 0; o >>= 1) c += __shfl_xor(c, o);
    __syncthreads();
    if (lane == 0) ic[w] = c;
    __syncthreads();
    int tot = ic[0] + ic[1] + ic[2] + ic[3];
    if (tot >= KTOP) cur = cand;
  }

  float sd = 0.f, ssum = 0.f;
  for (int i = tid; i < NE; i += 256) {
    float e = expf(decf(enc[i]) - m1);
    sd += e;
    if (enc[i] >= cur) ssum += e;
  }
  for (int o = 32; o > 0; o >>= 1) { sd += __shfl_xor(sd, o); ssum += __shfl_xor(ssum, o); }
  __syncthreads();
  if (lane == 0) { l4[w] = sd; }
  __syncthreads();
  float SD = l4[0] + l4[1] + l4[2] + l4[3];
  __syncthreads();
  if (lane == 0) { l4[w] = ssum; }
  __syncthreads();
  float SS = l4[0] + l4[1] + l4[2] + l4[3];

  float alpha = alpha_p[0];
  float wd = alpha / SD;
  float ws_ = (1.0f - alpha) / SS;
  for (int i = tid; i < NE; i += 256) {
    float e = expf(decf(enc[i]) - m1);
    float wv = wd * e + ((enc[i] >= cur) ? ws_ * e : 0.0f);
    wout[(size_t)blockIdx.x * NE + i] = wv;
  }

  int myc = 0;
  for (int i = tid; i < NE; i += 256) myc += (enc[i] >= cur) ? 1 : 0;
  __syncthreads();
  ic[tid] = myc;
  __syncthreads();
  if (tid == 0) {
    int s = 0;
    for (int t = 0; t < 256; ++t) { int v = ic[t]; ic[t] = s; s += v; }
    ic[256] = s;
    cnt[blockIdx.x] = s;
  }
  __syncthreads();
  int off = ic[tid];
  for (int i = tid; i < NE; i += 256)
    if (enc[i] >= cur) idx[(size_t)blockIdx.x * NE + (off++)] = i;
}

// ---------------- K5: O = rmsnorm(weights @ En, on_w) ----------------
__global__ void out_o_k(const float* __restrict__ wts, const float* __restrict__ E,
                        const float* __restrict__ rinvE, const float* __restrict__ sn_w,
                        const float* __restrict__ on_w, const float* __restrict__ alpha_p,
                        const int* __restrict__ idx, const int* __restrict__ cnt,
                        float* __restrict__ O) {
  __shared__ float l4[4];
  int b = blockIdx.x, tid = threadIdx.x;
  float acc[4] = {0.f, 0.f, 0.f, 0.f};
  float alpha = alpha_p[0];
  if (alpha == 0.0f) {
    int nsel = cnt[b];
    for (int j = 0; j < nsel; ++j) {
      int n = idx[(size_t)b * NE + j];
      float wv = wts[(size_t)b * NE + n] * rinvE[n];
      const float* er = E + (size_t)n * D_DIM;
#pragma unroll
      for (int i = 0; i < 4; ++i) acc[i] += wv * er[tid + 256 * i];
    }
  } else {
    for (int n = 0; n < NE; ++n) {
      float wv = wts[(size_t)b * NE + n] * rinvE[n];
      const float* er = E + (size_t)n * D_DIM;
#pragma unroll
      for (int i = 0; i < 4; ++i) acc[i] += wv * er[tid + 256 * i];
    }
  }
  float ssq = 0.f;
#pragma unroll
  for (int i = 0; i < 4; ++i) {
    acc[i] *= sn_w[tid + 256 * i];
    ssq += acc[i] * acc[i];
  }
  for (int o = 32; o > 0; o >>= 1) ssq += __shfl_xor(ssq, o);
  int lane = tid & 63, w = tid >> 6;
  if (lane == 0) l4[w] = ssq;
  __syncthreads();
  float tot = l4[0] + l4[1] + l4[2] + l4[3];
  float r = rsqrtf(tot * (1.0f / D_DIM) + 1e-6f);
#pragma unroll
  for (int i = 0; i < 4; ++i)
    O[(size_t)b * D_DIM + tid + 256 * i] = acc[i] * r * on_w[tid + 256 * i];
}

}  // namespace

extern "C" void kernel_launch(void* const* d_in, const int* in_sizes, int n_in,
                              void* d_out, int out_size, void* d_ws, size_t ws_size,
                              hipStream_t stream) {
  const float* X     = (const float*)d_in[0];
  const float* alpha = (const float*)d_in[1];
  const float* E     = (const float*)d_in[2];
  const float* Wq    = (const float*)d_in[3];
  const float* Wk    = (const float*)d_in[4];
  const float* xn_w  = (const float*)d_in[5];
  const float* sn_w  = (const float*)d_in[6];
  const float* on_w  = (const float*)d_in[7];
  float* O    = (float*)d_out;                          // [16][1024]
  float* Wout = (float*)d_out + (size_t)BATCH * D_DIM;  // [16][4096]

  char* ws = (char*)d_ws;
  size_t off = 0;
  auto alloc = [&](size_t bytes) {
    char* p = ws + off;
    off += (bytes + 255) & ~(size_t)255;
    return p;
  };
  signed char*    XQ    = (signed char*)alloc((size_t)MX * D_DIM);          // 32 MB
  signed char*    PQ    = (signed char*)alloc((size_t)NE * D_DIM);          // 4 MB
  float*          WqTf  = (float*)alloc((size_t)D_DIM * D_DIM * 4);
  unsigned short* WkTH  = (unsigned short*)alloc((size_t)D_DIM * D_DIM * 2);
  unsigned short* WkTL  = (unsigned short*)alloc((size_t)D_DIM * D_DIM * 2);
  unsigned short* W2TH  = (unsigned short*)alloc((size_t)D_DIM * D_DIM * 2);
  unsigned short* W2TL  = (unsigned short*)alloc((size_t)D_DIM * D_DIM * 2);
  unsigned short* PH    = (unsigned short*)alloc((size_t)NE * D_DIM * 2);
  unsigned short* PL    = (unsigned short*)alloc((size_t)NE * D_DIM * 2);
  unsigned short* cPH   = (unsigned short*)alloc((size_t)BATCH * CAND * D_DIM * 2);
  unsigned short* cPL   = (unsigned short*)alloc((size_t)BATCH * CAND * D_DIM * 2);
  float* rinvX = (float*)alloc((size_t)MX * 4);
  float* sxr   = (float*)alloc((size_t)MX * 4);
  float* rinvE = (float*)alloc((size_t)NE * 4);
  float* sp    = (float*)alloc((size_t)NE * 4);
  unsigned* gmax  = (unsigned*)alloc((size_t)BATCH * NE * 4);
  unsigned* gmax2 = (unsigned*)alloc((size_t)BATCH * CAND * 4);
  int* candIdx = (int*)alloc((size_t)BATCH * CAND * 4);
  int* idx = (int*)alloc((size_t)BATCH * NE * 4);
  int* cnt = (int*)alloc((size_t)BATCH * 4);
  if (off > ws_size) return;  // needs ~75 MB scratch

  hipMemsetAsync(gmax, 0, (size_t)BATCH * NE * 4, stream);

  row_rinv_k<<<NE, 256, 0, stream>>>(E, rinvE);
  transpose_k<<<dim3(D_DIM / 32, D_DIM / 32), 256, 0, stream>>>(Wq, WqTf);
  split_wt_k<<<dim3(D_DIM / 32, D_DIM / 32), 256, 0, stream>>>(Wk, sn_w, WkTH, WkTL);
  // W2T[j][d] = xn_w[j] * sum_k WqT[j,k] * WkT'[d,k]   (1024^2, 3-product)
  gemm_a32_k<0><<<dim3(8, 8), 256, 0, stream>>>(
      WqTf, xn_w, WkTH, WkTL, W2TH, W2TL, nullptr);
  // P'[n][j] = sum_d (E[n,d]*rinvE[n]) * W2T[j,d]      (4096x1024, 3-product)
  gemm_a32_k<0><<<dim3(NE / 128, D_DIM / 128), 256, 0, stream>>>(
      E, rinvE, W2TH, W2TL, PH, PL, nullptr);
  quant_p_k<<<NE, 256, 0, stream>>>(PH, PL, sp, (int*)PQ);

  // all-M: rinv + int8 quant of X
  rinv_quantx_k<<<MX, 256, 0, stream>>>(X, rinvX, sxr, (int*)XQ);
  // approx scores (int8), single dispatch, m-strip-per-XCD swizzle
  gemm_scores1_k<<<(MX / 256) * (NE / 256), 512, 0, stream>>>(XQ, PQ, sxr, sp, gmax);

  cand_select_k<<<BATCH, 256, 0, stream>>>(gmax, candIdx, gmax2);
  gather_k<<<dim3(CAND, BATCH), 256, 0, stream>>>(PH, PL, candIdx, cPH, cPL);
  gemm_rescore_k<<<dim3(SEQ / 128, 1, BATCH), 256, 0, stream>>>(
      X, rinvX, cPH, cPL, gmax2);
  scatter_k<<<BATCH, CAND, 0, stream>>>(gmax2, candIdx, gmax);

  topk_weights_k<<<BATCH, 256, 0, stream>>>(gmax, alpha, Wout, idx, cnt);
  out_o_k<<<BATCH, 256, 0, stream>>>(Wout, E, rinvE, sn_w, on_w, alpha, idx, cnt, O);
}

// Round 11
// 415.860 us; speedup vs baseline: 2.9562x; 1.0541x over previous
//
#include <hip/hip_runtime.h>

// BasisAttention: B=16,S=2048,D=1024,N=4096,K_TOP=64. fp32 in/out.
// R4: approx-then-rescore. R5: scores = Xn@(Km Wq)^T. R7: 256^2 8-wave
// phase-split pipeline. R8: weight-chain fusion + single dispatch.
// R9: m-strip-per-XCD swizzle. R10: int8 approx pass (mfma_i32_16x16x64_i8).
// R11: (a) within-XCD 8m x 8n co-resident order (4MB working set = L2-fit;
//      was 1+4MB -> PQ thrash, FETCH 145MB@900GB/s). (b) rescore stages
//      candidate P rows INDIRECTLY via candIdx (gather_k gone). (c)
//      scatter+topk+out_o merged into final_k; transpose+split merged.

namespace {

constexpr int D_DIM = 1024;
constexpr int NE    = 4096;
constexpr int BATCH = 16;
constexpr int SEQ   = 2048;
constexpr int MX    = BATCH * SEQ;   // 32768
constexpr int KTOP  = 64;
constexpr int CAND  = 128;           // candidates per batch
constexpr int BK    = 32;

using f32x4  = __attribute__((ext_vector_type(4))) float;
using bf16x8 = __attribute__((ext_vector_type(8))) short;
using i32x4  = __attribute__((ext_vector_type(4))) int;

__device__ inline unsigned encf(float f) {
  unsigned u = __float_as_uint(f);
  return (u & 0x80000000u) ? ~u : (u | 0x80000000u);
}
__device__ inline float decf(unsigned e) {
  unsigned u = (e & 0x80000000u) ? (e ^ 0x80000000u) : ~e;
  return __uint_as_float(u);
}

__device__ inline unsigned short f2bf(float f) {  // RNE float->bf16 bits
  unsigned u = __float_as_uint(f);
  unsigned lsb = (u >> 16) & 1u;
  u += 0x7fffu + lsb;
  return (unsigned short)(u >> 16);
}
__device__ inline float bf2f(unsigned short h) {
  return __uint_as_float(((unsigned)h) << 16);
}

__device__ inline void gload16(const void* gsrc, void* ldst) {
  __builtin_amdgcn_global_load_lds(
      (const __attribute__((address_space(1))) unsigned int*)gsrc,
      (__attribute__((address_space(3))) unsigned int*)ldst, 16, 0, 0);
}

#define LGK0_SB() do { asm volatile("s_waitcnt lgkmcnt(0)" ::: "memory"); \
                       __builtin_amdgcn_sched_barrier(0); } while (0)

// ---------------- K1: per-row rsqrt(mean(x^2)+eps) ----------------
__global__ void row_rinv_k(const float* __restrict__ X, float* __restrict__ rinv) {
  __shared__ float l4[4];
  int row = blockIdx.x;
  float4 v = ((const float4*)(X + (size_t)row * D_DIM))[threadIdx.x];
  float ss = v.x * v.x + v.y * v.y + v.z * v.z + v.w * v.w;
  for (int o = 32; o > 0; o >>= 1) ss += __shfl_xor(ss, o);
  int lane = threadIdx.x & 63, w = threadIdx.x >> 6;
  if (lane == 0) l4[w] = ss;
  __syncthreads();
  if (threadIdx.x == 0) {
    float t = l4[0] + l4[1] + l4[2] + l4[3];
    rinv[row] = rsqrtf(t * (1.0f / D_DIM) + 1e-6f);
  }
}

// ---------------- K1a: fused per-row rinv + int8 quant of X ----------------
__global__ void rinv_quantx_k(const float* __restrict__ X, float* __restrict__ rinv,
                              float* __restrict__ sxr, int* __restrict__ XQ) {
  __shared__ float l4[4], m4[4];
  int row = blockIdx.x;
  float4 v = ((const float4*)(X + (size_t)row * D_DIM))[threadIdx.x];
  float ss = v.x * v.x + v.y * v.y + v.z * v.z + v.w * v.w;
  float am = fmaxf(fmaxf(fabsf(v.x), fabsf(v.y)), fmaxf(fabsf(v.z), fabsf(v.w)));
  for (int o = 32; o > 0; o >>= 1) {
    ss += __shfl_xor(ss, o);
    am = fmaxf(am, __shfl_xor(am, o));
  }
  int lane = threadIdx.x & 63, w = threadIdx.x >> 6;
  if (lane == 0) { l4[w] = ss; m4[w] = am; }
  __syncthreads();
  float t  = l4[0] + l4[1] + l4[2] + l4[3];
  float amax = fmaxf(fmaxf(m4[0], m4[1]), fmaxf(m4[2], m4[3]));
  amax = fmaxf(amax, 1e-30f);
  float ri = rsqrtf(t * (1.0f / D_DIM) + 1e-6f);
  if (threadIdx.x == 0) {
    rinv[row] = ri;
    sxr[row]  = ri * amax * (1.0f / 127.0f);
  }
  float qs = 127.0f / amax;
  int q0 = (int)rintf(v.x * qs) & 0xff;
  int q1 = (int)rintf(v.y * qs) & 0xff;
  int q2 = (int)rintf(v.z * qs) & 0xff;
  int q3 = (int)rintf(v.w * qs) & 0xff;
  XQ[(size_t)row * 256 + threadIdx.x] = q0 | (q1 << 8) | (q2 << 16) | (q3 << 24);
}

// ---------------- K1e: int8 quant of P rows (from bf16 hi/lo) ----------------
__global__ void quant_p_k(const unsigned short* __restrict__ PH,
                          const unsigned short* __restrict__ PL,
                          float* __restrict__ sp, int* __restrict__ PQ) {
  __shared__ float m4[4];
  int row = blockIdx.x;
  ushort4 h = *(const ushort4*)(PH + (size_t)row * D_DIM + threadIdx.x * 4);
  ushort4 l = *(const ushort4*)(PL + (size_t)row * D_DIM + threadIdx.x * 4);
  float p0 = bf2f(h.x) + bf2f(l.x);
  float p1 = bf2f(h.y) + bf2f(l.y);
  float p2 = bf2f(h.z) + bf2f(l.z);
  float p3 = bf2f(h.w) + bf2f(l.w);
  float am = fmaxf(fmaxf(fabsf(p0), fabsf(p1)), fmaxf(fabsf(p2), fabsf(p3)));
  for (int o = 32; o > 0; o >>= 1) am = fmaxf(am, __shfl_xor(am, o));
  int lane = threadIdx.x & 63, w = threadIdx.x >> 6;
  if (lane == 0) m4[w] = am;
  __syncthreads();
  float amax = fmaxf(fmaxf(m4[0], m4[1]), fmaxf(m4[2], m4[3]));
  amax = fmaxf(amax, 1e-30f);
  if (threadIdx.x == 0) sp[row] = amax * (1.0f / 127.0f);
  float qs = 127.0f / amax;
  int q0 = (int)rintf(p0 * qs) & 0xff;
  int q1 = (int)rintf(p1 * qs) & 0xff;
  int q2 = (int)rintf(p2 * qs) & 0xff;
  int q3 = (int)rintf(p3 * qs) & 0xff;
  PQ[(size_t)row * 256 + threadIdx.x] = q0 | (q1 << 8) | (q2 << 16) | (q3 << 24);
}

// ---------------- K1b: fused Wq fp32-transpose + Wk scaled bf16-split-transpose ----------------
// T[r][c] = Wq[c][r];  H/L[r][c] = split(Wk[c][r] * cw[r])
__global__ void prep_w_k(const float* __restrict__ Wq, const float* __restrict__ Wk,
                         const float* __restrict__ cw, float* __restrict__ T,
                         unsigned short* __restrict__ H, unsigned short* __restrict__ L) {
  __shared__ float t[32][33], u[32][33];
  int k0 = blockIdx.x * 32, d0 = blockIdx.y * 32;
  int tx = threadIdx.x & 31, ty4 = (threadIdx.x >> 5) * 4;
#pragma unroll
  for (int i = 0; i < 4; ++i) {
    t[ty4 + i][tx] = Wq[(size_t)(d0 + ty4 + i) * D_DIM + k0 + tx];
    u[ty4 + i][tx] = Wk[(size_t)(d0 + ty4 + i) * D_DIM + k0 + tx];
  }
  __syncthreads();
#pragma unroll
  for (int i = 0; i < 4; ++i) {
    int a = ty4 + i;
    T[(size_t)(k0 + a) * D_DIM + d0 + tx] = t[tx][a];
    float v = u[tx][a] * cw[k0 + a];
    unsigned short h = f2bf(v);
    H[(size_t)(k0 + a) * D_DIM + d0 + tx] = h;
    L[(size_t)(k0 + a) * D_DIM + d0 + tx] = f2bf(v - bf2f(h));
  }
}

// ---------------- K2: O = rowscale(A_f32) @ B(hi,lo)^T (3-product) ----------------
template <int FPOUT>
__global__ __launch_bounds__(256, 2) void gemm_a32_k(
    const float* __restrict__ A, const float* __restrict__ rinv,
    const unsigned short* __restrict__ BH, const unsigned short* __restrict__ BL,
    unsigned short* __restrict__ OH, unsigned short* __restrict__ OL,
    float* __restrict__ Of) {
  __shared__ __align__(16) float lA[128 * 32];
  __shared__ __align__(16) unsigned short lBH[128 * 32];
  __shared__ __align__(16) unsigned short lBL[128 * 32];
  __shared__ float ldsR[128];

  int tid = threadIdx.x;
  int lane = tid & 63, wid = tid >> 6;
  int wr = wid >> 1, wc = wid & 1;
  int fr = lane & 15, fg = lane >> 4;
  long m0 = (long)blockIdx.x * 128;
  long n0 = (long)blockIdx.y * 128;

  if (tid < 128) ldsR[tid] = rinv ? rinv[m0 + tid] : 1.0f;

  f32x4 acc[4][4] = {};

  for (int kk = 0; kk < D_DIM; kk += BK) {
#pragma unroll
    for (int i = 0; i < 4; ++i) {
      int chunk = i * 256 + tid;
      int r = chunk >> 3, c = chunk & 7;
      int cs = c ^ (r & 7);
      const float* src = A + (m0 + r) * (long)D_DIM + kk + cs * 4;
      gload16(src, (void*)(lA + ((i * 256 + (tid & ~63)) << 2)));
    }
#pragma unroll
    for (int i = 0; i < 2; ++i) {
      int chunk = i * 256 + tid;
      int r = chunk >> 2, c = chunk & 3;
      int cs = c ^ ((r >> 1) & 3);
      long boff = (n0 + r) * (long)D_DIM + kk + cs * 8;
      int lo = (i * 256 + (tid & ~63)) << 3;
      gload16(BH + boff, (void*)(lBH + lo));
      gload16(BL + boff, (void*)(lBL + lo));
    }
    __syncthreads();

    bf16x8 aH[4], aL[4], bH[4], bL[4];
#pragma unroll
    for (int m = 0; m < 4; ++m) {
      int row = wr * 64 + m * 16 + fr;
      int rm = row & 7;
      f32x4 p0 = *(const f32x4*)(lA + row * 32 + (((fg * 2 + 0) ^ rm) * 4));
      f32x4 p1 = *(const f32x4*)(lA + row * 32 + (((fg * 2 + 1) ^ rm) * 4));
#pragma unroll
      for (int e = 0; e < 8; ++e) {
        float f = (e < 4) ? p0[e] : p1[e - 4];
        unsigned short h = f2bf(f);
        aH[m][e] = (short)h;
        aL[m][e] = (short)f2bf(f - bf2f(h));
      }
    }
#pragma unroll
    for (int n = 0; n < 4; ++n) {
      int row = wc * 64 + n * 16 + fr;
      int sc = fg ^ ((row >> 1) & 3);
      bH[n] = *(const bf16x8*)(lBH + row * 32 + sc * 8);
      bL[n] = *(const bf16x8*)(lBL + row * 32 + sc * 8);
    }
#pragma unroll
    for (int m = 0; m < 4; ++m)
#pragma unroll
      for (int n = 0; n < 4; ++n) {
        acc[m][n] = __builtin_amdgcn_mfma_f32_16x16x32_bf16(aH[m], bH[n], acc[m][n], 0, 0, 0);
        acc[m][n] = __builtin_amdgcn_mfma_f32_16x16x32_bf16(aH[m], bL[n], acc[m][n], 0, 0, 0);
        acc[m][n] = __builtin_amdgcn_mfma_f32_16x16x32_bf16(aL[m], bH[n], acc[m][n], 0, 0, 0);
      }
    __syncthreads();
  }

#pragma unroll
  for (int m = 0; m < 4; ++m) {
#pragma unroll
    for (int j = 0; j < 4; ++j) {
      int rloc = wr * 64 + m * 16 + fg * 4 + j;
      float rv = ldsR[rloc];
      long grow = m0 + rloc;
#pragma unroll
      for (int n = 0; n < 4; ++n) {
        long gcol = n0 + wc * 64 + n * 16 + fr;
        float v = acc[m][n][j] * rv;
        if (FPOUT) {
          Of[grow * D_DIM + gcol] = v;
        } else {
          unsigned short h = f2bf(v);
          OH[grow * D_DIM + gcol] = h;
          OL[grow * D_DIM + gcol] = f2bf(v - bf2f(h));
        }
      }
    }
  }
}

// ---------------- K3a: APPROX scores INT8, 256^2 / BK=64 / 8-wave phase-split ----------------
__global__ __launch_bounds__(512, 2) void gemm_scores1_k(
    const signed char* __restrict__ XQ, const signed char* __restrict__ PQ,
    const float* __restrict__ sxr, const float* __restrict__ sp,
    unsigned* __restrict__ gmax) {
  __shared__ __align__(16) signed char lA[2][256 * 64];
  __shared__ __align__(16) signed char lB[2][256 * 64];
  __shared__ float ldsR[256];

  int tid = threadIdx.x;                 // 0..511
  int lane = tid & 63, wid = tid >> 6;   // 8 waves
  int wr = wid >> 2;                     // 0..1  (M half)
  int wcn = wid & 3;                     // 0..3  (N quarter)
  int fr = lane & 15, fg = lane >> 4;

  // R11 swizzle: per XCD, co-resident ~64 blocks span 8m x 8n (4MB = L2-fit).
  int id = blockIdx.x;
  int xcd = id & 7;
  int r = id >> 3;                          // 0..255
  int tile_n = (r & 7) | ((r >> 7) << 3);   // 0..15
  int tile_m = xcd * 16 + ((r >> 3) & 15);  // 0..127
  long m0 = (long)tile_m * 256;
  long n0 = (long)tile_n * 256;

  if (tid < 256) ldsR[tid] = sxr[m0 + tid];

  auto stageTile = [&](int buf, int kt) {
    int kk = kt * 64;
#pragma unroll
    for (int i = 0; i < 2; ++i) {
      int chunk = i * 512 + tid;
      int r2 = chunk >> 2, c = chunk & 3;
      int cs = c ^ ((r2 >> 1) & 3);            // pre-swizzled source
      gload16(XQ + (m0 + r2) * (long)D_DIM + kk + cs * 16,
              (void*)(&lA[buf][0] + ((i * 512 + (tid & ~63)) << 4)));
    }
#pragma unroll
    for (int i = 0; i < 2; ++i) {
      int chunk = i * 512 + tid;
      int r2 = chunk >> 2, c = chunk & 3;
      int cs = c ^ ((r2 >> 1) & 3);
      gload16(PQ + (n0 + r2) * (long)D_DIM + kk + cs * 16,
              (void*)(&lB[buf][0] + ((i * 512 + (tid & ~63)) << 4)));
    }
  };

  i32x4 acc[8][4] = {};

  stageTile(0, 0);
  stageTile(1, 1);
  asm volatile("s_waitcnt lgkmcnt(0)" ::: "memory");  // ldsR visible at barrier

  i32x4 aF[4], bF[4];

  for (int kt = 0; kt < 16; ++kt) {
    int cur = kt & 1;
    const signed char* As = &lA[cur][0];
    const signed char* Bs = &lB[cur][0];

    if (kt < 15) {
      asm volatile("s_waitcnt vmcnt(4)" ::: "memory");
    } else {
      asm volatile("s_waitcnt vmcnt(0)" ::: "memory");
    }
    __builtin_amdgcn_s_barrier();

    // ---- P1: read A[m0..3] + B[n0..1]; MFMA (m0-3, n0-1)
#pragma unroll
    for (int mi = 0; mi < 4; ++mi) {
      int row = wr * 128 + mi * 16 + fr;
      int ck = fg ^ ((row >> 1) & 3);
      aF[mi] = *(const i32x4*)(As + row * 64 + ck * 16);
    }
#pragma unroll
    for (int ni = 0; ni < 2; ++ni) {
      int row = wcn * 64 + ni * 16 + fr;
      int ck = fg ^ ((row >> 1) & 3);
      bF[ni] = *(const i32x4*)(Bs + row * 64 + ck * 16);
    }
    LGK0_SB();
    __builtin_amdgcn_s_setprio(1);
#pragma unroll
    for (int mi = 0; mi < 4; ++mi)
#pragma unroll
      for (int ni = 0; ni < 2; ++ni)
        acc[mi][ni] = __builtin_amdgcn_mfma_i32_16x16x64_i8(
            aF[mi], bF[ni], acc[mi][ni], 0, 0, 0);
    __builtin_amdgcn_s_setprio(0);

    // ---- P2: read B[n2..3]; MFMA (m0-3, n2-3)
#pragma unroll
    for (int ni = 2; ni < 4; ++ni) {
      int row = wcn * 64 + ni * 16 + fr;
      int ck = fg ^ ((row >> 1) & 3);
      bF[ni] = *(const i32x4*)(Bs + row * 64 + ck * 16);
    }
    LGK0_SB();
    __builtin_amdgcn_s_setprio(1);
#pragma unroll
    for (int mi = 0; mi < 4; ++mi)
#pragma unroll
      for (int ni = 2; ni < 4; ++ni)
        acc[mi][ni] = __builtin_amdgcn_mfma_i32_16x16x64_i8(
            aF[mi], bF[ni], acc[mi][ni], 0, 0, 0);
    __builtin_amdgcn_s_setprio(0);

    // ---- P3: read A[m4..7]; barrier closes all reads of buf[cur];
    //          stage(kt+2 -> buf[cur]); MFMA (m4-7, n2-3)
#pragma unroll
    for (int mi = 0; mi < 4; ++mi) {
      int row = wr * 128 + (mi + 4) * 16 + fr;
      int ck = fg ^ ((row >> 1) & 3);
      aF[mi] = *(const i32x4*)(As + row * 64 + ck * 16);
    }
    LGK0_SB();
    __builtin_amdgcn_s_barrier();
    if (kt + 2 < 16) stageTile(cur, kt + 2);
    __builtin_amdgcn_s_setprio(1);
#pragma unroll
    for (int mi = 0; mi < 4; ++mi)
#pragma unroll
      for (int ni = 2; ni < 4; ++ni)
        acc[mi + 4][ni] = __builtin_amdgcn_mfma_i32_16x16x64_i8(
            aF[mi], bF[ni], acc[mi + 4][ni], 0, 0, 0);
    __builtin_amdgcn_s_setprio(0);

    // ---- P4: MFMA (m4-7, n0-1), register-only
    __builtin_amdgcn_s_setprio(1);
#pragma unroll
    for (int mi = 0; mi < 4; ++mi)
#pragma unroll
      for (int ni = 0; ni < 2; ++ni)
        acc[mi + 4][ni] = __builtin_amdgcn_mfma_i32_16x16x64_i8(
            aF[mi], bF[ni], acc[mi + 4][ni], 0, 0, 0);
    __builtin_amdgcn_s_setprio(0);
  }

  // epilogue: v = acc*sxr[row]*sp[col]; column max over 256 rows; atomicMax.
  int b = (int)(m0 >> 11);
#pragma unroll
  for (int ni = 0; ni < 4; ++ni) {
    long col = n0 + wcn * 64 + ni * 16 + fr;
    float spc = sp[col];
    float v = -3.0e38f;
#pragma unroll
    for (int mi = 0; mi < 8; ++mi)
#pragma unroll
      for (int j = 0; j < 4; ++j) {
        int row = wr * 128 + mi * 16 + fg * 4 + j;
        v = fmaxf(v, (float)acc[mi][ni][j] * ldsR[row]);
      }
    v *= spc;
    v = fmaxf(v, __shfl_xor(v, 16));
    v = fmaxf(v, __shfl_xor(v, 32));
    if (fg == 0) {
      atomicMax(&gmax[(long)b * NE + col], encf(v * 0.03125f));
    }
  }
}

// ---------------- K3b: per-batch top-CAND candidate selection (+ zero gmax2) ----------------
__global__ void cand_select_k(const unsigned* __restrict__ gmax,
                              int* __restrict__ candIdx, unsigned* __restrict__ gmax2) {
  __shared__ unsigned enc[NE];
  __shared__ int ic[257];
  int tid = threadIdx.x;
  int lane = tid & 63, w = tid >> 6;
  int zb = blockIdx.x;
  if (tid < CAND) gmax2[zb * CAND + tid] = 0u;
  const unsigned* g = gmax + (size_t)zb * NE;
  for (int i = tid; i < NE; i += 256) enc[i] = g[i];
  __syncthreads();

  unsigned cur = 0;
  for (int bit = 31; bit >= 0; --bit) {
    unsigned cand = cur | (1u << bit);
    int c = 0;
    for (int i = tid; i < NE; i += 256) c += (enc[i] >= cand) ? 1 : 0;
    for (int o = 32; o > 0; o >>= 1) c += __shfl_xor(c, o);
    __syncthreads();
    if (lane == 0) ic[w] = c;
    __syncthreads();
    int tot = ic[0] + ic[1] + ic[2] + ic[3];
    if (tot >= CAND) cur = cand;
  }

  int myc = 0;
  for (int i = tid; i < NE; i += 256) myc += (enc[i] >= cur) ? 1 : 0;
  __syncthreads();
  ic[tid] = myc;
  __syncthreads();
  if (tid == 0) {
    int s = 0;
    for (int t = 0; t < 256; ++t) { int v = ic[t]; ic[t] = s; s += v; }
  }
  __syncthreads();
  int off = ic[tid];
  for (int i = tid; i < NE; i += 256)
    if (enc[i] >= cur) {
      if (off < CAND) candIdx[zb * CAND + off] = i;
      ++off;
    }
}

// ---------------- K3d: EXACT rescore (indirect candidate staging) ----------------
__global__ __launch_bounds__(256, 2) void gemm_rescore_k(
    const float* __restrict__ X, const float* __restrict__ rinvA,
    const unsigned short* __restrict__ PH, const unsigned short* __restrict__ PL,
    const int* __restrict__ candIdx, unsigned* __restrict__ gmax2) {
  __shared__ __align__(16) float lA[128 * 32];
  __shared__ __align__(16) unsigned short lBH[128 * 32], lBL[128 * 32];
  __shared__ float ldsR[128];

  int tid = threadIdx.x;
  int lane = tid & 63, wid = tid >> 6;
  int wr = wid >> 1, wc = wid & 1;
  int fr = lane & 15, fg = lane >> 4;
  int z = blockIdx.z;
  long m0 = (long)blockIdx.x * 128;
  long arow0 = (long)z * SEQ + m0;

  if (tid < 128) ldsR[tid] = rinvA[arow0 + tid];

  // indirect row bases for the B tile (candidate rows of P)
  long bbase[2];
#pragma unroll
  for (int i = 0; i < 2; ++i) {
    int r = (i * 256 + tid) >> 2;          // 0..127
    bbase[i] = (long)candIdx[z * CAND + r] * D_DIM;
  }

  f32x4 acc[4][4] = {};

  for (int kk = 0; kk < D_DIM; kk += BK) {
#pragma unroll
    for (int i = 0; i < 4; ++i) {
      int chunk = i * 256 + tid;
      int r = chunk >> 3, c = chunk & 7;
      int cs = c ^ (r & 7);
      const float* src = X + (arow0 + r) * (long)D_DIM + kk + cs * 4;
      gload16(src, (void*)(lA + ((i * 256 + (tid & ~63)) << 2)));
    }
#pragma unroll
    for (int i = 0; i < 2; ++i) {
      int chunk = i * 256 + tid;
      int r = chunk >> 2, c = chunk & 3;
      int cs = c ^ ((r >> 1) & 3);
      long boff = bbase[i] + kk + cs * 8;
      int lo = (i * 256 + (tid & ~63)) << 3;
      gload16(PH + boff, (void*)(lBH + lo));
      gload16(PL + boff, (void*)(lBL + lo));
    }
    __syncthreads();

    bf16x8 aH[4], aL[4], bH[4], bL[4];
#pragma unroll
    for (int m = 0; m < 4; ++m) {
      int row = wr * 64 + m * 16 + fr;
      int rm = row & 7;
      f32x4 p0 = *(const f32x4*)(lA + row * 32 + (((fg * 2 + 0) ^ rm) * 4));
      f32x4 p1 = *(const f32x4*)(lA + row * 32 + (((fg * 2 + 1) ^ rm) * 4));
#pragma unroll
      for (int e = 0; e < 8; ++e) {
        float f = (e < 4) ? p0[e] : p1[e - 4];
        unsigned short h = f2bf(f);
        aH[m][e] = (short)h;
        aL[m][e] = (short)f2bf(f - bf2f(h));
      }
    }
#pragma unroll
    for (int n = 0; n < 4; ++n) {
      int row = wc * 64 + n * 16 + fr;
      int sc = fg ^ ((row >> 1) & 3);
      bH[n] = *(const bf16x8*)(lBH + row * 32 + sc * 8);
      bL[n] = *(const bf16x8*)(lBL + row * 32 + sc * 8);
    }
#pragma unroll
    for (int m = 0; m < 4; ++m)
#pragma unroll
      for (int n = 0; n < 4; ++n) {
        acc[m][n] = __builtin_amdgcn_mfma_f32_16x16x32_bf16(aH[m], bH[n], acc[m][n], 0, 0, 0);
        acc[m][n] = __builtin_amdgcn_mfma_f32_16x16x32_bf16(aH[m], bL[n], acc[m][n], 0, 0, 0);
        acc[m][n] = __builtin_amdgcn_mfma_f32_16x16x32_bf16(aL[m], bH[n], acc[m][n], 0, 0, 0);
      }
    __syncthreads();
  }

#pragma unroll
  for (int n = 0; n < 4; ++n) {
    float v = -3.0e38f;
#pragma unroll
    for (int m = 0; m < 4; ++m)
#pragma unroll
      for (int j = 0; j < 4; ++j) {
        float rv = ldsR[wr * 64 + m * 16 + fg * 4 + j];
        v = fmaxf(v, acc[m][n][j] * rv);
      }
    v = fmaxf(v, __shfl_xor(v, 16));
    v = fmaxf(v, __shfl_xor(v, 32));
    if (fg == 0) {
      int col = wc * 64 + n * 16 + fr;
      atomicMax(&gmax2[z * CAND + col], encf(v * 0.03125f));
    }
  }
}

// ---------------- K4: final — patch exact vals, top-64, weights, O ----------------
__global__ void final_k(const unsigned* __restrict__ gmax,
                        const unsigned* __restrict__ gmax2,
                        const int* __restrict__ candIdx,
                        const float* __restrict__ alpha_p,
                        const float* __restrict__ E, const float* __restrict__ rinvE,
                        const float* __restrict__ sn_w, const float* __restrict__ on_w,
                        float* __restrict__ wout, float* __restrict__ O) {
  __shared__ unsigned enc[NE];
  __shared__ int sel[NE];
  __shared__ unsigned ubc[4];
  __shared__ float l4[4];
  __shared__ int ic[257];
  int tid = threadIdx.x;
  int lane = tid & 63, w = tid >> 6;
  int b = blockIdx.x;
  const unsigned* g = gmax + (size_t)b * NE;
  for (int i = tid; i < NE; i += 256) enc[i] = g[i];
  __syncthreads();
  if (tid < CAND) enc[candIdx[b * CAND + tid]] = gmax2[b * CAND + tid];  // exact patch
  __syncthreads();

  unsigned mx = 0;
  for (int i = tid; i < NE; i += 256) mx = enc[i] > mx ? enc[i] : mx;
  for (int o = 32; o > 0; o >>= 1) {
    unsigned other = (unsigned)__shfl_xor((int)mx, o);
    if (other > mx) mx = other;
  }
  if (lane == 0) ubc[w] = mx;
  __syncthreads();
  unsigned m1e = ubc[0];
  for (int t = 1; t < 4; ++t) m1e = ubc[t] > m1e ? ubc[t] : m1e;
  float m1 = decf(m1e);

  unsigned cur = 0;
  for (int bit = 31; bit >= 0; --bit) {
    unsigned cand = cur | (1u << bit);
    int c = 0;
    for (int i = tid; i < NE; i += 256) c += (enc[i] >= cand) ? 1 : 0;
    for (int o = 32; o > 0; o >>= 1) c += __shfl_xor(c, o);
    __syncthreads();
    if (lane == 0) ic[w] = c;
    __syncthreads();
    int tot = ic[0] + ic[1] + ic[2] + ic[3];
    if (tot >= KTOP) cur = cand;
  }

  float sd = 0.f, ssum = 0.f;
  for (int i = tid; i < NE; i += 256) {
    float e = expf(decf(enc[i]) - m1);
    sd += e;
    if (enc[i] >= cur) ssum += e;
  }
  for (int o = 32; o > 0; o >>= 1) { sd += __shfl_xor(sd, o); ssum += __shfl_xor(ssum, o); }
  __syncthreads();
  if (lane == 0) { l4[w] = sd; }
  __syncthreads();
  float SD = l4[0] + l4[1] + l4[2] + l4[3];
  __syncthreads();
  if (lane == 0) { l4[w] = ssum; }
  __syncthreads();
  float SS = l4[0] + l4[1] + l4[2] + l4[3];

  float alpha = alpha_p[0];
  float wd = alpha / SD;
  float ws_ = (1.0f - alpha) / SS;
  for (int i = tid; i < NE; i += 256) {
    float e = expf(decf(enc[i]) - m1);
    float wv = wd * e + ((enc[i] >= cur) ? ws_ * e : 0.0f);
    wout[(size_t)b * NE + i] = wv;
  }

  // compact selected indices into LDS
  int myc = 0;
  for (int i = tid; i < NE; i += 256) myc += (enc[i] >= cur) ? 1 : 0;
  __syncthreads();
  ic[tid] = myc;
  __syncthreads();
  if (tid == 0) {
    int s = 0;
    for (int t = 0; t < 256; ++t) { int v = ic[t]; ic[t] = s; s += v; }
    ic[256] = s;
  }
  __syncthreads();
  int off = ic[tid];
  for (int i = tid; i < NE; i += 256)
    if (enc[i] >= cur) sel[off++] = i;
  __syncthreads();
  int nsel = ic[256];

  // O = rmsnorm(weights @ En, on_w)
  float acc[4] = {0.f, 0.f, 0.f, 0.f};
  if (alpha == 0.0f) {
    float coef = wd + ws_;
    for (int j = 0; j < nsel; ++j) {
      int n = sel[j];
      float e = expf(decf(enc[n]) - m1);
      float wv = coef * e * rinvE[n];
      const float* er = E + (size_t)n * D_DIM;
#pragma unroll
      for (int i = 0; i < 4; ++i) acc[i] += wv * er[tid + 256 * i];
    }
  } else {
    for (int n = 0; n < NE; ++n) {
      float e = expf(decf(enc[n]) - m1);
      float wv = (wd * e + ((enc[n] >= cur) ? ws_ * e : 0.0f)) * rinvE[n];
      const float* er = E + (size_t)n * D_DIM;
#pragma unroll
      for (int i = 0; i < 4; ++i) acc[i] += wv * er[tid + 256 * i];
    }
  }
  float ssq = 0.f;
#pragma unroll
  for (int i = 0; i < 4; ++i) {
    acc[i] *= sn_w[tid + 256 * i];
    ssq += acc[i] * acc[i];
  }
  for (int o = 32; o > 0; o >>= 1) ssq += __shfl_xor(ssq, o);
  if (lane == 0) l4[w] = ssq;
  __syncthreads();
  float tot = l4[0] + l4[1] + l4[2] + l4[3];
  float rn = rsqrtf(tot * (1.0f / D_DIM) + 1e-6f);
#pragma unroll
  for (int i = 0; i < 4; ++i)
    O[(size_t)b * D_DIM + tid + 256 * i] = acc[i] * rn * on_w[tid + 256 * i];
}

}  // namespace

extern "C" void kernel_launch(void* const* d_in, const int* in_sizes, int n_in,
                              void* d_out, int out_size, void* d_ws, size_t ws_size,
                              hipStream_t stream) {
  const float* X     = (const float*)d_in[0];
  const float* alpha = (const float*)d_in[1];
  const float* E     = (const float*)d_in[2];
  const float* Wq    = (const float*)d_in[3];
  const float* Wk    = (const float*)d_in[4];
  const float* xn_w  = (const float*)d_in[5];
  const float* sn_w  = (const float*)d_in[6];
  const float* on_w  = (const float*)d_in[7];
  float* O    = (float*)d_out;                          // [16][1024]
  float* Wout = (float*)d_out + (size_t)BATCH * D_DIM;  // [16][4096]

  char* ws = (char*)d_ws;
  size_t off = 0;
  auto alloc = [&](size_t bytes) {
    char* p = ws + off;
    off += (bytes + 255) & ~(size_t)255;
    return p;
  };
  signed char*    XQ    = (signed char*)alloc((size_t)MX * D_DIM);          // 32 MB
  signed char*    PQ    = (signed char*)alloc((size_t)NE * D_DIM);          // 4 MB
  float*          WqTf  = (float*)alloc((size_t)D_DIM * D_DIM * 4);
  unsigned short* WkTH  = (unsigned short*)alloc((size_t)D_DIM * D_DIM * 2);
  unsigned short* WkTL  = (unsigned short*)alloc((size_t)D_DIM * D_DIM * 2);
  unsigned short* W2TH  = (unsigned short*)alloc((size_t)D_DIM * D_DIM * 2);
  unsigned short* W2TL  = (unsigned short*)alloc((size_t)D_DIM * D_DIM * 2);
  unsigned short* PH    = (unsigned short*)alloc((size_t)NE * D_DIM * 2);
  unsigned short* PL    = (unsigned short*)alloc((size_t)NE * D_DIM * 2);
  float* rinvX = (float*)alloc((size_t)MX * 4);
  float* sxr   = (float*)alloc((size_t)MX * 4);
  float* rinvE = (float*)alloc((size_t)NE * 4);
  float* sp    = (float*)alloc((size_t)NE * 4);
  unsigned* gmax  = (unsigned*)alloc((size_t)BATCH * NE * 4);
  unsigned* gmax2 = (unsigned*)alloc((size_t)BATCH * CAND * 4);
  int* candIdx = (int*)alloc((size_t)BATCH * CAND * 4);
  if (off > ws_size) return;  // needs ~67 MB scratch

  hipMemsetAsync(gmax, 0, (size_t)BATCH * NE * 4, stream);

  row_rinv_k<<<NE, 256, 0, stream>>>(E, rinvE);
  prep_w_k<<<dim3(D_DIM / 32, D_DIM / 32), 256, 0, stream>>>(
      Wq, Wk, sn_w, WqTf, WkTH, WkTL);
  // W2T[j][d] = xn_w[j] * sum_k WqT[j,k] * WkT'[d,k]   (1024^2, 3-product)
  gemm_a32_k<0><<<dim3(8, 8), 256, 0, stream>>>(
      WqTf, xn_w, WkTH, WkTL, W2TH, W2TL, nullptr);
  // P'[n][j] = sum_d (E[n,d]*rinvE[n]) * W2T[j,d]      (4096x1024, 3-product)
  gemm_a32_k<0><<<dim3(NE / 128, D_DIM / 128), 256, 0, stream>>>(
      E, rinvE, W2TH, W2TL, PH, PL, nullptr);
  quant_p_k<<<NE, 256, 0, stream>>>(PH, PL, sp, (int*)PQ);

  rinv_quantx_k<<<MX, 256, 0, stream>>>(X, rinvX, sxr, (int*)XQ);
  gemm_scores1_k<<<(MX / 256) * (NE / 256), 512, 0, stream>>>(XQ, PQ, sxr, sp, gmax);

  cand_select_k<<<BATCH, 256, 0, stream>>>(gmax, candIdx, gmax2);
  gemm_rescore_k<<<dim3(SEQ / 128, 1, BATCH), 256, 0, stream>>>(
      X, rinvX, PH, PL, candIdx, gmax2);
  final_k<<<BATCH, 256, 0, stream>>>(gmax, gmax2, candIdx, alpha, E, rinvE,
                                     sn_w, on_w, Wout, O);
}